// Round 7
// baseline (706.539 us; speedup 1.0000x reference)
//
#include <hip/hip_runtime.h>
#include <stdint.h>

// ---------------------------------------------------------------------------
// MultiHeadedAttention (4-scale patch attention) for MI355X / gfx950
// R7: k_conv — A operand from global regs (wobf repacked [tap][cc][o][32ch],
//     coalesced 1KB fragment loads), B-only LDS double-buffer, ONE barrier
//     per stage, B 2-stage-deep prefetch. k_pv XCD-chunked swizzle.
//     Rest = R6.
// ---------------------------------------------------------------------------

typedef __attribute__((ext_vector_type(8))) short short8;
typedef __attribute__((ext_vector_type(4))) float floatx4;
typedef __attribute__((ext_vector_type(4))) unsigned int uintx4;

#define DEV static __device__ __forceinline__

DEV unsigned short f2bf(float f) {
  unsigned u = __builtin_bit_cast(unsigned, f);
  unsigned r = u + 0x7FFFu + ((u >> 16) & 1u);
  return (unsigned short)(r >> 16);
}

DEV void patch_row(int n, int sc, int lw, int& pt, int& sp0) {
  pt = n >> (2 + 2 * sc);
  int rem = n & ((4 << (2 * sc)) - 1);
  int oh = rem >> (1 + sc), ow = rem & ((2 << sc) - 1);
  sp0 = (oh << (lw + 8)) + (ow << lw);
}

// ---------------- prep kernels ----------------
__global__ void k_prep_w(const float* __restrict__ Wq, const float* __restrict__ Wk,
                         const float* __restrict__ Wv, const float* __restrict__ bq,
                         const float* __restrict__ bk, const float* __restrict__ bv,
                         const float* __restrict__ Wmq, const float* __restrict__ bmq,
                         const float* __restrict__ Wmk, const float* __restrict__ bmk,
                         unsigned short* __restrict__ wqkv, float* __restrict__ bias,
                         float* __restrict__ msc) {
  int b = blockIdx.x;
  int t = threadIdx.x;
  if (b < 768) {
    const float* src = b < 256 ? (Wq + b * 256) : (b < 512 ? (Wk + (b - 256) * 256)
                                                           : (Wv + (b - 512) * 256));
    wqkv[b * 256 + t] = f2bf(src[t]);
    if (t == 0) bias[b] = b < 256 ? bq[b] : (b < 512 ? bk[b - 256] : bv[b - 512]);
  } else {
    int sc = t >> 6, lane = t & 63;
    int ch = sc * 64 + lane;
    float a0 = Wmq[ch] * Wmk[ch];
    float a1 = Wmq[ch] * bmk[ch];
    float a2 = bmq[ch] * Wmk[ch];
    float a3 = bmq[ch] * bmk[ch];
    for (int off = 32; off; off >>= 1) {
      a0 += __shfl_xor(a0, off); a1 += __shfl_xor(a1, off);
      a2 += __shfl_xor(a2, off); a3 += __shfl_xor(a3, off);
    }
    if (lane == 0) {
      msc[sc * 4 + 0] = a0; msc[sc * 4 + 1] = a1;
      msc[sc * 4 + 2] = a2; msc[sc * 4 + 3] = a3;
    }
  }
}

// Wo repack ([tap][cc8][o256][ch32]) + zero(scores||G, pbuf) merged
__global__ void k_prep_wo(const float* __restrict__ Wo, unsigned short* __restrict__ wobf,
                          float* __restrict__ scoresG, unsigned int* __restrict__ pbuf) {
  int blk = blockIdx.x;
  if (blk < 2304) {
    int didx = blk >> 8, o = blk & 255, c = threadIdx.x;
    wobf[((didx * 8 + (c >> 5)) * 256 + o) * 32 + (c & 31)] = f2bf(Wo[o * 2304 + c * 9 + didx]);
  } else {
    int i = (blk - 2304) * 256 + threadIdx.x;
    if (i < 559232) scoresG[i] = 0.f;
    if (i < 140032) pbuf[i] = 0u;
  }
}

// ---------------- transpose kernels ----------------
__global__ __launch_bounds__(256) void k_xt(const float* __restrict__ x,
                                            unsigned short* __restrict__ xt) {
  __shared__ __align__(16) unsigned short tile[64][72];
  int p0 = blockIdx.x * 64, c0 = blockIdx.y * 64, t = blockIdx.z;
  int tid = threadIdx.x;
  {
    int cc = tid >> 2, pq = (tid & 3) * 16;
    const float* src = x + ((t * 256 + c0 + cc) * 65536 + p0 + pq);
    __align__(16) unsigned short tmp[16];
#pragma unroll
    for (int e = 0; e < 16; e += 4) {
      floatx4 v = *(const floatx4*)(src + e);
      tmp[e + 0] = f2bf(v[0]); tmp[e + 1] = f2bf(v[1]);
      tmp[e + 2] = f2bf(v[2]); tmp[e + 3] = f2bf(v[3]);
    }
    *(uintx4*)&tile[cc][pq] = *(const uintx4*)&tmp[0];
    *(uintx4*)&tile[cc][pq + 8] = *(const uintx4*)&tmp[8];
  }
  __syncthreads();
  {
    int pp = tid >> 2, cg = (tid & 3) * 16;
    __align__(16) unsigned short outv[16];
#pragma unroll
    for (int e = 0; e < 16; ++e) outv[e] = tile[cg + e][pp];
    unsigned short* dst = xt + ((t * 65536 + p0 + pp) * 256 + c0 + cg);
    *(uintx4*)dst = *(const uintx4*)&outv[0];
    *(uintx4*)(dst + 8) = *(const uintx4*)&outv[8];
  }
}

__global__ __launch_bounds__(256) void k_yt(const unsigned short* __restrict__ ynat,
                                            unsigned short* __restrict__ yt) {
  __shared__ __align__(16) unsigned short tile[64][72];
  int p0 = blockIdx.x * 64, c0 = blockIdx.y * 64, t = blockIdx.z;
  int tid = threadIdx.x;
  {
    int cc = tid >> 2, pq = (tid & 3) * 16;
    const unsigned short* src = ynat + ((t * 256 + c0 + cc) * 65536 + p0 + pq);
    *(uintx4*)&tile[cc][pq] = *(const uintx4*)src;
    *(uintx4*)&tile[cc][pq + 8] = *(const uintx4*)(src + 8);
  }
  __syncthreads();
  {
    int pp = tid >> 2, cg = (tid & 3) * 16;
    __align__(16) unsigned short outv[16];
#pragma unroll
    for (int e = 0; e < 16; ++e) outv[e] = tile[cg + e][pp];
    unsigned short* dst = yt + ((t * 65536 + p0 + pp) * 256 + c0 + cg);
    *(uintx4*)dst = *(const uintx4*)&outv[0];
    *(uintx4*)(dst + 8) = *(const uintx4*)&outv[8];
  }
}

// ---------------- QKV GEMM: 128x256 tile, 64 MFMA/wave/stage (R6) ----------------
__global__ __launch_bounds__(256, 2) void k_qkv(const unsigned short* __restrict__ xt,
                                                const unsigned short* __restrict__ wqkv,
                                                const float* __restrict__ bias,
                                                unsigned short* __restrict__ qkv) {
  __shared__ __align__(16) unsigned short As[128][64];
  __shared__ __align__(16) unsigned short Bs[256][64];
  int flat = blockIdx.x;
  int lg = (flat & 7) * 384 + (flat >> 3);
  int n_t = lg / 6, m_t = lg - n_t * 6;
  int n0 = n_t << 8, m0 = m_t << 7;
  int tid = threadIdx.x;
  int w = tid >> 6, l = tid & 63;
  int wr = w >> 1, wc = w & 1;
  int l15 = l & 15, lhi = l >> 4;
  int sr = tid >> 1, sbase = (tid & 1) * 4, r7 = sr & 7;
  int b7 = tid & 7;
  const unsigned short* gA = wqkv + (m0 + sr) * 256 + sbase * 8;
  const unsigned short* gB = xt + (n0 + tid) * 256;
  floatx4 zf = {0.f, 0.f, 0.f, 0.f};
  floatx4 acc[4][8];
#pragma unroll
  for (int i = 0; i < 4; ++i)
#pragma unroll
    for (int j = 0; j < 8; ++j) acc[i][j] = zf;
  uintx4 ra[4], rb[8];
#define QLOAD(K0) { const uintx4* pa = (const uintx4*)(gA + (K0)); \
                    ra[0] = pa[0]; ra[1] = pa[1]; ra[2] = pa[2]; ra[3] = pa[3]; \
                    const uintx4* pb = (const uintx4*)(gB + (K0)); \
                    rb[0] = pb[0]; rb[1] = pb[1]; rb[2] = pb[2]; rb[3] = pb[3]; \
                    rb[4] = pb[4]; rb[5] = pb[5]; rb[6] = pb[6]; rb[7] = pb[7]; }
  QLOAD(0);
#pragma unroll
  for (int ch = 0; ch < 4; ++ch) {
    __syncthreads();
#pragma unroll
    for (int j = 0; j < 4; ++j)
      *(uintx4*)&As[sr][((sbase + j) ^ r7) * 8] = ra[j];
#pragma unroll
    for (int j = 0; j < 8; ++j)
      *(uintx4*)&Bs[tid][(j ^ b7) * 8] = rb[j];
    __syncthreads();
    if (ch < 3) QLOAD((ch + 1) * 64);
#pragma unroll
    for (int kk = 0; kk < 2; ++kk) {
      short8 af[4];
#pragma unroll
      for (int f = 0; f < 4; ++f) {
        int arow = wr * 64 + f * 16 + l15;
        af[f] = *(const short8*)&As[arow][(((kk << 2) + lhi) ^ (arow & 7)) * 8];
      }
#pragma unroll
      for (int fn = 0; fn < 8; ++fn) {
        int brow = wc * 128 + fn * 16 + l15;
        short8 b = *(const short8*)&Bs[brow][(((kk << 2) + lhi) ^ (brow & 7)) * 8];
#pragma unroll
        for (int fm = 0; fm < 4; ++fm)
          acc[fm][fn] = __builtin_amdgcn_mfma_f32_16x16x32_bf16(af[fm], b, acc[fm][fn], 0, 0, 0);
      }
    }
  }
#undef QLOAD
#pragma unroll
  for (int fm = 0; fm < 4; ++fm) {
    int crow = m0 + wr * 64 + fm * 16 + lhi * 4;
#pragma unroll
    for (int rr = 0; rr < 4; ++rr) {
      float bv = bias[crow + rr];
#pragma unroll
      for (int fn = 0; fn < 8; ++fn) {
        int pcol = n0 + wc * 128 + fn * 16 + l15;
        int t = pcol >> 16, p = pcol & 65535;
        qkv[(t * 768 + crow + rr) * 65536 + p] = f2bf(acc[fm][fn][rr] + bv);
      }
    }
  }
}

// ---------------- mask gram: LDS-tiled fp32, 32x32 pair tiles ----------------
__global__ __launch_bounds__(256) void k_gram2(const float* __restrict__ m,
                                               float* __restrict__ G) {
  __shared__ __align__(16) float Ns[32][68];
  __shared__ __align__(16) float Ms[32][68];
  int bid = blockIdx.x;
  int sc, tn, tm, z, nchunks, soff;
  if (bid < 32)      { sc = 0; tn = 0; tm = 0; z = bid;      nchunks = 8; soff = 0; }
  else if (bid < 40) { sc = 1; tn = 0; tm = 0; z = bid - 32; nchunks = 8; soff = 64; }
  else if (bid < 72) { int r = bid - 40; int tl = r >> 1; sc = 2; tn = tl >> 2; tm = tl & 3; z = r & 1; nchunks = 8; soff = 1088; }
  else               { int tl = bid - 72; sc = 3; tn = tl >> 4; tm = tl & 15; z = 0; nchunks = 4; soff = 17472; }
  int lw = 7 - sc, W = 1 << lw, N = 8 << (2 * sc);
  int kbase = z * nchunks * 64;
  int n0 = tn * 32, m0 = tm * 32;
  int tid = threadIdx.x;
  bool isA = tid < 128;
  int u = tid & 127;
  int srow = u >> 2, sslot0 = (u & 3) * 4;
  int grow = (isA ? n0 : m0) + srow;
  bool valid = grow < N;
  int pt = 0, sp0 = 0;
  if (valid) patch_row(grow, sc, lw, pt, sp0);
  int gbase = pt * 65536 + sp0;
  int trc = tid >> 4, tcc = tid & 15;
  float a00 = 0.f, a01 = 0.f, a10 = 0.f, a11 = 0.f;
  floatx4 zf = {0.f, 0.f, 0.f, 0.f};
  for (int c = 0; c < nchunks; ++c) {
    int k0 = kbase + c * 64;
    floatx4 v[4];
#pragma unroll
    for (int j = 0; j < 4; ++j) {
      v[j] = zf;
      if (valid) {
        int s = k0 + (sslot0 + j) * 4;
        int hh = s >> lw, ww = s & (W - 1);
        v[j] = *(const floatx4*)(m + gbase + (hh << 8) + ww);
      }
    }
    __syncthreads();
    float* dstrow = isA ? &Ns[srow][0] : &Ms[srow][0];
#pragma unroll
    for (int j = 0; j < 4; ++j) *(floatx4*)&dstrow[(sslot0 + j) * 4] = v[j];
    __syncthreads();
#pragma unroll 4
    for (int k = 0; k < 64; k += 4) {
      floatx4 na = *(const floatx4*)&Ns[2 * trc][k];
      floatx4 nb = *(const floatx4*)&Ns[2 * trc + 1][k];
      floatx4 ma = *(const floatx4*)&Ms[2 * tcc][k];
      floatx4 mb = *(const floatx4*)&Ms[2 * tcc + 1][k];
#pragma unroll
      for (int e = 0; e < 4; ++e) {
        a00 += na[e] * ma[e]; a01 += na[e] * mb[e];
        a10 += nb[e] * ma[e]; a11 += nb[e] * mb[e];
      }
    }
  }
  int rn = n0 + 2 * trc, rm = m0 + 2 * tcc;
  float res[2][2] = {{a00, a01}, {a10, a11}};
#pragma unroll
  for (int i = 0; i < 2; ++i)
#pragma unroll
    for (int j = 0; j < 2; ++j) {
      if (rn + i < N && rm + j < N) {
        float* dst = &G[soff + (rn + i) * N + rm + j];
        if (sc < 3) atomicAdd(dst, res[i][j]); else *dst = res[i][j];
      }
    }
}

__global__ void k_rsum(const float* __restrict__ m, float* __restrict__ rbuf) {
  int row = blockIdx.x, lane = threadIdx.x;
  int sc, n;
  if (row < 8)        { sc = 0; n = row; }
  else if (row < 40)  { sc = 1; n = row - 8; }
  else if (row < 168) { sc = 2; n = row - 40; }
  else                { sc = 3; n = row - 168; }
  int lw = 7 - sc, W = 1 << lw;
  int pt, sp0;
  patch_row(n, sc, lw, pt, sp0);
  int base = pt * 65536 + sp0;
  int S = 1 << (14 - 2 * sc);
  float acc = 0.f;
  for (int s = lane; s < S; s += 64) {
    int hh = s >> lw, ww = s & (W - 1);
    acc += m[base + (hh << 8) + ww];
  }
  for (int off = 32; off; off >>= 1) acc += __shfl_xor(acc, off);
  if (lane == 0) rbuf[row] = acc;
}

// ---------------- scores sc0/sc1: 32x32 tiles, K-chunk 128 ----------------
__global__ __launch_bounds__(256) void k_scores2(const unsigned short* __restrict__ qkv,
                                                 float* __restrict__ scores) {
  __shared__ __align__(16) unsigned short As[32][136];
  __shared__ __align__(16) unsigned short Bs[32][136];
  int bid = blockIdx.x;
  int sc, tn, tm, z, soff;
  if (bid < 256)      { sc = 0; tn = 0; tm = 0; z = bid;       soff = 0; }
  else                { sc = 1; tn = 0; tm = 0; z = bid - 256; soff = 64; }
  int lw = 7 - sc, W = 1 << lw, lS = 14 - 2 * sc, N = 8 << (2 * sc);
  int n0 = tn * 32, m0 = tm * 32;
  int kbase = z * 4096;
  int tid = threadIdx.x, w = tid >> 6, l = tid & 63;
  int wr = w >> 1, wc = w & 1, l15 = l & 15, lhi = l >> 4;
  floatx4 acc = {0.f, 0.f, 0.f, 0.f};
  bool isA = tid < 128;
  int u = tid & 127;
  int srow = u >> 2, sslot0 = (u & 3) * 4;
  int grow = (isA ? n0 : m0) + srow;
  int cb = (isA ? 0 : 256) + sc * 64;
  int pt = 0, sp0 = 0;
  bool valid = grow < N;
  if (valid) patch_row(grow, sc, lw, pt, sp0);
  int rowbase = (pt * 768 + cb) * 65536 + sp0;
  uintx4 zu = {0u, 0u, 0u, 0u};
  uintx4 r[4];
#define SLOAD(KS) { int kb2 = kbase + (KS) * 128; \
  _Pragma("unroll") for (int j = 0; j < 4; ++j) { \
    uintx4 v = zu; \
    if (valid) { int k = kb2 + (sslot0 + j) * 8; \
      int cl = k >> lS; int s = k & ((1 << lS) - 1); \
      int hh = s >> lw, ww = s & (W - 1); \
      v = *(const uintx4*)(qkv + rowbase + cl * 65536 + (hh << 8) + ww); } \
    r[j] = v; } }
  SLOAD(0);
  for (int ks = 0; ks < 32; ++ks) {
    __syncthreads();
    {
      unsigned short* dstrow = isA ? &As[srow][0] : &Bs[srow][0];
#pragma unroll
      for (int j = 0; j < 4; ++j) *(uintx4*)&dstrow[(sslot0 + j) * 8] = r[j];
    }
    __syncthreads();
    if (ks < 31) SLOAD(ks + 1);
#pragma unroll
    for (int kk = 0; kk < 4; ++kk) {
      short8 a = *(const short8*)&As[wr * 16 + l15][(kk * 4 + lhi) * 8];
      short8 b = *(const short8*)&Bs[wc * 16 + l15][(kk * 4 + lhi) * 8];
      acc = __builtin_amdgcn_mfma_f32_16x16x32_bf16(a, b, acc, 0, 0, 0);
    }
  }
#undef SLOAD
  int rrow = n0 + wr * 16 + lhi * 4;
  int ccol = m0 + wc * 16 + l15;
  if (ccol < N) {
#pragma unroll
    for (int rr = 0; rr < 4; ++rr)
      if (rrow + rr < N) atomicAdd(&scores[soff + (rrow + rr) * N + ccol], acc[rr]);
  }
}

// ---------------- scores sc2/sc3: 128x128 tiles, K-split 2048 ----------------
__global__ __launch_bounds__(256) void k_scores_big(const unsigned short* __restrict__ qkv,
                                                    float* __restrict__ scores) {
  __shared__ __align__(16) unsigned short As[128][64];
  __shared__ __align__(16) unsigned short Bs[128][64];
  int flat = blockIdx.x;
  int lg = (flat & 7) * 20 + (flat >> 3);
  int sc, tn, tm, z, soff;
  if (lg < 32) { sc = 2; tn = 0; tm = 0; z = lg; soff = 1088; }
  else { int r = lg - 32; int tl = r >> 3; sc = 3; tn = tl >> 2; tm = tl & 3; z = r & 7; soff = 17472; }
  int N = 8 << (2 * sc);
  int lw = 7 - sc, W = 1 << lw, lS = 14 - 2 * sc;
  int n0 = tn * 128, m0 = tm * 128;
  int kbase = z * 2048;
  int tid = threadIdx.x;
  int w = tid >> 6, l = tid & 63;
  int wr = w >> 1, wc = w & 1;
  int l15 = l & 15, lhi = l >> 4;
  int sr = tid >> 1, sbase = (tid & 1) * 4, r7 = sr & 7;
  int ptA, spA, ptB, spB;
  patch_row(n0 + sr, sc, lw, ptA, spA);
  patch_row(m0 + sr, sc, lw, ptB, spB);
  int baseA = (ptA * 768 + sc * 64) * 65536 + spA;
  int baseB = (ptB * 768 + 256 + sc * 64) * 65536 + spB;
  floatx4 zf = {0.f, 0.f, 0.f, 0.f};
  floatx4 acc[4][4];
#pragma unroll
  for (int i = 0; i < 4; ++i)
#pragma unroll
    for (int j = 0; j < 4; ++j) acc[i][j] = zf;
  uintx4 ra[4], rb[4];
#define GLOAD(K0) { \
  _Pragma("unroll") for (int j = 0; j < 4; ++j) { \
    int k = kbase + (K0) + (sbase + j) * 8; \
    int cl = k >> lS; int s = k & ((1 << lS) - 1); \
    int hh = s >> lw, ww = s & (W - 1); \
    int off = cl * 65536 + (hh << 8) + ww; \
    ra[j] = *(const uintx4*)(qkv + baseA + off); \
    rb[j] = *(const uintx4*)(qkv + baseB + off); } }
  GLOAD(0);
  for (int st = 0; st < 32; ++st) {
    __syncthreads();
#pragma unroll
    for (int j = 0; j < 4; ++j) {
      *(uintx4*)&As[sr][((sbase + j) ^ r7) * 8] = ra[j];
      *(uintx4*)&Bs[sr][((sbase + j) ^ r7) * 8] = rb[j];
    }
    __syncthreads();
    if (st < 31) GLOAD((st + 1) * 64);
#pragma unroll
    for (int kk = 0; kk < 2; ++kk) {
      short8 af[4], bfr[4];
#pragma unroll
      for (int f = 0; f < 4; ++f) {
        int arow = wr * 64 + f * 16 + l15;
        af[f] = *(const short8*)&As[arow][(((kk << 2) + lhi) ^ (arow & 7)) * 8];
        int brow = wc * 64 + f * 16 + l15;
        bfr[f] = *(const short8*)&Bs[brow][(((kk << 2) + lhi) ^ (brow & 7)) * 8];
      }
#pragma unroll
      for (int fm = 0; fm < 4; ++fm)
#pragma unroll
        for (int fn = 0; fn < 4; ++fn)
          acc[fm][fn] = __builtin_amdgcn_mfma_f32_16x16x32_bf16(af[fm], bfr[fn], acc[fm][fn], 0, 0, 0);
    }
  }
#undef GLOAD
#pragma unroll
  for (int fm = 0; fm < 4; ++fm) {
    int nrow = n0 + wr * 64 + fm * 16 + lhi * 4;
#pragma unroll
    for (int rr = 0; rr < 4; ++rr) {
#pragma unroll
      for (int fn = 0; fn < 4; ++fn) {
        int mcol = m0 + wc * 64 + fn * 16 + l15;
        atomicAdd(&scores[soff + (nrow + rr) * N + mcol], acc[fm][fn][rr]);
      }
    }
  }
}

// ---------------- logits + softmax -> P bf16 ----------------
__global__ void k_softmax(const float* __restrict__ scores, const float* __restrict__ G,
                          const float* __restrict__ rbuf, const float* __restrict__ msc,
                          unsigned short* __restrict__ pbuf) {
  int row = blockIdx.x, lane = threadIdx.x;
  int sc, n, roff, soff, poff;
  if (row < 8)        { sc = 0; n = row;       roff = 0;   soff = 0;     poff = 0; }
  else if (row < 40)  { sc = 1; n = row - 8;   roff = 8;   soff = 64;    poff = 512; }
  else if (row < 168) { sc = 2; n = row - 40;  roff = 40;  soff = 1088;  poff = 1536; }
  else                { sc = 3; n = row - 168; roff = 168; soff = 17472; poff = 17920; }
  int N = 8 << (2 * sc);
  int Kpad = (sc < 2) ? 32 : N;
  float Sf = (float)(1 << (14 - 2 * sc));
  float invD = 1.0f / (float)(1 << (20 - 2 * sc));
  float alpha = msc[sc * 4 + 0], beta = msc[sc * 4 + 1];
  float gamma = msc[sc * 4 + 2], delta = msc[sc * 4 + 3];
  float rn = rbuf[roff + n];
  float vals[8];
  float mx = -1e30f;
#pragma unroll
  for (int j = 0; j < 8; ++j) {
    float v = -1e30f;
    int mcol = lane + j * 64;
    if (j * 64 < N && mcol < N) {
      float sq = scores[soff + n * N + mcol];
      float g = G[soff + n * N + mcol];
      float rm = rbuf[roff + mcol];
      v = sq * (alpha * g + beta * rn + gamma * rm + delta * Sf) * invD;
    }
    vals[j] = v;
    mx = fmaxf(mx, v);
  }
  for (int off = 32; off; off >>= 1) mx = fmaxf(mx, __shfl_xor(mx, off));
  float sum = 0.f;
#pragma unroll
  for (int j = 0; j < 8; ++j) {
    int mcol = lane + j * 64;
    float e = 0.f;
    if (j * 64 < N && mcol < N) e = __expf(vals[j] - mx);
    vals[j] = e;
    sum += e;
  }
  for (int off = 32; off; off >>= 1) sum += __shfl_xor(sum, off);
  float inv = 1.f / sum;
#pragma unroll
  for (int j = 0; j < 8; ++j) {
    int mcol = lane + j * 64;
    if (j * 64 < N && mcol < N) pbuf[poff + n * Kpad + mcol] = f2bf(vals[j] * inv);
  }
}

// ---------------- PV GEMM: dbuf LDS, 1 barrier/K-step, XCD-chunked ----------------
__global__ __launch_bounds__(256) void k_pv(const unsigned short* __restrict__ qkv,
                                            const unsigned short* __restrict__ pbuf,
                                            unsigned short* __restrict__ ynat) {
  int bid0 = blockIdx.x;
  int bid = (bid0 & 7) * 1280 + (bid0 >> 3);   // XCD chunking: sibling by-groups co-XCD
  int sc, bx, by;
  if (bid < 4096)      { sc = 0; bx = bid; by = 0; }
  else if (bid < 6144) { sc = 1; bx = bid - 4096; by = 0; }
  else if (bid < 8192) { int r = bid - 6144; sc = 2; bx = r >> 1; by = r & 1; }
  else                 { int r = bid - 8192; sc = 3; bx = r >> 3; by = r & 7; }
  int WR    = (sc == 0) ? 1 : (sc == 1) ? 2 : 4;
  int logWC = (sc == 0) ? 2 : (sc == 1) ? 1 : 0;
  int poff  = (sc == 0) ? 0 : (sc == 1) ? 512 : (sc == 2) ? 1536 : 17920;
  int lw = 7 - sc, W = 1 << lw;
  int lS = 14 - 2 * sc;
  int N = 8 << (2 * sc);
  int Kpad = (sc < 2) ? 32 : N;
  int WC = 1 << logWC;
  int d0 = bx * (WC * 64);
  int nb = by * (WR * 16);
  __shared__ __align__(16) unsigned short As[2][64][40];
  __shared__ __align__(16) unsigned short Bt[2][256][32];
  int tid = threadIdx.x;
  int w = tid >> 6, l = tid & 63;
  int wr = w >> logWC, wc = w & (WC - 1);
  int l15 = l & 15, lhi = l >> 4;
  floatx4 zf = {0.f, 0.f, 0.f, 0.f};
  floatx4 acc[4];
#pragma unroll
  for (int i = 0; i < 4; ++i) acc[i] = zf;
  int bmp = tid & 15;
  int dg = tid >> 4;
  bool act0 = (WC > 1) || (dg < 8);
  bool has1 = (WC == 4);
  bool doA = tid < WR * 64;
  int arow = tid >> 2, akg = (tid & 3) * 8;
  int ksteps = Kpad >> 5;
  uintx4 zu = {0u, 0u, 0u, 0u};
  int vcb = (512 + sc * 64) * 65536;
  uintx4 av = zu, lo0 = zu, hi0 = zu, lo1 = zu, hi1 = zu;
#define PLOADS(KS) { int k0 = (KS) * 32; \
    av = zu; lo0 = zu; hi0 = zu; lo1 = zu; hi1 = zu; \
    if (doA) av = *(const uintx4*)(pbuf + poff + (nb + arow) * Kpad + k0 + akg); \
    int gm0 = k0 + 2 * bmp, gm1 = gm0 + 1; \
    bool mv0 = gm0 < N, mv1 = gm1 < N; \
    int pt0 = 0, sp00 = 0, pt1 = 0, sp01 = 0; \
    if (mv0) patch_row(gm0, sc, lw, pt0, sp00); \
    if (mv1) patch_row(gm1, sc, lw, pt1, sp01); \
    { int d = d0 + dg * 8; int cl = d >> lS; int s = d & ((1 << lS) - 1); \
      int hh = s >> lw, ww = s & (W - 1); int sp = (hh << 8) + ww; \
      if (act0 && mv0) lo0 = *(const uintx4*)(qkv + pt0 * 768 * 65536 + vcb + cl * 65536 + sp00 + sp); \
      if (act0 && mv1) hi0 = *(const uintx4*)(qkv + pt1 * 768 * 65536 + vcb + cl * 65536 + sp01 + sp); } \
    if (has1) { int d = d0 + (dg + 16) * 8; int cl = d >> lS; int s = d & ((1 << lS) - 1); \
      int hh = s >> lw, ww = s & (W - 1); int sp = (hh << 8) + ww; \
      if (mv0) lo1 = *(const uintx4*)(qkv + pt0 * 768 * 65536 + vcb + cl * 65536 + sp00 + sp); \
      if (mv1) hi1 = *(const uintx4*)(qkv + pt1 * 768 * 65536 + vcb + cl * 65536 + sp01 + sp); } }
  PLOADS(0);
  for (int ks = 0; ks < ksteps; ++ks) {
    int b = ks & 1;
    if (doA) *(uintx4*)&As[b][arow][akg] = av;
    if (act0) {
      int du = dg * 8;
#pragma unroll
      for (int j = 0; j < 8; ++j) {
        int d = du + j;
        unsigned losh = (lo0[j >> 1] >> ((j & 1) * 16)) & 0xFFFFu;
        unsigned hish = (hi0[j >> 1] >> ((j & 1) * 16)) & 0xFFFFu;
        unsigned wv = losh | (hish << 16);
        int slot = (bmp >> 2) ^ ((d >> 1) & 3) ^ ((d >> 3) & 3);
        ((unsigned int*)&Bt[b][d][0])[slot * 4 + (bmp & 3)] = wv;
      }
    }
    if (has1) {
      int du = (dg + 16) * 8;
#pragma unroll
      for (int j = 0; j < 8; ++j) {
        int d = du + j;
        unsigned losh = (lo1[j >> 1] >> ((j & 1) * 16)) & 0xFFFFu;
        unsigned hish = (hi1[j >> 1] >> ((j & 1) * 16)) & 0xFFFFu;
        unsigned wv = losh | (hish << 16);
        int slot = (bmp >> 2) ^ ((d >> 1) & 3) ^ ((d >> 3) & 3);
        ((unsigned int*)&Bt[b][d][0])[slot * 4 + (bmp & 3)] = wv;
      }
    }
    __syncthreads();
    if (ks + 1 < ksteps) PLOADS(ks + 1);
    short8 a = *(const short8*)&As[b][wr * 16 + l15][lhi * 8];
#pragma unroll
    for (int fn = 0; fn < 4; ++fn) {
      int row = wc * 64 + fn * 16 + l15;
      int slot = lhi ^ ((row >> 1) & 3) ^ ((row >> 3) & 3);
      short8 bb = *(const short8*)&Bt[b][row][slot * 8];
      acc[fn] = __builtin_amdgcn_mfma_f32_16x16x32_bf16(a, bb, acc[fn], 0, 0, 0);
    }
  }
#undef PLOADS
  int nrow = nb + wr * 16 + lhi * 4;
#pragma unroll
  for (int rr = 0; rr < 4; ++rr) {
    int n = nrow + rr;
    if (n < N) {
      int pt, sp0;
      patch_row(n, sc, lw, pt, sp0);
#pragma unroll
      for (int fn = 0; fn < 4; ++fn) {
        int d = d0 + wc * 64 + fn * 16 + l15;
        int cl = d >> lS;
        int s = d & ((1 << lS) - 1);
        int hh = s >> lw, ww = s & (W - 1);
        int c = sc * 64 + cl;
        ynat[(pt * 256 + c) * 65536 + sp0 + (hh << 8) + ww] = f2bf(acc[fn][rr]);
      }
    }
  }
}

// ---------------- conv3x3: A-from-global, B-only dbuf LDS, 1 barrier/stage ----------------
__global__ __launch_bounds__(256, 2) void k_conv(const unsigned short* __restrict__ yt,
                                                 const unsigned short* __restrict__ wo2,
                                                 const float* __restrict__ bo,
                                                 float* __restrict__ out) {
  __shared__ __align__(16) unsigned short Bs[2][130][64];
  int flat = blockIdx.x;
  int lg = ((flat & 7) << 7) + (flat >> 3);
  int n_t = lg >> 1, m_t = lg & 1;
  int n0 = n_t << 8, m0 = m_t << 7;
  int tt = n0 >> 16, yy = (n0 >> 8) & 255;
  int tid = threadIdx.x;
  int w = tid >> 6, l = tid & 63;
  int wr = w >> 1, wc = w & 1;
  int l15 = l & 15, lhi = l >> 4;
  bool doBh = tid >= 254;
  floatx4 zf = {0.f, 0.f, 0.f, 0.f};
  floatx4 acc[4][8];
#pragma unroll
  for (int i = 0; i < 4; ++i)
#pragma unroll
    for (int j = 0; j < 8; ++j) acc[i][j] = zf;
  uintx4 zu = {0u, 0u, 0u, 0u};
  uintx4 rbA[4], rbB[4], rh[4];
  const unsigned short* ybase = yt + (tt << 24);
  // A fragment lane base: wo2 layout [tap9][cc8][o256][ch32]
  const unsigned short* wbase = wo2 + (m0 + wr * 64 + l15) * 32 + lhi * 8;
#define CLB(ST, RB) { int dy_ = (ST) >> 3, cc_ = ((ST) & 7) << 5; \
    int yq_ = yy + dy_ - 1; int xq_ = tid - 1; \
    if (((unsigned)yq_ < 256u) && ((unsigned)xq_ < 256u)) { \
      const uintx4* p_ = (const uintx4*)(ybase + ((yq_ << 8) + xq_) * 256 + cc_); \
      RB[0] = p_[0]; RB[1] = p_[1]; RB[2] = p_[2]; RB[3] = p_[3]; \
    } else { RB[0] = zu; RB[1] = zu; RB[2] = zu; RB[3] = zu; } }
#define CLH(ST) { int dy_ = (ST) >> 3, cc_ = ((ST) & 7) << 5; \
    int yq_ = yy + dy_ - 1; int xq_ = tid + 1; \
    if (doBh && ((unsigned)yq_ < 256u) && (xq_ < 256)) { \
      const uintx4* p_ = (const uintx4*)(ybase + ((yq_ << 8) + xq_) * 256 + cc_); \
      rh[0] = p_[0]; rh[1] = p_[1]; rh[2] = p_[2]; rh[3] = p_[3]; \
    } else { rh[0] = zu; rh[1] = zu; rh[2] = zu; rh[3] = zu; } }
#define BWR(BUF, RB) { int brow_ = tid >> 1, bhf_ = (tid & 1) * 4, br7_ = brow_ & 7; \
    _Pragma("unroll") for (int j = 0; j < 4; ++j) \
      *(uintx4*)&Bs[BUF][brow_][((bhf_ + j) ^ br7_) * 8] = RB[j]; \
    if (doBh) { int xh_ = tid + 2; int brow2_ = xh_ >> 1, bhf2_ = (xh_ & 1) * 4, br72_ = brow2_ & 7; \
    _Pragma("unroll") for (int j = 0; j < 4; ++j) \
      *(uintx4*)&Bs[BUF][brow2_][((bhf2_ + j) ^ br72_) * 8] = rh[j]; } }
  // prologue: stage0 -> buf0; stage1 loaded
  CLB(0, rbA); CLH(0);
  BWR(0, rbA);
  CLB(1, rbB); CLH(1);
  __syncthreads();
  for (int st = 0; st < 24; ++st) {
    int cur = st & 1;
    // write stage st+1 into the other buffer (data pre-loaded)
    if (st < 23) { if (cur == 0) { BWR(1, rbB); } else { BWR(0, rbA); } }
    // issue stage st+2 loads into the freed set
    if (st < 22) { if (cur == 0) { CLB(st + 2, rbA); } else { CLB(st + 2, rbB); } }
    if (st < 22) { CLH(st + 2); }
    // A fragments for stage st (global, L1/L2-hot), per-dx pipelined
    int dy = st >> 3, ccs = st & 7;
    const unsigned short* abase = wbase + ((dy * 3) * 8 + ccs) * 256 * 32;
    short8 af[4], ag[4];
#pragma unroll
    for (int f = 0; f < 4; ++f) af[f] = *(const short8*)(abase + f * 512);
#pragma unroll
    for (int dx = 0; dx < 3; ++dx) {
      if (dx < 2) {
        const unsigned short* ab2 = abase + (dx + 1) * 65536;
#pragma unroll
        for (int f = 0; f < 4; ++f) ag[f] = *(const short8*)(ab2 + f * 512);
      }
#pragma unroll
      for (int fn = 0; fn < 8; ++fn) {
        int xh = wc * 128 + fn * 16 + l15 + dx;
        short8 b = *(const short8*)&Bs[cur][xh >> 1][((((xh & 1) * 4 + lhi)) ^ ((xh >> 1) & 7)) * 8];
#pragma unroll
        for (int fm = 0; fm < 4; ++fm)
          acc[fm][fn] = __builtin_amdgcn_mfma_f32_16x16x32_bf16(af[fm], b, acc[fm][fn], 0, 0, 0);
      }
      if (dx < 2) {
#pragma unroll
        for (int f = 0; f < 4; ++f) af[f] = ag[f];
      }
    }
    __syncthreads();
  }
#undef CLB
#undef CLH
#undef BWR
#pragma unroll
  for (int fm = 0; fm < 4; ++fm) {
    int o = m0 + wr * 64 + fm * 16 + lhi * 4;
#pragma unroll
    for (int rr = 0; rr < 4; ++rr) {
      float bias = bo[o + rr];
#pragma unroll
      for (int fn = 0; fn < 8; ++fn) {
        int xcol = wc * 128 + fn * 16 + l15;
        float z = acc[fm][fn][rr] + bias;
        out[((tt * 256 + o + rr) << 16) + (yy << 8) + xcol] = z > 0.f ? z : 0.2f * z;
      }
    }
  }
}

// ---------------------------------------------------------------------------
extern "C" void kernel_launch(void* const* d_in, const int* in_sizes, int n_in,
                              void* d_out, int out_size, void* d_ws, size_t ws_size,
                              hipStream_t stream) {
  const float* x   = (const float*)d_in[0];
  const float* m   = (const float*)d_in[1];
  const float* Wq  = (const float*)d_in[2];
  const float* bq  = (const float*)d_in[3];
  const float* Wk  = (const float*)d_in[4];
  const float* bk  = (const float*)d_in[5];
  const float* Wv  = (const float*)d_in[6];
  const float* bv  = (const float*)d_in[7];
  const float* Wmq = (const float*)d_in[8];
  const float* bmq = (const float*)d_in[9];
  const float* Wmk = (const float*)d_in[10];
  const float* bmk = (const float*)d_in[11];
  const float* Wo  = (const float*)d_in[12];
  const float* bo  = (const float*)d_in[13];

  char* ws = (char*)d_ws;
  unsigned short* qkv   = (unsigned short*)(ws);
  unsigned short* xtb   = (unsigned short*)(ws + 201326592);  // xt, later yt
  unsigned short* wqkv  = (unsigned short*)(ws + 268435456);
  unsigned short* wobf  = (unsigned short*)(ws + 268828672);
  float* bias           = (float*)(ws + 270008320);
  float* msc            = (float*)(ws + 270011392);
  float* scores         = (float*)(ws + 270011456);
  float* G              = (float*)(ws + 271129920);
  float* rbuf           = (float*)(ws + 272248384);
  unsigned short* pbuf  = (unsigned short*)(ws + 272251104);
  float* out            = (float*)d_out;
  unsigned short* ynat  = (unsigned short*)d_out;  // low half of d_out as bf16 scratch

  k_prep_w<<<dim3(769), dim3(256), 0, stream>>>(Wq, Wk, Wv, bq, bk, bv, Wmq, bmq, Wmk, bmk,
                                                wqkv, bias, msc);
  k_prep_wo<<<dim3(4489), dim3(256), 0, stream>>>(Wo, wobf, scores, (unsigned int*)pbuf);
  k_xt<<<dim3(1024, 4, 2), dim3(256), 0, stream>>>(x, xtb);
  k_qkv<<<dim3(3072), dim3(256), 0, stream>>>(xtb, wqkv, bias, qkv);
  k_gram2<<<dim3(328), dim3(256), 0, stream>>>(m, G);
  k_rsum<<<dim3(680), dim3(64), 0, stream>>>(m, rbuf);
  k_scores2<<<dim3(320), dim3(256), 0, stream>>>(qkv, scores);
  k_scores_big<<<dim3(160), dim3(256), 0, stream>>>(qkv, scores);
  k_softmax<<<dim3(680), dim3(64), 0, stream>>>(scores, G, rbuf, msc, pbuf);
  k_pv<<<dim3(10240), dim3(256), 0, stream>>>(qkv, pbuf, ynat);
  k_yt<<<dim3(1024, 4, 2), dim3(256), 0, stream>>>(ynat, xtb);
  k_conv<<<dim3(1024), dim3(256), 0, stream>>>(xtb, wobf, bo, out);
}

// Round 8
// 614.491 us; speedup vs baseline: 1.1498x; 1.1498x over previous
//
#include <hip/hip_runtime.h>
#include <stdint.h>

// ---------------------------------------------------------------------------
// MultiHeadedAttention (4-scale patch attention) for MI355X / gfx950
// R8: pv reverted to R6 (no XCD chunk). conv rewritten as m201-style GEMM:
//     M=256(o) x N=131072(p2) x K=2304 (tap-major, BK=64 = one tap/tile),
//     512 thr / 8 waves, A+B dbuf 128KB LDS via global_load_lds(16B) with
//     pre-swizzled sources, 1 barrier per K-tile, 64 MFMA/wave/tile, setprio.
// ---------------------------------------------------------------------------

typedef __attribute__((ext_vector_type(8))) short short8;
typedef __attribute__((ext_vector_type(4))) float floatx4;
typedef __attribute__((ext_vector_type(4))) unsigned int uintx4;

#define DEV static __device__ __forceinline__

DEV unsigned short f2bf(float f) {
  unsigned u = __builtin_bit_cast(unsigned, f);
  unsigned r = u + 0x7FFFu + ((u >> 16) & 1u);
  return (unsigned short)(r >> 16);
}

DEV void patch_row(int n, int sc, int lw, int& pt, int& sp0) {
  pt = n >> (2 + 2 * sc);
  int rem = n & ((4 << (2 * sc)) - 1);
  int oh = rem >> (1 + sc), ow = rem & ((2 << sc) - 1);
  sp0 = (oh << (lw + 8)) + (ow << lw);
}

// ---------------- prep kernels ----------------
__global__ void k_prep_w(const float* __restrict__ Wq, const float* __restrict__ Wk,
                         const float* __restrict__ Wv, const float* __restrict__ bq,
                         const float* __restrict__ bk, const float* __restrict__ bv,
                         const float* __restrict__ Wmq, const float* __restrict__ bmq,
                         const float* __restrict__ Wmk, const float* __restrict__ bmk,
                         unsigned short* __restrict__ wqkv, float* __restrict__ bias,
                         float* __restrict__ msc) {
  int b = blockIdx.x;
  int t = threadIdx.x;
  if (b < 768) {
    const float* src = b < 256 ? (Wq + b * 256) : (b < 512 ? (Wk + (b - 256) * 256)
                                                           : (Wv + (b - 512) * 256));
    wqkv[b * 256 + t] = f2bf(src[t]);
    if (t == 0) bias[b] = b < 256 ? bq[b] : (b < 512 ? bk[b - 256] : bv[b - 512]);
  } else {
    int sc = t >> 6, lane = t & 63;
    int ch = sc * 64 + lane;
    float a0 = Wmq[ch] * Wmk[ch];
    float a1 = Wmq[ch] * bmk[ch];
    float a2 = bmq[ch] * Wmk[ch];
    float a3 = bmq[ch] * bmk[ch];
    for (int off = 32; off; off >>= 1) {
      a0 += __shfl_xor(a0, off); a1 += __shfl_xor(a1, off);
      a2 += __shfl_xor(a2, off); a3 += __shfl_xor(a3, off);
    }
    if (lane == 0) {
      msc[sc * 4 + 0] = a0; msc[sc * 4 + 1] = a1;
      msc[sc * 4 + 2] = a2; msc[sc * 4 + 3] = a3;
    }
  }
}

// Wo repack to [o][k=tap*256+c] + zero(scores||G, pbuf) merged
__global__ void k_prep_wo(const float* __restrict__ Wo, unsigned short* __restrict__ wo3,
                          float* __restrict__ scoresG, unsigned int* __restrict__ pbuf) {
  int blk = blockIdx.x;
  if (blk < 2304) {
    int didx = blk >> 8, o = blk & 255, c = threadIdx.x;
    wo3[o * 2304 + didx * 256 + c] = f2bf(Wo[o * 2304 + c * 9 + didx]);
  } else {
    int i = (blk - 2304) * 256 + threadIdx.x;
    if (i < 559232) scoresG[i] = 0.f;
    if (i < 140032) pbuf[i] = 0u;
  }
}

// ---------------- transpose kernels ----------------
__global__ __launch_bounds__(256) void k_xt(const float* __restrict__ x,
                                            unsigned short* __restrict__ xt) {
  __shared__ __align__(16) unsigned short tile[64][72];
  int p0 = blockIdx.x * 64, c0 = blockIdx.y * 64, t = blockIdx.z;
  int tid = threadIdx.x;
  {
    int cc = tid >> 2, pq = (tid & 3) * 16;
    const float* src = x + ((t * 256 + c0 + cc) * 65536 + p0 + pq);
    __align__(16) unsigned short tmp[16];
#pragma unroll
    for (int e = 0; e < 16; e += 4) {
      floatx4 v = *(const floatx4*)(src + e);
      tmp[e + 0] = f2bf(v[0]); tmp[e + 1] = f2bf(v[1]);
      tmp[e + 2] = f2bf(v[2]); tmp[e + 3] = f2bf(v[3]);
    }
    *(uintx4*)&tile[cc][pq] = *(const uintx4*)&tmp[0];
    *(uintx4*)&tile[cc][pq + 8] = *(const uintx4*)&tmp[8];
  }
  __syncthreads();
  {
    int pp = tid >> 2, cg = (tid & 3) * 16;
    __align__(16) unsigned short outv[16];
#pragma unroll
    for (int e = 0; e < 16; ++e) outv[e] = tile[cg + e][pp];
    unsigned short* dst = xt + ((t * 65536 + p0 + pp) * 256 + c0 + cg);
    *(uintx4*)dst = *(const uintx4*)&outv[0];
    *(uintx4*)(dst + 8) = *(const uintx4*)&outv[8];
  }
}

__global__ __launch_bounds__(256) void k_yt(const unsigned short* __restrict__ ynat,
                                            unsigned short* __restrict__ yt) {
  __shared__ __align__(16) unsigned short tile[64][72];
  int p0 = blockIdx.x * 64, c0 = blockIdx.y * 64, t = blockIdx.z;
  int tid = threadIdx.x;
  {
    int cc = tid >> 2, pq = (tid & 3) * 16;
    const unsigned short* src = ynat + ((t * 256 + c0 + cc) * 65536 + p0 + pq);
    *(uintx4*)&tile[cc][pq] = *(const uintx4*)src;
    *(uintx4*)&tile[cc][pq + 8] = *(const uintx4*)(src + 8);
  }
  __syncthreads();
  {
    int pp = tid >> 2, cg = (tid & 3) * 16;
    __align__(16) unsigned short outv[16];
#pragma unroll
    for (int e = 0; e < 16; ++e) outv[e] = tile[cg + e][pp];
    unsigned short* dst = yt + ((t * 65536 + p0 + pp) * 256 + c0 + cg);
    *(uintx4*)dst = *(const uintx4*)&outv[0];
    *(uintx4*)(dst + 8) = *(const uintx4*)&outv[8];
  }
}

// ---------------- QKV GEMM: 128x256 tile, 64 MFMA/wave/stage (R6) ----------------
__global__ __launch_bounds__(256, 2) void k_qkv(const unsigned short* __restrict__ xt,
                                                const unsigned short* __restrict__ wqkv,
                                                const float* __restrict__ bias,
                                                unsigned short* __restrict__ qkv) {
  __shared__ __align__(16) unsigned short As[128][64];
  __shared__ __align__(16) unsigned short Bs[256][64];
  int flat = blockIdx.x;
  int lg = (flat & 7) * 384 + (flat >> 3);
  int n_t = lg / 6, m_t = lg - n_t * 6;
  int n0 = n_t << 8, m0 = m_t << 7;
  int tid = threadIdx.x;
  int w = tid >> 6, l = tid & 63;
  int wr = w >> 1, wc = w & 1;
  int l15 = l & 15, lhi = l >> 4;
  int sr = tid >> 1, sbase = (tid & 1) * 4, r7 = sr & 7;
  int b7 = tid & 7;
  const unsigned short* gA = wqkv + (m0 + sr) * 256 + sbase * 8;
  const unsigned short* gB = xt + (n0 + tid) * 256;
  floatx4 zf = {0.f, 0.f, 0.f, 0.f};
  floatx4 acc[4][8];
#pragma unroll
  for (int i = 0; i < 4; ++i)
#pragma unroll
    for (int j = 0; j < 8; ++j) acc[i][j] = zf;
  uintx4 ra[4], rb[8];
#define QLOAD(K0) { const uintx4* pa = (const uintx4*)(gA + (K0)); \
                    ra[0] = pa[0]; ra[1] = pa[1]; ra[2] = pa[2]; ra[3] = pa[3]; \
                    const uintx4* pb = (const uintx4*)(gB + (K0)); \
                    rb[0] = pb[0]; rb[1] = pb[1]; rb[2] = pb[2]; rb[3] = pb[3]; \
                    rb[4] = pb[4]; rb[5] = pb[5]; rb[6] = pb[6]; rb[7] = pb[7]; }
  QLOAD(0);
#pragma unroll
  for (int ch = 0; ch < 4; ++ch) {
    __syncthreads();
#pragma unroll
    for (int j = 0; j < 4; ++j)
      *(uintx4*)&As[sr][((sbase + j) ^ r7) * 8] = ra[j];
#pragma unroll
    for (int j = 0; j < 8; ++j)
      *(uintx4*)&Bs[tid][(j ^ b7) * 8] = rb[j];
    __syncthreads();
    if (ch < 3) QLOAD((ch + 1) * 64);
#pragma unroll
    for (int kk = 0; kk < 2; ++kk) {
      short8 af[4];
#pragma unroll
      for (int f = 0; f < 4; ++f) {
        int arow = wr * 64 + f * 16 + l15;
        af[f] = *(const short8*)&As[arow][(((kk << 2) + lhi) ^ (arow & 7)) * 8];
      }
#pragma unroll
      for (int fn = 0; fn < 8; ++fn) {
        int brow = wc * 128 + fn * 16 + l15;
        short8 b = *(const short8*)&Bs[brow][(((kk << 2) + lhi) ^ (brow & 7)) * 8];
#pragma unroll
        for (int fm = 0; fm < 4; ++fm)
          acc[fm][fn] = __builtin_amdgcn_mfma_f32_16x16x32_bf16(af[fm], b, acc[fm][fn], 0, 0, 0);
      }
    }
  }
#undef QLOAD
#pragma unroll
  for (int fm = 0; fm < 4; ++fm) {
    int crow = m0 + wr * 64 + fm * 16 + lhi * 4;
#pragma unroll
    for (int rr = 0; rr < 4; ++rr) {
      float bv = bias[crow + rr];
#pragma unroll
      for (int fn = 0; fn < 8; ++fn) {
        int pcol = n0 + wc * 128 + fn * 16 + l15;
        int t = pcol >> 16, p = pcol & 65535;
        qkv[(t * 768 + crow + rr) * 65536 + p] = f2bf(acc[fm][fn][rr] + bv);
      }
    }
  }
}

// ---------------- mask gram: LDS-tiled fp32, 32x32 pair tiles ----------------
__global__ __launch_bounds__(256) void k_gram2(const float* __restrict__ m,
                                               float* __restrict__ G) {
  __shared__ __align__(16) float Ns[32][68];
  __shared__ __align__(16) float Ms[32][68];
  int bid = blockIdx.x;
  int sc, tn, tm, z, nchunks, soff;
  if (bid < 32)      { sc = 0; tn = 0; tm = 0; z = bid;      nchunks = 8; soff = 0; }
  else if (bid < 40) { sc = 1; tn = 0; tm = 0; z = bid - 32; nchunks = 8; soff = 64; }
  else if (bid < 72) { int r = bid - 40; int tl = r >> 1; sc = 2; tn = tl >> 2; tm = tl & 3; z = r & 1; nchunks = 8; soff = 1088; }
  else               { int tl = bid - 72; sc = 3; tn = tl >> 4; tm = tl & 15; z = 0; nchunks = 4; soff = 17472; }
  int lw = 7 - sc, W = 1 << lw, N = 8 << (2 * sc);
  int kbase = z * nchunks * 64;
  int n0 = tn * 32, m0 = tm * 32;
  int tid = threadIdx.x;
  bool isA = tid < 128;
  int u = tid & 127;
  int srow = u >> 2, sslot0 = (u & 3) * 4;
  int grow = (isA ? n0 : m0) + srow;
  bool valid = grow < N;
  int pt = 0, sp0 = 0;
  if (valid) patch_row(grow, sc, lw, pt, sp0);
  int gbase = pt * 65536 + sp0;
  int trc = tid >> 4, tcc = tid & 15;
  float a00 = 0.f, a01 = 0.f, a10 = 0.f, a11 = 0.f;
  floatx4 zf = {0.f, 0.f, 0.f, 0.f};
  for (int c = 0; c < nchunks; ++c) {
    int k0 = kbase + c * 64;
    floatx4 v[4];
#pragma unroll
    for (int j = 0; j < 4; ++j) {
      v[j] = zf;
      if (valid) {
        int s = k0 + (sslot0 + j) * 4;
        int hh = s >> lw, ww = s & (W - 1);
        v[j] = *(const floatx4*)(m + gbase + (hh << 8) + ww);
      }
    }
    __syncthreads();
    float* dstrow = isA ? &Ns[srow][0] : &Ms[srow][0];
#pragma unroll
    for (int j = 0; j < 4; ++j) *(floatx4*)&dstrow[(sslot0 + j) * 4] = v[j];
    __syncthreads();
#pragma unroll 4
    for (int k = 0; k < 64; k += 4) {
      floatx4 na = *(const floatx4*)&Ns[2 * trc][k];
      floatx4 nb = *(const floatx4*)&Ns[2 * trc + 1][k];
      floatx4 ma = *(const floatx4*)&Ms[2 * tcc][k];
      floatx4 mb = *(const floatx4*)&Ms[2 * tcc + 1][k];
#pragma unroll
      for (int e = 0; e < 4; ++e) {
        a00 += na[e] * ma[e]; a01 += na[e] * mb[e];
        a10 += nb[e] * ma[e]; a11 += nb[e] * mb[e];
      }
    }
  }
  int rn = n0 + 2 * trc, rm = m0 + 2 * tcc;
  float res[2][2] = {{a00, a01}, {a10, a11}};
#pragma unroll
  for (int i = 0; i < 2; ++i)
#pragma unroll
    for (int j = 0; j < 2; ++j) {
      if (rn + i < N && rm + j < N) {
        float* dst = &G[soff + (rn + i) * N + rm + j];
        if (sc < 3) atomicAdd(dst, res[i][j]); else *dst = res[i][j];
      }
    }
}

__global__ void k_rsum(const float* __restrict__ m, float* __restrict__ rbuf) {
  int row = blockIdx.x, lane = threadIdx.x;
  int sc, n;
  if (row < 8)        { sc = 0; n = row; }
  else if (row < 40)  { sc = 1; n = row - 8; }
  else if (row < 168) { sc = 2; n = row - 40; }
  else                { sc = 3; n = row - 168; }
  int lw = 7 - sc, W = 1 << lw;
  int pt, sp0;
  patch_row(n, sc, lw, pt, sp0);
  int base = pt * 65536 + sp0;
  int S = 1 << (14 - 2 * sc);
  float acc = 0.f;
  for (int s = lane; s < S; s += 64) {
    int hh = s >> lw, ww = s & (W - 1);
    acc += m[base + (hh << 8) + ww];
  }
  for (int off = 32; off; off >>= 1) acc += __shfl_xor(acc, off);
  if (lane == 0) rbuf[row] = acc;
}

// ---------------- scores sc0/sc1: 32x32 tiles, K-chunk 128 ----------------
__global__ __launch_bounds__(256) void k_scores2(const unsigned short* __restrict__ qkv,
                                                 float* __restrict__ scores) {
  __shared__ __align__(16) unsigned short As[32][136];
  __shared__ __align__(16) unsigned short Bs[32][136];
  int bid = blockIdx.x;
  int sc, tn, tm, z, soff;
  if (bid < 256)      { sc = 0; tn = 0; tm = 0; z = bid;       soff = 0; }
  else                { sc = 1; tn = 0; tm = 0; z = bid - 256; soff = 64; }
  int lw = 7 - sc, W = 1 << lw, lS = 14 - 2 * sc, N = 8 << (2 * sc);
  int n0 = tn * 32, m0 = tm * 32;
  int kbase = z * 4096;
  int tid = threadIdx.x, w = tid >> 6, l = tid & 63;
  int wr = w >> 1, wc = w & 1, l15 = l & 15, lhi = l >> 4;
  floatx4 acc = {0.f, 0.f, 0.f, 0.f};
  bool isA = tid < 128;
  int u = tid & 127;
  int srow = u >> 2, sslot0 = (u & 3) * 4;
  int grow = (isA ? n0 : m0) + srow;
  int cb = (isA ? 0 : 256) + sc * 64;
  int pt = 0, sp0 = 0;
  bool valid = grow < N;
  if (valid) patch_row(grow, sc, lw, pt, sp0);
  int rowbase = (pt * 768 + cb) * 65536 + sp0;
  uintx4 zu = {0u, 0u, 0u, 0u};
  uintx4 r[4];
#define SLOAD(KS) { int kb2 = kbase + (KS) * 128; \
  _Pragma("unroll") for (int j = 0; j < 4; ++j) { \
    uintx4 v = zu; \
    if (valid) { int k = kb2 + (sslot0 + j) * 8; \
      int cl = k >> lS; int s = k & ((1 << lS) - 1); \
      int hh = s >> lw, ww = s & (W - 1); \
      v = *(const uintx4*)(qkv + rowbase + cl * 65536 + (hh << 8) + ww); } \
    r[j] = v; } }
  SLOAD(0);
  for (int ks = 0; ks < 32; ++ks) {
    __syncthreads();
    {
      unsigned short* dstrow = isA ? &As[srow][0] : &Bs[srow][0];
#pragma unroll
      for (int j = 0; j < 4; ++j) *(uintx4*)&dstrow[(sslot0 + j) * 8] = r[j];
    }
    __syncthreads();
    if (ks < 31) SLOAD(ks + 1);
#pragma unroll
    for (int kk = 0; kk < 4; ++kk) {
      short8 a = *(const short8*)&As[wr * 16 + l15][(kk * 4 + lhi) * 8];
      short8 b = *(const short8*)&Bs[wc * 16 + l15][(kk * 4 + lhi) * 8];
      acc = __builtin_amdgcn_mfma_f32_16x16x32_bf16(a, b, acc, 0, 0, 0);
    }
  }
#undef SLOAD
  int rrow = n0 + wr * 16 + lhi * 4;
  int ccol = m0 + wc * 16 + l15;
  if (ccol < N) {
#pragma unroll
    for (int rr = 0; rr < 4; ++rr)
      if (rrow + rr < N) atomicAdd(&scores[soff + (rrow + rr) * N + ccol], acc[rr]);
  }
}

// ---------------- scores sc2/sc3: 128x128 tiles, K-split 2048 ----------------
__global__ __launch_bounds__(256) void k_scores_big(const unsigned short* __restrict__ qkv,
                                                    float* __restrict__ scores) {
  __shared__ __align__(16) unsigned short As[128][64];
  __shared__ __align__(16) unsigned short Bs[128][64];
  int flat = blockIdx.x;
  int lg = (flat & 7) * 20 + (flat >> 3);
  int sc, tn, tm, z, soff;
  if (lg < 32) { sc = 2; tn = 0; tm = 0; z = lg; soff = 1088; }
  else { int r = lg - 32; int tl = r >> 3; sc = 3; tn = tl >> 2; tm = tl & 3; z = r & 7; soff = 17472; }
  int N = 8 << (2 * sc);
  int lw = 7 - sc, W = 1 << lw, lS = 14 - 2 * sc;
  int n0 = tn * 128, m0 = tm * 128;
  int kbase = z * 2048;
  int tid = threadIdx.x;
  int w = tid >> 6, l = tid & 63;
  int wr = w >> 1, wc = w & 1;
  int l15 = l & 15, lhi = l >> 4;
  int sr = tid >> 1, sbase = (tid & 1) * 4, r7 = sr & 7;
  int ptA, spA, ptB, spB;
  patch_row(n0 + sr, sc, lw, ptA, spA);
  patch_row(m0 + sr, sc, lw, ptB, spB);
  int baseA = (ptA * 768 + sc * 64) * 65536 + spA;
  int baseB = (ptB * 768 + 256 + sc * 64) * 65536 + spB;
  floatx4 zf = {0.f, 0.f, 0.f, 0.f};
  floatx4 acc[4][4];
#pragma unroll
  for (int i = 0; i < 4; ++i)
#pragma unroll
    for (int j = 0; j < 4; ++j) acc[i][j] = zf;
  uintx4 ra[4], rb[4];
#define GLOAD(K0) { \
  _Pragma("unroll") for (int j = 0; j < 4; ++j) { \
    int k = kbase + (K0) + (sbase + j) * 8; \
    int cl = k >> lS; int s = k & ((1 << lS) - 1); \
    int hh = s >> lw, ww = s & (W - 1); \
    int off = cl * 65536 + (hh << 8) + ww; \
    ra[j] = *(const uintx4*)(qkv + baseA + off); \
    rb[j] = *(const uintx4*)(qkv + baseB + off); } }
  GLOAD(0);
  for (int st = 0; st < 32; ++st) {
    __syncthreads();
#pragma unroll
    for (int j = 0; j < 4; ++j) {
      *(uintx4*)&As[sr][((sbase + j) ^ r7) * 8] = ra[j];
      *(uintx4*)&Bs[sr][((sbase + j) ^ r7) * 8] = rb[j];
    }
    __syncthreads();
    if (st < 31) GLOAD((st + 1) * 64);
#pragma unroll
    for (int kk = 0; kk < 2; ++kk) {
      short8 af[4], bfr[4];
#pragma unroll
      for (int f = 0; f < 4; ++f) {
        int arow = wr * 64 + f * 16 + l15;
        af[f] = *(const short8*)&As[arow][(((kk << 2) + lhi) ^ (arow & 7)) * 8];
        int brow = wc * 64 + f * 16 + l15;
        bfr[f] = *(const short8*)&Bs[brow][(((kk << 2) + lhi) ^ (brow & 7)) * 8];
      }
#pragma unroll
      for (int fm = 0; fm < 4; ++fm)
#pragma unroll
        for (int fn = 0; fn < 4; ++fn)
          acc[fm][fn] = __builtin_amdgcn_mfma_f32_16x16x32_bf16(af[fm], bfr[fn], acc[fm][fn], 0, 0, 0);
    }
  }
#undef GLOAD
#pragma unroll
  for (int fm = 0; fm < 4; ++fm) {
    int nrow = n0 + wr * 64 + fm * 16 + lhi * 4;
#pragma unroll
    for (int rr = 0; rr < 4; ++rr) {
#pragma unroll
      for (int fn = 0; fn < 4; ++fn) {
        int mcol = m0 + wc * 64 + fn * 16 + l15;
        atomicAdd(&scores[soff + (nrow + rr) * N + mcol], acc[fm][fn][rr]);
      }
    }
  }
}

// ---------------- logits + softmax -> P bf16 ----------------
__global__ void k_softmax(const float* __restrict__ scores, const float* __restrict__ G,
                          const float* __restrict__ rbuf, const float* __restrict__ msc,
                          unsigned short* __restrict__ pbuf) {
  int row = blockIdx.x, lane = threadIdx.x;
  int sc, n, roff, soff, poff;
  if (row < 8)        { sc = 0; n = row;       roff = 0;   soff = 0;     poff = 0; }
  else if (row < 40)  { sc = 1; n = row - 8;   roff = 8;   soff = 64;    poff = 512; }
  else if (row < 168) { sc = 2; n = row - 40;  roff = 40;  soff = 1088;  poff = 1536; }
  else                { sc = 3; n = row - 168; roff = 168; soff = 17472; poff = 17920; }
  int N = 8 << (2 * sc);
  int Kpad = (sc < 2) ? 32 : N;
  float Sf = (float)(1 << (14 - 2 * sc));
  float invD = 1.0f / (float)(1 << (20 - 2 * sc));
  float alpha = msc[sc * 4 + 0], beta = msc[sc * 4 + 1];
  float gamma = msc[sc * 4 + 2], delta = msc[sc * 4 + 3];
  float rn = rbuf[roff + n];
  float vals[8];
  float mx = -1e30f;
#pragma unroll
  for (int j = 0; j < 8; ++j) {
    float v = -1e30f;
    int mcol = lane + j * 64;
    if (j * 64 < N && mcol < N) {
      float sq = scores[soff + n * N + mcol];
      float g = G[soff + n * N + mcol];
      float rm = rbuf[roff + mcol];
      v = sq * (alpha * g + beta * rn + gamma * rm + delta * Sf) * invD;
    }
    vals[j] = v;
    mx = fmaxf(mx, v);
  }
  for (int off = 32; off; off >>= 1) mx = fmaxf(mx, __shfl_xor(mx, off));
  float sum = 0.f;
#pragma unroll
  for (int j = 0; j < 8; ++j) {
    int mcol = lane + j * 64;
    float e = 0.f;
    if (j * 64 < N && mcol < N) e = __expf(vals[j] - mx);
    vals[j] = e;
    sum += e;
  }
  for (int off = 32; off; off >>= 1) sum += __shfl_xor(sum, off);
  float inv = 1.f / sum;
#pragma unroll
  for (int j = 0; j < 8; ++j) {
    int mcol = lane + j * 64;
    if (j * 64 < N && mcol < N) pbuf[poff + n * Kpad + mcol] = f2bf(vals[j] * inv);
  }
}

// ---------------- PV GEMM: double-buffered LDS, 1 barrier/K-step (R6) ----------------
__global__ __launch_bounds__(256) void k_pv(const unsigned short* __restrict__ qkv,
                                            const unsigned short* __restrict__ pbuf,
                                            unsigned short* __restrict__ ynat) {
  int bid = blockIdx.x;
  int sc, bx, by;
  if (bid < 4096)      { sc = 0; bx = bid; by = 0; }
  else if (bid < 6144) { sc = 1; bx = bid - 4096; by = 0; }
  else if (bid < 8192) { int r = bid - 6144; sc = 2; bx = r >> 1; by = r & 1; }
  else                 { int r = bid - 8192; sc = 3; bx = r >> 3; by = r & 7; }
  int WR    = (sc == 0) ? 1 : (sc == 1) ? 2 : 4;
  int logWC = (sc == 0) ? 2 : (sc == 1) ? 1 : 0;
  int poff  = (sc == 0) ? 0 : (sc == 1) ? 512 : (sc == 2) ? 1536 : 17920;
  int lw = 7 - sc, W = 1 << lw;
  int lS = 14 - 2 * sc;
  int N = 8 << (2 * sc);
  int Kpad = (sc < 2) ? 32 : N;
  int WC = 1 << logWC;
  int d0 = bx * (WC * 64);
  int nb = by * (WR * 16);
  __shared__ __align__(16) unsigned short As[2][64][40];
  __shared__ __align__(16) unsigned short Bt[2][256][32];
  int tid = threadIdx.x;
  int w = tid >> 6, l = tid & 63;
  int wr = w >> logWC, wc = w & (WC - 1);
  int l15 = l & 15, lhi = l >> 4;
  floatx4 zf = {0.f, 0.f, 0.f, 0.f};
  floatx4 acc[4];
#pragma unroll
  for (int i = 0; i < 4; ++i) acc[i] = zf;
  int bmp = tid & 15;
  int dg = tid >> 4;
  bool act0 = (WC > 1) || (dg < 8);
  bool has1 = (WC == 4);
  bool doA = tid < WR * 64;
  int arow = tid >> 2, akg = (tid & 3) * 8;
  int ksteps = Kpad >> 5;
  uintx4 zu = {0u, 0u, 0u, 0u};
  int vcb = (512 + sc * 64) * 65536;
  uintx4 av = zu, lo0 = zu, hi0 = zu, lo1 = zu, hi1 = zu;
#define PLOADS(KS) { int k0 = (KS) * 32; \
    av = zu; lo0 = zu; hi0 = zu; lo1 = zu; hi1 = zu; \
    if (doA) av = *(const uintx4*)(pbuf + poff + (nb + arow) * Kpad + k0 + akg); \
    int gm0 = k0 + 2 * bmp, gm1 = gm0 + 1; \
    bool mv0 = gm0 < N, mv1 = gm1 < N; \
    int pt0 = 0, sp00 = 0, pt1 = 0, sp01 = 0; \
    if (mv0) patch_row(gm0, sc, lw, pt0, sp00); \
    if (mv1) patch_row(gm1, sc, lw, pt1, sp01); \
    { int d = d0 + dg * 8; int cl = d >> lS; int s = d & ((1 << lS) - 1); \
      int hh = s >> lw, ww = s & (W - 1); int sp = (hh << 8) + ww; \
      if (act0 && mv0) lo0 = *(const uintx4*)(qkv + pt0 * 768 * 65536 + vcb + cl * 65536 + sp00 + sp); \
      if (act0 && mv1) hi0 = *(const uintx4*)(qkv + pt1 * 768 * 65536 + vcb + cl * 65536 + sp01 + sp); } \
    if (has1) { int d = d0 + (dg + 16) * 8; int cl = d >> lS; int s = d & ((1 << lS) - 1); \
      int hh = s >> lw, ww = s & (W - 1); int sp = (hh << 8) + ww; \
      if (mv0) lo1 = *(const uintx4*)(qkv + pt0 * 768 * 65536 + vcb + cl * 65536 + sp00 + sp); \
      if (mv1) hi1 = *(const uintx4*)(qkv + pt1 * 768 * 65536 + vcb + cl * 65536 + sp01 + sp); } }
  PLOADS(0);
  for (int ks = 0; ks < ksteps; ++ks) {
    int b = ks & 1;
    if (doA) *(uintx4*)&As[b][arow][akg] = av;
    if (act0) {
      int du = dg * 8;
#pragma unroll
      for (int j = 0; j < 8; ++j) {
        int d = du + j;
        unsigned losh = (lo0[j >> 1] >> ((j & 1) * 16)) & 0xFFFFu;
        unsigned hish = (hi0[j >> 1] >> ((j & 1) * 16)) & 0xFFFFu;
        unsigned wv = losh | (hish << 16);
        int slot = (bmp >> 2) ^ ((d >> 1) & 3) ^ ((d >> 3) & 3);
        ((unsigned int*)&Bt[b][d][0])[slot * 4 + (bmp & 3)] = wv;
      }
    }
    if (has1) {
      int du = (dg + 16) * 8;
#pragma unroll
      for (int j = 0; j < 8; ++j) {
        int d = du + j;
        unsigned losh = (lo1[j >> 1] >> ((j & 1) * 16)) & 0xFFFFu;
        unsigned hish = (hi1[j >> 1] >> ((j & 1) * 16)) & 0xFFFFu;
        unsigned wv = losh | (hish << 16);
        int slot = (bmp >> 2) ^ ((d >> 1) & 3) ^ ((d >> 3) & 3);
        ((unsigned int*)&Bt[b][d][0])[slot * 4 + (bmp & 3)] = wv;
      }
    }
    __syncthreads();
    if (ks + 1 < ksteps) PLOADS(ks + 1);
    short8 a = *(const short8*)&As[b][wr * 16 + l15][lhi * 8];
#pragma unroll
    for (int fn = 0; fn < 4; ++fn) {
      int row = wc * 64 + fn * 16 + l15;
      int slot = lhi ^ ((row >> 1) & 3) ^ ((row >> 3) & 3);
      short8 bb = *(const short8*)&Bt[b][row][slot * 8];
      acc[fn] = __builtin_amdgcn_mfma_f32_16x16x32_bf16(a, bb, acc[fn], 0, 0, 0);
    }
  }
#undef PLOADS
  int nrow = nb + wr * 16 + lhi * 4;
#pragma unroll
  for (int rr = 0; rr < 4; ++rr) {
    int n = nrow + rr;
    if (n < N) {
      int pt, sp0;
      patch_row(n, sc, lw, pt, sp0);
#pragma unroll
      for (int fn = 0; fn < 4; ++fn) {
        int d = d0 + wc * 64 + fn * 16 + l15;
        int cl = d >> lS;
        int s = d & ((1 << lS) - 1);
        int hh = s >> lw, ww = s & (W - 1);
        int c = sc * 64 + cl;
        ynat[(pt * 256 + c) * 65536 + sp0 + (hh << 8) + ww] = f2bf(acc[fn][rr]);
      }
    }
  }
}

// ---------------- conv3x3: m201-style GEMM, 256x256 tile, gload_lds dbuf ----------------
// M=256(o) x N=131072(p2) x K=2304 (tap-major; BK=64 => one tap per K-tile).
// 512 thr / 8 waves (2x4); per-wave 128x64 out (acc[8][4]).
// LDS 128KB: A[2][256][64], B[2][256][64]; staged via global_load_lds(16B)
// with pre-swizzled source (dest linear, slot = j ^ (row&7)); one
// __syncthreads per K-tile (drains loads issued a full tile earlier).
__global__ __launch_bounds__(512, 1) void k_conv(const unsigned short* __restrict__ yt,
                                                 const unsigned short* __restrict__ wo3,
                                                 const float* __restrict__ bo,
                                                 float* __restrict__ out) {
  __shared__ __align__(16) unsigned short Asm[2][256][64];
  __shared__ __align__(16) unsigned short Bsm[2][256][64];
  int flat = blockIdx.x;                      // 512 blocks
  int lg = (flat & 7) * 64 + (flat >> 3);     // bijective XCD chunking (8x64)
  int tt = lg >> 8, yy = lg & 255;            // n-tile = one image row
  int tid = threadIdx.x;
  int w = tid >> 6, l = tid & 63;
  int wr = w >> 2, wc = w & 3;
  int l15 = l & 15, lhi = l >> 4;
  int wb16 = tid & 448;                       // wave base in 16B units (w*64)
  const unsigned short* ybase = yt + (tt << 24);
  floatx4 zf = {0.f, 0.f, 0.f, 0.f};
  floatx4 acc[8][4];
#pragma unroll
  for (int i = 0; i < 8; ++i)
#pragma unroll
    for (int j = 0; j < 4; ++j) acc[i][j] = zf;
  uintx4 zu = {0u, 0u, 0u, 0u};

#define STGA(BUF, H, K0) { \
  _Pragma("unroll") for (int i = 0; i < 2; ++i) { \
    int idx = i * 512 + tid; int r_ = idx >> 3, sl_ = idx & 7; \
    const unsigned short* gp = wo3 + ((H) * 128 + r_) * 2304 + (K0) + ((sl_ ^ (r_ & 7)) << 3); \
    unsigned short* lp = &Asm[BUF][0][0] + ((H) * 1024 + i * 512 + wb16) * 8; \
    __builtin_amdgcn_global_load_lds((const unsigned int*)gp, (unsigned int*)lp, 16, 0, 0); \
  } }
#define STGB(BUF, H, YQ, DX, CH0) { \
  _Pragma("unroll") for (int i = 0; i < 2; ++i) { \
    int idx = i * 512 + tid; int r_ = idx >> 3, sl_ = idx & 7; \
    int p_ = (H) * 128 + r_; int xq_ = p_ + (DX) - 1; \
    bool oob = (((unsigned)(YQ)) >= 256u) || (((unsigned)xq_) >= 256u); \
    const unsigned short* gp = ybase + ((((YQ) << 8) + xq_) << 8) + (CH0) + ((sl_ ^ (r_ & 7)) << 3); \
    unsigned short* lp = &Bsm[BUF][0][0] + ((H) * 1024 + i * 512 + wb16) * 8; \
    if (!oob) __builtin_amdgcn_global_load_lds((const unsigned int*)gp, (unsigned int*)lp, 16, 0, 0); \
    if (oob) *(uintx4*)(&Bsm[BUF][0][0] + ((H) * 1024 + idx) * 8) = zu; \
  } }

  // prologue: stage tile 0 (tap 0: dy=0 -> yq=yy-1, dx=0, ch0=0)
  STGA(0, 0, 0); STGA(0, 1, 0);
  { int yq0 = yy - 1; STGB(0, 0, yq0, 0, 0); STGB(0, 1, yq0, 0, 0); }
  __syncthreads();

  for (int t = 0; t < 36; ++t) {
    int cur = t & 1, nxt = cur ^ 1;
    int tn = t + 1;
    int k0n = tn << 6;
    int tapn = tn >> 2;
    int dyn = (tapn * 11) >> 5;
    int dxn = tapn - dyn * 3;
    int ch0n = (tn & 3) << 6;
    int yqn = yy + dyn - 1;
    bool st = (t < 35);
    // B fragments for this tile (held through all 4 phases)
    short8 bf[8];
#pragma unroll
    for (int fn = 0; fn < 4; ++fn)
#pragma unroll
      for (int kk = 0; kk < 2; ++kk) {
        int row = wc * 64 + fn * 16 + l15;
        bf[fn * 2 + kk] = *(const short8*)&Bsm[cur][row][(((kk << 2) + lhi) ^ (row & 7)) * 8];
      }
#pragma unroll
    for (int q = 0; q < 4; ++q) {
      // stage one half of tile t+1 (A halves first, then B halves)
      if (st) {
        if (q == 0)      { STGA(nxt, 0, k0n); }
        else if (q == 1) { STGA(nxt, 1, k0n); }
        else if (q == 2) { STGB(nxt, 0, yqn, dxn, ch0n); }
        else             { STGB(nxt, 1, yqn, dxn, ch0n); }
      }
      short8 af[2][2];
#pragma unroll
      for (int f2 = 0; f2 < 2; ++f2)
#pragma unroll
        for (int kk = 0; kk < 2; ++kk) {
          int row = wr * 128 + (q * 2 + f2) * 16 + l15;
          af[f2][kk] = *(const short8*)&Asm[cur][row][(((kk << 2) + lhi) ^ (row & 7)) * 8];
        }
      __builtin_amdgcn_s_setprio(1);
#pragma unroll
      for (int f2 = 0; f2 < 2; ++f2)
#pragma unroll
        for (int fn = 0; fn < 4; ++fn)
#pragma unroll
          for (int kk = 0; kk < 2; ++kk)
            acc[q * 2 + f2][fn] = __builtin_amdgcn_mfma_f32_16x16x32_bf16(
                af[f2][kk], bf[fn * 2 + kk], acc[q * 2 + f2][fn], 0, 0, 0);
      __builtin_amdgcn_s_setprio(0);
    }
    __syncthreads();   // drains vm (tile t+1 loads, issued 1-4 phases ago) + lgkm
  }
#undef STGA
#undef STGB
#pragma unroll
  for (int fm = 0; fm < 8; ++fm) {
    int o = wr * 128 + fm * 16 + lhi * 4;
#pragma unroll
    for (int rr = 0; rr < 4; ++rr) {
      float bias = bo[o + rr];
#pragma unroll
      for (int fn = 0; fn < 4; ++fn) {
        int xcol = wc * 64 + fn * 16 + l15;
        float z = acc[fm][fn][rr] + bias;
        out[((tt * 256 + o + rr) << 16) + (yy << 8) + xcol] = z > 0.f ? z : 0.2f * z;
      }
    }
  }
}

// ---------------------------------------------------------------------------
extern "C" void kernel_launch(void* const* d_in, const int* in_sizes, int n_in,
                              void* d_out, int out_size, void* d_ws, size_t ws_size,
                              hipStream_t stream) {
  const float* x   = (const float*)d_in[0];
  const float* m   = (const float*)d_in[1];
  const float* Wq  = (const float*)d_in[2];
  const float* bq  = (const float*)d_in[3];
  const float* Wk  = (const float*)d_in[4];
  const float* bk  = (const float*)d_in[5];
  const float* Wv  = (const float*)d_in[6];
  const float* bv  = (const float*)d_in[7];
  const float* Wmq = (const float*)d_in[8];
  const float* bmq = (const float*)d_in[9];
  const float* Wmk = (const float*)d_in[10];
  const float* bmk = (const float*)d_in[11];
  const float* Wo  = (const float*)d_in[12];
  const float* bo  = (const float*)d_in[13];

  char* ws = (char*)d_ws;
  unsigned short* qkv   = (unsigned short*)(ws);
  unsigned short* xtb   = (unsigned short*)(ws + 201326592);  // xt, later yt
  unsigned short* wqkv  = (unsigned short*)(ws + 268435456);
  unsigned short* wo3   = (unsigned short*)(ws + 268828672);
  float* bias           = (float*)(ws + 270008320);
  float* msc            = (float*)(ws + 270011392);
  float* scores         = (float*)(ws + 270011456);
  float* G              = (float*)(ws + 271129920);
  float* rbuf           = (float*)(ws + 272248384);
  unsigned short* pbuf  = (unsigned short*)(ws + 272251104);
  float* out            = (float*)d_out;
  unsigned short* ynat  = (unsigned short*)d_out;  // low half of d_out as bf16 scratch

  k_prep_w<<<dim3(769), dim3(256), 0, stream>>>(Wq, Wk, Wv, bq, bk, bv, Wmq, bmq, Wmk, bmk,
                                                wqkv, bias, msc);
  k_prep_wo<<<dim3(4489), dim3(256), 0, stream>>>(Wo, wo3, scores, (unsigned int*)pbuf);
  k_xt<<<dim3(1024, 4, 2), dim3(256), 0, stream>>>(x, xtb);
  k_qkv<<<dim3(3072), dim3(256), 0, stream>>>(xtb, wqkv, bias, qkv);
  k_gram2<<<dim3(328), dim3(256), 0, stream>>>(m, G);
  k_rsum<<<dim3(680), dim3(64), 0, stream>>>(m, rbuf);
  k_scores2<<<dim3(320), dim3(256), 0, stream>>>(qkv, scores);
  k_scores_big<<<dim3(160), dim3(256), 0, stream>>>(qkv, scores);
  k_softmax<<<dim3(680), dim3(64), 0, stream>>>(scores, G, rbuf, msc, pbuf);
  k_pv<<<dim3(10240), dim3(256), 0, stream>>>(qkv, pbuf, ynat);
  k_yt<<<dim3(1024, 4, 2), dim3(256), 0, stream>>>(ynat, xtb);
  k_conv<<<dim3(512), dim3(512), 0, stream>>>(xtb, wo3, bo, out);
}

// Round 9
// 583.659 us; speedup vs baseline: 1.2105x; 1.0528x over previous
//
#include <hip/hip_runtime.h>
#include <stdint.h>

// ---------------------------------------------------------------------------
// MultiHeadedAttention (4-scale patch attention) for MI355X / gfx950
// R9: conv + prep_wo reverted to R6 (R4 halo conv, 187us known-good).
//     k_qkv epilogue: LDS-staged C transpose -> 16 coalesced 16B stores per
//     thread (was 128 scalar 2B stores). Dynamic smem 48KB carved As/Bs/Cs.
// ---------------------------------------------------------------------------

typedef __attribute__((ext_vector_type(8))) short short8;
typedef __attribute__((ext_vector_type(4))) float floatx4;
typedef __attribute__((ext_vector_type(4))) unsigned int uintx4;

#define DEV static __device__ __forceinline__

DEV unsigned short f2bf(float f) {
  unsigned u = __builtin_bit_cast(unsigned, f);
  unsigned r = u + 0x7FFFu + ((u >> 16) & 1u);
  return (unsigned short)(r >> 16);
}

DEV void patch_row(int n, int sc, int lw, int& pt, int& sp0) {
  pt = n >> (2 + 2 * sc);
  int rem = n & ((4 << (2 * sc)) - 1);
  int oh = rem >> (1 + sc), ow = rem & ((2 << sc) - 1);
  sp0 = (oh << (lw + 8)) + (ow << lw);
}

// ---------------- prep kernels ----------------
__global__ void k_prep_w(const float* __restrict__ Wq, const float* __restrict__ Wk,
                         const float* __restrict__ Wv, const float* __restrict__ bq,
                         const float* __restrict__ bk, const float* __restrict__ bv,
                         const float* __restrict__ Wmq, const float* __restrict__ bmq,
                         const float* __restrict__ Wmk, const float* __restrict__ bmk,
                         unsigned short* __restrict__ wqkv, float* __restrict__ bias,
                         float* __restrict__ msc) {
  int b = blockIdx.x;
  int t = threadIdx.x;
  if (b < 768) {
    const float* src = b < 256 ? (Wq + b * 256) : (b < 512 ? (Wk + (b - 256) * 256)
                                                           : (Wv + (b - 512) * 256));
    wqkv[b * 256 + t] = f2bf(src[t]);
    if (t == 0) bias[b] = b < 256 ? bq[b] : (b < 512 ? bk[b - 256] : bv[b - 512]);
  } else {
    int sc = t >> 6, lane = t & 63;
    int ch = sc * 64 + lane;
    float a0 = Wmq[ch] * Wmk[ch];
    float a1 = Wmq[ch] * bmk[ch];
    float a2 = bmq[ch] * Wmk[ch];
    float a3 = bmq[ch] * bmk[ch];
    for (int off = 32; off; off >>= 1) {
      a0 += __shfl_xor(a0, off); a1 += __shfl_xor(a1, off);
      a2 += __shfl_xor(a2, off); a3 += __shfl_xor(a3, off);
    }
    if (lane == 0) {
      msc[sc * 4 + 0] = a0; msc[sc * 4 + 1] = a1;
      msc[sc * 4 + 2] = a2; msc[sc * 4 + 3] = a3;
    }
  }
}

// Wo repack + zero(scores||G, pbuf) merged
__global__ void k_prep_wo(const float* __restrict__ Wo, unsigned short* __restrict__ wobf,
                          float* __restrict__ scoresG, unsigned int* __restrict__ pbuf) {
  int blk = blockIdx.x;
  if (blk < 2304) {
    int didx = blk >> 8, o = blk & 255, c = threadIdx.x;
    wobf[didx * 65536 + o * 256 + c] = f2bf(Wo[o * 2304 + c * 9 + didx]);
  } else {
    int i = (blk - 2304) * 256 + threadIdx.x;
    if (i < 559232) scoresG[i] = 0.f;
    if (i < 140032) pbuf[i] = 0u;
  }
}

// ---------------- transpose kernels ----------------
__global__ __launch_bounds__(256) void k_xt(const float* __restrict__ x,
                                            unsigned short* __restrict__ xt) {
  __shared__ __align__(16) unsigned short tile[64][72];
  int p0 = blockIdx.x * 64, c0 = blockIdx.y * 64, t = blockIdx.z;
  int tid = threadIdx.x;
  {
    int cc = tid >> 2, pq = (tid & 3) * 16;
    const float* src = x + ((t * 256 + c0 + cc) * 65536 + p0 + pq);
    __align__(16) unsigned short tmp[16];
#pragma unroll
    for (int e = 0; e < 16; e += 4) {
      floatx4 v = *(const floatx4*)(src + e);
      tmp[e + 0] = f2bf(v[0]); tmp[e + 1] = f2bf(v[1]);
      tmp[e + 2] = f2bf(v[2]); tmp[e + 3] = f2bf(v[3]);
    }
    *(uintx4*)&tile[cc][pq] = *(const uintx4*)&tmp[0];
    *(uintx4*)&tile[cc][pq + 8] = *(const uintx4*)&tmp[8];
  }
  __syncthreads();
  {
    int pp = tid >> 2, cg = (tid & 3) * 16;
    __align__(16) unsigned short outv[16];
#pragma unroll
    for (int e = 0; e < 16; ++e) outv[e] = tile[cg + e][pp];
    unsigned short* dst = xt + ((t * 65536 + p0 + pp) * 256 + c0 + cg);
    *(uintx4*)dst = *(const uintx4*)&outv[0];
    *(uintx4*)(dst + 8) = *(const uintx4*)&outv[8];
  }
}

__global__ __launch_bounds__(256) void k_yt(const unsigned short* __restrict__ ynat,
                                            unsigned short* __restrict__ yt) {
  __shared__ __align__(16) unsigned short tile[64][72];
  int p0 = blockIdx.x * 64, c0 = blockIdx.y * 64, t = blockIdx.z;
  int tid = threadIdx.x;
  {
    int cc = tid >> 2, pq = (tid & 3) * 16;
    const unsigned short* src = ynat + ((t * 256 + c0 + cc) * 65536 + p0 + pq);
    *(uintx4*)&tile[cc][pq] = *(const uintx4*)src;
    *(uintx4*)&tile[cc][pq + 8] = *(const uintx4*)(src + 8);
  }
  __syncthreads();
  {
    int pp = tid >> 2, cg = (tid & 3) * 16;
    __align__(16) unsigned short outv[16];
#pragma unroll
    for (int e = 0; e < 16; ++e) outv[e] = tile[cg + e][pp];
    unsigned short* dst = yt + ((t * 65536 + p0 + pp) * 256 + c0 + cg);
    *(uintx4*)dst = *(const uintx4*)&outv[0];
    *(uintx4*)(dst + 8) = *(const uintx4*)&outv[8];
  }
}

// ---------------- QKV GEMM: 128x256 tile + LDS-transposed coalesced epilogue ----------------
__global__ __launch_bounds__(256, 2) void k_qkv(const unsigned short* __restrict__ xt,
                                                const unsigned short* __restrict__ wqkv,
                                                const float* __restrict__ bias,
                                                unsigned short* __restrict__ qkv) {
  extern __shared__ __align__(16) char smem[];
  auto As = (unsigned short (*)[64])(smem);            // [128][64]  16KB
  auto Bs = (unsigned short (*)[64])(smem + 16384);    // [256][64]  32KB
  auto Cs = (unsigned short (*)[280])(smem);           // [64][280]  35KB (overlay)
  int flat = blockIdx.x;
  int lg = (flat & 7) * 384 + (flat >> 3);
  int n_t = lg / 6, m_t = lg - n_t * 6;
  int n0 = n_t << 8, m0 = m_t << 7;
  int tid = threadIdx.x;
  int w = tid >> 6, l = tid & 63;
  int wr = w >> 1, wc = w & 1;
  int l15 = l & 15, lhi = l >> 4;
  int sr = tid >> 1, sbase = (tid & 1) * 4, r7 = sr & 7;
  int b7 = tid & 7;
  const unsigned short* gA = wqkv + (m0 + sr) * 256 + sbase * 8;
  const unsigned short* gB = xt + (n0 + tid) * 256;
  floatx4 zf = {0.f, 0.f, 0.f, 0.f};
  floatx4 acc[4][8];
#pragma unroll
  for (int i = 0; i < 4; ++i)
#pragma unroll
    for (int j = 0; j < 8; ++j) acc[i][j] = zf;
  uintx4 ra[4], rb[8];
#define QLOAD(K0) { const uintx4* pa = (const uintx4*)(gA + (K0)); \
                    ra[0] = pa[0]; ra[1] = pa[1]; ra[2] = pa[2]; ra[3] = pa[3]; \
                    const uintx4* pb = (const uintx4*)(gB + (K0)); \
                    rb[0] = pb[0]; rb[1] = pb[1]; rb[2] = pb[2]; rb[3] = pb[3]; \
                    rb[4] = pb[4]; rb[5] = pb[5]; rb[6] = pb[6]; rb[7] = pb[7]; }
  QLOAD(0);
#pragma unroll
  for (int ch = 0; ch < 4; ++ch) {
    __syncthreads();
#pragma unroll
    for (int j = 0; j < 4; ++j)
      *(uintx4*)&As[sr][((sbase + j) ^ r7) * 8] = ra[j];
#pragma unroll
    for (int j = 0; j < 8; ++j)
      *(uintx4*)&Bs[tid][(j ^ b7) * 8] = rb[j];
    __syncthreads();
    if (ch < 3) QLOAD((ch + 1) * 64);
#pragma unroll
    for (int kk = 0; kk < 2; ++kk) {
      short8 af[4];
#pragma unroll
      for (int f = 0; f < 4; ++f) {
        int arow = wr * 64 + f * 16 + l15;
        af[f] = *(const short8*)&As[arow][(((kk << 2) + lhi) ^ (arow & 7)) * 8];
      }
#pragma unroll
      for (int fn = 0; fn < 8; ++fn) {
        int brow = wc * 128 + fn * 16 + l15;
        short8 b = *(const short8*)&Bs[brow][(((kk << 2) + lhi) ^ (brow & 7)) * 8];
#pragma unroll
        for (int fm = 0; fm < 4; ++fm)
          acc[fm][fn] = __builtin_amdgcn_mfma_f32_16x16x32_bf16(af[fm], b, acc[fm][fn], 0, 0, 0);
      }
    }
  }
#undef QLOAD
  // Epilogue: two 64-row halves through LDS, then fully-coalesced 16B stores.
#pragma unroll
  for (int h = 0; h < 2; ++h) {
    __syncthreads();
    if (wr == h) {
#pragma unroll
      for (int fm = 0; fm < 4; ++fm) {
#pragma unroll
        for (int rr = 0; rr < 4; ++rr) {
          int rl = fm * 16 + lhi * 4 + rr;
          float bv = bias[m0 + h * 64 + rl];
#pragma unroll
          for (int fn = 0; fn < 8; ++fn)
            Cs[rl][wc * 128 + fn * 16 + l15] = f2bf(acc[fm][fn][rr] + bv);
        }
      }
    }
    __syncthreads();
    {
      int p8 = (tid & 31) * 8;
      int pcol = n0 + p8;
      int t = pcol >> 16, p = pcol & 65535;
#pragma unroll
      for (int pass = 0; pass < 8; ++pass) {
        int rl = (tid >> 5) + pass * 8;
        uintx4 v = *(const uintx4*)&Cs[rl][p8];
        *(uintx4*)&qkv[((t * 768 + m0 + h * 64 + rl) << 16) + p] = v;
      }
    }
  }
}

// ---------------- mask gram: LDS-tiled fp32, 32x32 pair tiles ----------------
__global__ __launch_bounds__(256) void k_gram2(const float* __restrict__ m,
                                               float* __restrict__ G) {
  __shared__ __align__(16) float Ns[32][68];
  __shared__ __align__(16) float Ms[32][68];
  int bid = blockIdx.x;
  int sc, tn, tm, z, nchunks, soff;
  if (bid < 32)      { sc = 0; tn = 0; tm = 0; z = bid;      nchunks = 8; soff = 0; }
  else if (bid < 40) { sc = 1; tn = 0; tm = 0; z = bid - 32; nchunks = 8; soff = 64; }
  else if (bid < 72) { int r = bid - 40; int tl = r >> 1; sc = 2; tn = tl >> 2; tm = tl & 3; z = r & 1; nchunks = 8; soff = 1088; }
  else               { int tl = bid - 72; sc = 3; tn = tl >> 4; tm = tl & 15; z = 0; nchunks = 4; soff = 17472; }
  int lw = 7 - sc, W = 1 << lw, N = 8 << (2 * sc);
  int kbase = z * nchunks * 64;
  int n0 = tn * 32, m0 = tm * 32;
  int tid = threadIdx.x;
  bool isA = tid < 128;
  int u = tid & 127;
  int srow = u >> 2, sslot0 = (u & 3) * 4;
  int grow = (isA ? n0 : m0) + srow;
  bool valid = grow < N;
  int pt = 0, sp0 = 0;
  if (valid) patch_row(grow, sc, lw, pt, sp0);
  int gbase = pt * 65536 + sp0;
  int trc = tid >> 4, tcc = tid & 15;
  float a00 = 0.f, a01 = 0.f, a10 = 0.f, a11 = 0.f;
  floatx4 zf = {0.f, 0.f, 0.f, 0.f};
  for (int c = 0; c < nchunks; ++c) {
    int k0 = kbase + c * 64;
    floatx4 v[4];
#pragma unroll
    for (int j = 0; j < 4; ++j) {
      v[j] = zf;
      if (valid) {
        int s = k0 + (sslot0 + j) * 4;
        int hh = s >> lw, ww = s & (W - 1);
        v[j] = *(const floatx4*)(m + gbase + (hh << 8) + ww);
      }
    }
    __syncthreads();
    float* dstrow = isA ? &Ns[srow][0] : &Ms[srow][0];
#pragma unroll
    for (int j = 0; j < 4; ++j) *(floatx4*)&dstrow[(sslot0 + j) * 4] = v[j];
    __syncthreads();
#pragma unroll 4
    for (int k = 0; k < 64; k += 4) {
      floatx4 na = *(const floatx4*)&Ns[2 * trc][k];
      floatx4 nb = *(const floatx4*)&Ns[2 * trc + 1][k];
      floatx4 ma = *(const floatx4*)&Ms[2 * tcc][k];
      floatx4 mb = *(const floatx4*)&Ms[2 * tcc + 1][k];
#pragma unroll
      for (int e = 0; e < 4; ++e) {
        a00 += na[e] * ma[e]; a01 += na[e] * mb[e];
        a10 += nb[e] * ma[e]; a11 += nb[e] * mb[e];
      }
    }
  }
  int rn = n0 + 2 * trc, rm = m0 + 2 * tcc;
  float res[2][2] = {{a00, a01}, {a10, a11}};
#pragma unroll
  for (int i = 0; i < 2; ++i)
#pragma unroll
    for (int j = 0; j < 2; ++j) {
      if (rn + i < N && rm + j < N) {
        float* dst = &G[soff + (rn + i) * N + rm + j];
        if (sc < 3) atomicAdd(dst, res[i][j]); else *dst = res[i][j];
      }
    }
}

__global__ void k_rsum(const float* __restrict__ m, float* __restrict__ rbuf) {
  int row = blockIdx.x, lane = threadIdx.x;
  int sc, n;
  if (row < 8)        { sc = 0; n = row; }
  else if (row < 40)  { sc = 1; n = row - 8; }
  else if (row < 168) { sc = 2; n = row - 40; }
  else                { sc = 3; n = row - 168; }
  int lw = 7 - sc, W = 1 << lw;
  int pt, sp0;
  patch_row(n, sc, lw, pt, sp0);
  int base = pt * 65536 + sp0;
  int S = 1 << (14 - 2 * sc);
  float acc = 0.f;
  for (int s = lane; s < S; s += 64) {
    int hh = s >> lw, ww = s & (W - 1);
    acc += m[base + (hh << 8) + ww];
  }
  for (int off = 32; off; off >>= 1) acc += __shfl_xor(acc, off);
  if (lane == 0) rbuf[row] = acc;
}

// ---------------- scores sc0/sc1: 32x32 tiles, K-chunk 128 ----------------
__global__ __launch_bounds__(256) void k_scores2(const unsigned short* __restrict__ qkv,
                                                 float* __restrict__ scores) {
  __shared__ __align__(16) unsigned short As[32][136];
  __shared__ __align__(16) unsigned short Bs[32][136];
  int bid = blockIdx.x;
  int sc, tn, tm, z, soff;
  if (bid < 256)      { sc = 0; tn = 0; tm = 0; z = bid;       soff = 0; }
  else                { sc = 1; tn = 0; tm = 0; z = bid - 256; soff = 64; }
  int lw = 7 - sc, W = 1 << lw, lS = 14 - 2 * sc, N = 8 << (2 * sc);
  int n0 = tn * 32, m0 = tm * 32;
  int kbase = z * 4096;
  int tid = threadIdx.x, w = tid >> 6, l = tid & 63;
  int wr = w >> 1, wc = w & 1, l15 = l & 15, lhi = l >> 4;
  floatx4 acc = {0.f, 0.f, 0.f, 0.f};
  bool isA = tid < 128;
  int u = tid & 127;
  int srow = u >> 2, sslot0 = (u & 3) * 4;
  int grow = (isA ? n0 : m0) + srow;
  int cb = (isA ? 0 : 256) + sc * 64;
  int pt = 0, sp0 = 0;
  bool valid = grow < N;
  if (valid) patch_row(grow, sc, lw, pt, sp0);
  int rowbase = (pt * 768 + cb) * 65536 + sp0;
  uintx4 zu = {0u, 0u, 0u, 0u};
  uintx4 r[4];
#define SLOAD(KS) { int kb2 = kbase + (KS) * 128; \
  _Pragma("unroll") for (int j = 0; j < 4; ++j) { \
    uintx4 v = zu; \
    if (valid) { int k = kb2 + (sslot0 + j) * 8; \
      int cl = k >> lS; int s = k & ((1 << lS) - 1); \
      int hh = s >> lw, ww = s & (W - 1); \
      v = *(const uintx4*)(qkv + rowbase + cl * 65536 + (hh << 8) + ww); } \
    r[j] = v; } }
  SLOAD(0);
  for (int ks = 0; ks < 32; ++ks) {
    __syncthreads();
    {
      unsigned short* dstrow = isA ? &As[srow][0] : &Bs[srow][0];
#pragma unroll
      for (int j = 0; j < 4; ++j) *(uintx4*)&dstrow[(sslot0 + j) * 8] = r[j];
    }
    __syncthreads();
    if (ks < 31) SLOAD(ks + 1);
#pragma unroll
    for (int kk = 0; kk < 4; ++kk) {
      short8 a = *(const short8*)&As[wr * 16 + l15][(kk * 4 + lhi) * 8];
      short8 b = *(const short8*)&Bs[wc * 16 + l15][(kk * 4 + lhi) * 8];
      acc = __builtin_amdgcn_mfma_f32_16x16x32_bf16(a, b, acc, 0, 0, 0);
    }
  }
#undef SLOAD
  int rrow = n0 + wr * 16 + lhi * 4;
  int ccol = m0 + wc * 16 + l15;
  if (ccol < N) {
#pragma unroll
    for (int rr = 0; rr < 4; ++rr)
      if (rrow + rr < N) atomicAdd(&scores[soff + (rrow + rr) * N + ccol], acc[rr]);
  }
}

// ---------------- scores sc2/sc3: 128x128 tiles, K-split 2048 ----------------
__global__ __launch_bounds__(256) void k_scores_big(const unsigned short* __restrict__ qkv,
                                                    float* __restrict__ scores) {
  __shared__ __align__(16) unsigned short As[128][64];
  __shared__ __align__(16) unsigned short Bs[128][64];
  int flat = blockIdx.x;
  int lg = (flat & 7) * 20 + (flat >> 3);
  int sc, tn, tm, z, soff;
  if (lg < 32) { sc = 2; tn = 0; tm = 0; z = lg; soff = 1088; }
  else { int r = lg - 32; int tl = r >> 3; sc = 3; tn = tl >> 2; tm = tl & 3; z = r & 7; soff = 17472; }
  int N = 8 << (2 * sc);
  int lw = 7 - sc, W = 1 << lw, lS = 14 - 2 * sc;
  int n0 = tn * 128, m0 = tm * 128;
  int kbase = z * 2048;
  int tid = threadIdx.x;
  int w = tid >> 6, l = tid & 63;
  int wr = w >> 1, wc = w & 1;
  int l15 = l & 15, lhi = l >> 4;
  int sr = tid >> 1, sbase = (tid & 1) * 4, r7 = sr & 7;
  int ptA, spA, ptB, spB;
  patch_row(n0 + sr, sc, lw, ptA, spA);
  patch_row(m0 + sr, sc, lw, ptB, spB);
  int baseA = (ptA * 768 + sc * 64) * 65536 + spA;
  int baseB = (ptB * 768 + 256 + sc * 64) * 65536 + spB;
  floatx4 zf = {0.f, 0.f, 0.f, 0.f};
  floatx4 acc[4][4];
#pragma unroll
  for (int i = 0; i < 4; ++i)
#pragma unroll
    for (int j = 0; j < 4; ++j) acc[i][j] = zf;
  uintx4 ra[4], rb[4];
#define GLOAD(K0) { \
  _Pragma("unroll") for (int j = 0; j < 4; ++j) { \
    int k = kbase + (K0) + (sbase + j) * 8; \
    int cl = k >> lS; int s = k & ((1 << lS) - 1); \
    int hh = s >> lw, ww = s & (W - 1); \
    int off = cl * 65536 + (hh << 8) + ww; \
    ra[j] = *(const uintx4*)(qkv + baseA + off); \
    rb[j] = *(const uintx4*)(qkv + baseB + off); } }
  GLOAD(0);
  for (int st = 0; st < 32; ++st) {
    __syncthreads();
#pragma unroll
    for (int j = 0; j < 4; ++j) {
      *(uintx4*)&As[sr][((sbase + j) ^ r7) * 8] = ra[j];
      *(uintx4*)&Bs[sr][((sbase + j) ^ r7) * 8] = rb[j];
    }
    __syncthreads();
    if (st < 31) GLOAD((st + 1) * 64);
#pragma unroll
    for (int kk = 0; kk < 2; ++kk) {
      short8 af[4], bfr[4];
#pragma unroll
      for (int f = 0; f < 4; ++f) {
        int arow = wr * 64 + f * 16 + l15;
        af[f] = *(const short8*)&As[arow][(((kk << 2) + lhi) ^ (arow & 7)) * 8];
        int brow = wc * 64 + f * 16 + l15;
        bfr[f] = *(const short8*)&Bs[brow][(((kk << 2) + lhi) ^ (brow & 7)) * 8];
      }
#pragma unroll
      for (int fm = 0; fm < 4; ++fm)
#pragma unroll
        for (int fn = 0; fn < 4; ++fn)
          acc[fm][fn] = __builtin_amdgcn_mfma_f32_16x16x32_bf16(af[fm], bfr[fn], acc[fm][fn], 0, 0, 0);
    }
  }
#undef GLOAD
#pragma unroll
  for (int fm = 0; fm < 4; ++fm) {
    int nrow = n0 + wr * 64 + fm * 16 + lhi * 4;
#pragma unroll
    for (int rr = 0; rr < 4; ++rr) {
#pragma unroll
      for (int fn = 0; fn < 4; ++fn) {
        int mcol = m0 + wc * 64 + fn * 16 + l15;
        atomicAdd(&scores[soff + (nrow + rr) * N + mcol], acc[fm][fn][rr]);
      }
    }
  }
}

// ---------------- logits + softmax -> P bf16 ----------------
__global__ void k_softmax(const float* __restrict__ scores, const float* __restrict__ G,
                          const float* __restrict__ rbuf, const float* __restrict__ msc,
                          unsigned short* __restrict__ pbuf) {
  int row = blockIdx.x, lane = threadIdx.x;
  int sc, n, roff, soff, poff;
  if (row < 8)        { sc = 0; n = row;       roff = 0;   soff = 0;     poff = 0; }
  else if (row < 40)  { sc = 1; n = row - 8;   roff = 8;   soff = 64;    poff = 512; }
  else if (row < 168) { sc = 2; n = row - 40;  roff = 40;  soff = 1088;  poff = 1536; }
  else                { sc = 3; n = row - 168; roff = 168; soff = 17472; poff = 17920; }
  int N = 8 << (2 * sc);
  int Kpad = (sc < 2) ? 32 : N;
  float Sf = (float)(1 << (14 - 2 * sc));
  float invD = 1.0f / (float)(1 << (20 - 2 * sc));
  float alpha = msc[sc * 4 + 0], beta = msc[sc * 4 + 1];
  float gamma = msc[sc * 4 + 2], delta = msc[sc * 4 + 3];
  float rn = rbuf[roff + n];
  float vals[8];
  float mx = -1e30f;
#pragma unroll
  for (int j = 0; j < 8; ++j) {
    float v = -1e30f;
    int mcol = lane + j * 64;
    if (j * 64 < N && mcol < N) {
      float sq = scores[soff + n * N + mcol];
      float g = G[soff + n * N + mcol];
      float rm = rbuf[roff + mcol];
      v = sq * (alpha * g + beta * rn + gamma * rm + delta * Sf) * invD;
    }
    vals[j] = v;
    mx = fmaxf(mx, v);
  }
  for (int off = 32; off; off >>= 1) mx = fmaxf(mx, __shfl_xor(mx, off));
  float sum = 0.f;
#pragma unroll
  for (int j = 0; j < 8; ++j) {
    int mcol = lane + j * 64;
    float e = 0.f;
    if (j * 64 < N && mcol < N) e = __expf(vals[j] - mx);
    vals[j] = e;
    sum += e;
  }
  for (int off = 32; off; off >>= 1) sum += __shfl_xor(sum, off);
  float inv = 1.f / sum;
#pragma unroll
  for (int j = 0; j < 8; ++j) {
    int mcol = lane + j * 64;
    if (j * 64 < N && mcol < N) pbuf[poff + n * Kpad + mcol] = f2bf(vals[j] * inv);
  }
}

// ---------------- PV GEMM: double-buffered LDS, 1 barrier/K-step (R6) ----------------
__global__ __launch_bounds__(256) void k_pv(const unsigned short* __restrict__ qkv,
                                            const unsigned short* __restrict__ pbuf,
                                            unsigned short* __restrict__ ynat) {
  int bid = blockIdx.x;
  int sc, bx, by;
  if (bid < 4096)      { sc = 0; bx = bid; by = 0; }
  else if (bid < 6144) { sc = 1; bx = bid - 4096; by = 0; }
  else if (bid < 8192) { int r = bid - 6144; sc = 2; bx = r >> 1; by = r & 1; }
  else                 { int r = bid - 8192; sc = 3; bx = r >> 3; by = r & 7; }
  int WR    = (sc == 0) ? 1 : (sc == 1) ? 2 : 4;
  int logWC = (sc == 0) ? 2 : (sc == 1) ? 1 : 0;
  int poff  = (sc == 0) ? 0 : (sc == 1) ? 512 : (sc == 2) ? 1536 : 17920;
  int lw = 7 - sc, W = 1 << lw;
  int lS = 14 - 2 * sc;
  int N = 8 << (2 * sc);
  int Kpad = (sc < 2) ? 32 : N;
  int WC = 1 << logWC;
  int d0 = bx * (WC * 64);
  int nb = by * (WR * 16);
  __shared__ __align__(16) unsigned short As[2][64][40];
  __shared__ __align__(16) unsigned short Bt[2][256][32];
  int tid = threadIdx.x;
  int w = tid >> 6, l = tid & 63;
  int wr = w >> logWC, wc = w & (WC - 1);
  int l15 = l & 15, lhi = l >> 4;
  floatx4 zf = {0.f, 0.f, 0.f, 0.f};
  floatx4 acc[4];
#pragma unroll
  for (int i = 0; i < 4; ++i) acc[i] = zf;
  int bmp = tid & 15;
  int dg = tid >> 4;
  bool act0 = (WC > 1) || (dg < 8);
  bool has1 = (WC == 4);
  bool doA = tid < WR * 64;
  int arow = tid >> 2, akg = (tid & 3) * 8;
  int ksteps = Kpad >> 5;
  uintx4 zu = {0u, 0u, 0u, 0u};
  int vcb = (512 + sc * 64) * 65536;
  uintx4 av = zu, lo0 = zu, hi0 = zu, lo1 = zu, hi1 = zu;
#define PLOADS(KS) { int k0 = (KS) * 32; \
    av = zu; lo0 = zu; hi0 = zu; lo1 = zu; hi1 = zu; \
    if (doA) av = *(const uintx4*)(pbuf + poff + (nb + arow) * Kpad + k0 + akg); \
    int gm0 = k0 + 2 * bmp, gm1 = gm0 + 1; \
    bool mv0 = gm0 < N, mv1 = gm1 < N; \
    int pt0 = 0, sp00 = 0, pt1 = 0, sp01 = 0; \
    if (mv0) patch_row(gm0, sc, lw, pt0, sp00); \
    if (mv1) patch_row(gm1, sc, lw, pt1, sp01); \
    { int d = d0 + dg * 8; int cl = d >> lS; int s = d & ((1 << lS) - 1); \
      int hh = s >> lw, ww = s & (W - 1); int sp = (hh << 8) + ww; \
      if (act0 && mv0) lo0 = *(const uintx4*)(qkv + pt0 * 768 * 65536 + vcb + cl * 65536 + sp00 + sp); \
      if (act0 && mv1) hi0 = *(const uintx4*)(qkv + pt1 * 768 * 65536 + vcb + cl * 65536 + sp01 + sp); } \
    if (has1) { int d = d0 + (dg + 16) * 8; int cl = d >> lS; int s = d & ((1 << lS) - 1); \
      int hh = s >> lw, ww = s & (W - 1); int sp = (hh << 8) + ww; \
      if (mv0) lo1 = *(const uintx4*)(qkv + pt0 * 768 * 65536 + vcb + cl * 65536 + sp00 + sp); \
      if (mv1) hi1 = *(const uintx4*)(qkv + pt1 * 768 * 65536 + vcb + cl * 65536 + sp01 + sp); } }
  PLOADS(0);
  for (int ks = 0; ks < ksteps; ++ks) {
    int b = ks & 1;
    if (doA) *(uintx4*)&As[b][arow][akg] = av;
    if (act0) {
      int du = dg * 8;
#pragma unroll
      for (int j = 0; j < 8; ++j) {
        int d = du + j;
        unsigned losh = (lo0[j >> 1] >> ((j & 1) * 16)) & 0xFFFFu;
        unsigned hish = (hi0[j >> 1] >> ((j & 1) * 16)) & 0xFFFFu;
        unsigned wv = losh | (hish << 16);
        int slot = (bmp >> 2) ^ ((d >> 1) & 3) ^ ((d >> 3) & 3);
        ((unsigned int*)&Bt[b][d][0])[slot * 4 + (bmp & 3)] = wv;
      }
    }
    if (has1) {
      int du = (dg + 16) * 8;
#pragma unroll
      for (int j = 0; j < 8; ++j) {
        int d = du + j;
        unsigned losh = (lo1[j >> 1] >> ((j & 1) * 16)) & 0xFFFFu;
        unsigned hish = (hi1[j >> 1] >> ((j & 1) * 16)) & 0xFFFFu;
        unsigned wv = losh | (hish << 16);
        int slot = (bmp >> 2) ^ ((d >> 1) & 3) ^ ((d >> 3) & 3);
        ((unsigned int*)&Bt[b][d][0])[slot * 4 + (bmp & 3)] = wv;
      }
    }
    __syncthreads();
    if (ks + 1 < ksteps) PLOADS(ks + 1);
    short8 a = *(const short8*)&As[b][wr * 16 + l15][lhi * 8];
#pragma unroll
    for (int fn = 0; fn < 4; ++fn) {
      int row = wc * 64 + fn * 16 + l15;
      int slot = lhi ^ ((row >> 1) & 3) ^ ((row >> 3) & 3);
      short8 bb = *(const short8*)&Bt[b][row][slot * 8];
      acc[fn] = __builtin_amdgcn_mfma_f32_16x16x32_bf16(a, bb, acc[fn], 0, 0, 0);
    }
  }
#undef PLOADS
  int nrow = nb + wr * 16 + lhi * 4;
#pragma unroll
  for (int rr = 0; rr < 4; ++rr) {
    int n = nrow + rr;
    if (n < N) {
      int pt, sp0;
      patch_row(n, sc, lw, pt, sp0);
#pragma unroll
      for (int fn = 0; fn < 4; ++fn) {
        int d = d0 + wc * 64 + fn * 16 + l15;
        int cl = d >> lS;
        int s = d & ((1 << lS) - 1);
        int hh = s >> lw, ww = s & (W - 1);
        int c = sc * 64 + cl;
        ynat[(pt * 256 + c) * 65536 + sp0 + (hh << 8) + ww] = f2bf(acc[fn][rr]);
      }
    }
  }
}

// ---------------- conv3x3: halo-row staging (R4, known-good 187us) ----------------
__global__ __launch_bounds__(256, 2) void k_conv(const unsigned short* __restrict__ yt,
                                                 const unsigned short* __restrict__ wo,
                                                 const float* __restrict__ bo,
                                                 float* __restrict__ out) {
  __shared__ __align__(16) unsigned short As[128][128];
  __shared__ __align__(16) unsigned short Bs[130][64];
  int flat = blockIdx.x;
  int lg = ((flat & 7) << 7) + (flat >> 3);
  int n_t = lg >> 1, m_t = lg & 1;
  int n0 = n_t << 8, m0 = m_t << 7;
  int tt = n0 >> 16, yy = (n0 >> 8) & 255;
  int tid = threadIdx.x;
  int w = tid >> 6, l = tid & 63;
  int wr = w >> 1, wc = w & 1;
  int l15 = l & 15, lhi = l >> 4;
  int a_d0 = tid >> 7, a_o0 = tid & 127;
  bool doA1 = tid < 128;
  bool doBh = tid >= 254;
  floatx4 zf = {0.f, 0.f, 0.f, 0.f};
  floatx4 acc[4][8];
#pragma unroll
  for (int i = 0; i < 4; ++i)
#pragma unroll
    for (int j = 0; j < 8; ++j) acc[i][j] = zf;
  uintx4 zu = {0u, 0u, 0u, 0u};
  uintx4 rb[4], ra0[4], ra1[4];
  const unsigned short* ybase = yt + (tt << 24);
#define CLOAD(ST) { \
    int dy = (ST) >> 3, cc = ((ST) & 7) << 5; \
    int yq = yy + dy - 1; \
    bool yv = (unsigned)yq < 256u; \
    { int xq = tid - 1; \
      if (yv && (unsigned)xq < 256u) { \
        const uintx4* p = (const uintx4*)(ybase + ((yq << 8) + xq) * 256 + cc); \
        rb[0] = p[0]; rb[1] = p[1]; rb[2] = p[2]; rb[3] = p[3]; \
      } else { rb[0] = zu; rb[1] = zu; rb[2] = zu; rb[3] = zu; } } \
    { const uintx4* p = (const uintx4*)(wo + (dy * 3 + a_d0) * 65536 + (m0 + a_o0) * 256 + cc); \
      ra0[0] = p[0]; ra0[1] = p[1]; ra0[2] = p[2]; ra0[3] = p[3]; } \
    if (doA1) { \
      const uintx4* p = (const uintx4*)(wo + (dy * 3 + 2) * 65536 + (m0 + tid) * 256 + cc); \
      ra1[0] = p[0]; ra1[1] = p[1]; ra1[2] = p[2]; ra1[3] = p[3]; \
    } else if (doBh) { \
      int xq = tid + 1; \
      if (yv && xq < 256) { \
        const uintx4* p = (const uintx4*)(ybase + ((yq << 8) + xq) * 256 + cc); \
        ra1[0] = p[0]; ra1[1] = p[1]; ra1[2] = p[2]; ra1[3] = p[3]; \
      } else { ra1[0] = zu; ra1[1] = zu; ra1[2] = zu; ra1[3] = zu; } } }
  CLOAD(0);
  for (int st = 0; st < 24; ++st) {
    __syncthreads();
    {
      int brow = tid >> 1, bhf = (tid & 1) * 4, br7 = brow & 7;
#pragma unroll
      for (int j = 0; j < 4; ++j)
        *(uintx4*)&Bs[brow][((bhf + j) ^ br7) * 8] = rb[j];
      int ao7 = a_o0 & 7;
#pragma unroll
      for (int j = 0; j < 4; ++j)
        *(uintx4*)&As[a_o0][((a_d0 * 4 + j) ^ ao7) * 8] = ra0[j];
      if (doA1) {
        int o7 = tid & 7;
#pragma unroll
        for (int j = 0; j < 4; ++j)
          *(uintx4*)&As[tid][((8 + j) ^ o7) * 8] = ra1[j];
      } else if (doBh) {
        int xh = tid + 2;
        int brow2 = xh >> 1, bhf2 = (xh & 1) * 4, br72 = brow2 & 7;
#pragma unroll
        for (int j = 0; j < 4; ++j)
          *(uintx4*)&Bs[brow2][((bhf2 + j) ^ br72) * 8] = ra1[j];
      }
    }
    __syncthreads();
    if (st < 23) CLOAD(st + 1);
#pragma unroll
    for (int dx = 0; dx < 3; ++dx) {
      short8 af[4];
#pragma unroll
      for (int f = 0; f < 4; ++f) {
        int ol = wr * 64 + f * 16 + l15;
        af[f] = *(const short8*)&As[ol][((dx * 4 + lhi) ^ (ol & 7)) * 8];
      }
#pragma unroll
      for (int fn = 0; fn < 8; ++fn) {
        int xh = wc * 128 + fn * 16 + l15 + dx;
        short8 b = *(const short8*)&Bs[xh >> 1][((((xh & 1) * 4 + lhi)) ^ ((xh >> 1) & 7)) * 8];
#pragma unroll
        for (int fm = 0; fm < 4; ++fm)
          acc[fm][fn] = __builtin_amdgcn_mfma_f32_16x16x32_bf16(af[fm], b, acc[fm][fn], 0, 0, 0);
      }
    }
  }
#undef CLOAD
#pragma unroll
  for (int fm = 0; fm < 4; ++fm) {
    int o = m0 + wr * 64 + fm * 16 + lhi * 4;
#pragma unroll
    for (int rr = 0; rr < 4; ++rr) {
      float bias = bo[o + rr];
#pragma unroll
      for (int fn = 0; fn < 8; ++fn) {
        int xcol = wc * 128 + fn * 16 + l15;
        float z = acc[fm][fn][rr] + bias;
        out[((tt * 256 + o + rr) << 16) + (yy << 8) + xcol] = z > 0.f ? z : 0.2f * z;
      }
    }
  }
}

// ---------------------------------------------------------------------------
extern "C" void kernel_launch(void* const* d_in, const int* in_sizes, int n_in,
                              void* d_out, int out_size, void* d_ws, size_t ws_size,
                              hipStream_t stream) {
  const float* x   = (const float*)d_in[0];
  const float* m   = (const float*)d_in[1];
  const float* Wq  = (const float*)d_in[2];
  const float* bq  = (const float*)d_in[3];
  const float* Wk  = (const float*)d_in[4];
  const float* bk  = (const float*)d_in[5];
  const float* Wv  = (const float*)d_in[6];
  const float* bv  = (const float*)d_in[7];
  const float* Wmq = (const float*)d_in[8];
  const float* bmq = (const float*)d_in[9];
  const float* Wmk = (const float*)d_in[10];
  const float* bmk = (const float*)d_in[11];
  const float* Wo  = (const float*)d_in[12];
  const float* bo  = (const float*)d_in[13];

  char* ws = (char*)d_ws;
  unsigned short* qkv   = (unsigned short*)(ws);
  unsigned short* xtb   = (unsigned short*)(ws + 201326592);  // xt, later yt
  unsigned short* wqkv  = (unsigned short*)(ws + 268435456);
  unsigned short* wobf  = (unsigned short*)(ws + 268828672);
  float* bias           = (float*)(ws + 270008320);
  float* msc            = (float*)(ws + 270011392);
  float* scores         = (float*)(ws + 270011456);
  float* G              = (float*)(ws + 271129920);
  float* rbuf           = (float*)(ws + 272248384);
  unsigned short* pbuf  = (unsigned short*)(ws + 272251104);
  float* out            = (float*)d_out;
  unsigned short* ynat  = (unsigned short*)d_out;  // low half of d_out as bf16 scratch

  k_prep_w<<<dim3(769), dim3(256), 0, stream>>>(Wq, Wk, Wv, bq, bk, bv, Wmq, bmq, Wmk, bmk,
                                                wqkv, bias, msc);
  k_prep_wo<<<dim3(4489), dim3(256), 0, stream>>>(Wo, wobf, scores, (unsigned int*)pbuf);
  k_xt<<<dim3(1024, 4, 2), dim3(256), 0, stream>>>(x, xtb);
  k_qkv<<<dim3(3072), dim3(256), 49152, stream>>>(xtb, wqkv, bias, qkv);
  k_gram2<<<dim3(328), dim3(256), 0, stream>>>(m, G);
  k_rsum<<<dim3(680), dim3(64), 0, stream>>>(m, rbuf);
  k_scores2<<<dim3(320), dim3(256), 0, stream>>>(qkv, scores);
  k_scores_big<<<dim3(160), dim3(256), 0, stream>>>(qkv, scores);
  k_softmax<<<dim3(680), dim3(64), 0, stream>>>(scores, G, rbuf, msc, pbuf);
  k_pv<<<dim3(10240), dim3(256), 0, stream>>>(qkv, pbuf, ynat);
  k_yt<<<dim3(1024, 4, 2), dim3(256), 0, stream>>>(ynat, xtb);
  k_conv<<<dim3(1024), dim3(256), 0, stream>>>(xtb, wobf, bo, out);
}

// Round 10
// 576.427 us; speedup vs baseline: 1.2257x; 1.0125x over previous
//
#include <hip/hip_runtime.h>
#include <stdint.h>

// ---------------------------------------------------------------------------
// MultiHeadedAttention (4-scale patch attention) for MI355X / gfx950
// R10: k_conv 64x256 tile / acc[4][4] / 3 blocks-CU (occupancy play);
//      launch merges: prep_w+prep_wo, gram2+rsum, scores2+scores_big.
//      qkv/pv/softmax/xt/yt unchanged from R9.
// ---------------------------------------------------------------------------

typedef __attribute__((ext_vector_type(8))) short short8;
typedef __attribute__((ext_vector_type(4))) float floatx4;
typedef __attribute__((ext_vector_type(4))) unsigned int uintx4;

#define DEV static __device__ __forceinline__

DEV unsigned short f2bf(float f) {
  unsigned u = __builtin_bit_cast(unsigned, f);
  unsigned r = u + 0x7FFFu + ((u >> 16) & 1u);
  return (unsigned short)(r >> 16);
}

DEV void patch_row(int n, int sc, int lw, int& pt, int& sp0) {
  pt = n >> (2 + 2 * sc);
  int rem = n & ((4 << (2 * sc)) - 1);
  int oh = rem >> (1 + sc), ow = rem & ((2 << sc) - 1);
  sp0 = (oh << (lw + 8)) + (ow << lw);
}

// ---------------- merged prep: weights + mask scalars + Wo repack + zeroing ----------------
__global__ void k_prep(const float* __restrict__ Wq, const float* __restrict__ Wk,
                       const float* __restrict__ Wv, const float* __restrict__ bq,
                       const float* __restrict__ bk, const float* __restrict__ bv,
                       const float* __restrict__ Wmq, const float* __restrict__ bmq,
                       const float* __restrict__ Wmk, const float* __restrict__ bmk,
                       const float* __restrict__ Wo, const float* __restrict__ bo,
                       unsigned short* __restrict__ wqkv, float* __restrict__ bias,
                       float* __restrict__ msc, unsigned short* __restrict__ wobf,
                       float* __restrict__ scoresG, unsigned int* __restrict__ pbuf) {
  int bid = blockIdx.x;
  int t = threadIdx.x;
  if (bid < 768) {
    const float* src = bid < 256 ? (Wq + bid * 256) : (bid < 512 ? (Wk + (bid - 256) * 256)
                                                                 : (Wv + (bid - 512) * 256));
    wqkv[bid * 256 + t] = f2bf(src[t]);
    if (t == 0) bias[bid] = bid < 256 ? bq[bid] : (bid < 512 ? bk[bid - 256] : bv[bid - 512]);
    return;
  }
  if (bid == 768) {
    int sc = t >> 6, lane = t & 63;
    int ch = sc * 64 + lane;
    float a0 = Wmq[ch] * Wmk[ch];
    float a1 = Wmq[ch] * bmk[ch];
    float a2 = bmq[ch] * Wmk[ch];
    float a3 = bmq[ch] * bmk[ch];
    for (int off = 32; off; off >>= 1) {
      a0 += __shfl_xor(a0, off); a1 += __shfl_xor(a1, off);
      a2 += __shfl_xor(a2, off); a3 += __shfl_xor(a3, off);
    }
    if (lane == 0) {
      msc[sc * 4 + 0] = a0; msc[sc * 4 + 1] = a1;
      msc[sc * 4 + 2] = a2; msc[sc * 4 + 3] = a3;
    }
    return;
  }
  int blk = bid - 769;
  if (blk < 2304) {
    int didx = blk >> 8, o = blk & 255, c = t;
    wobf[didx * 65536 + o * 256 + c] = f2bf(Wo[o * 2304 + c * 9 + didx]);
  } else {
    int i = (blk - 2304) * 256 + t;
    if (i < 559232) scoresG[i] = 0.f;
    if (i < 140032) pbuf[i] = 0u;
  }
}

// ---------------- transpose kernels ----------------
__global__ __launch_bounds__(256) void k_xt(const float* __restrict__ x,
                                            unsigned short* __restrict__ xt) {
  __shared__ __align__(16) unsigned short tile[64][72];
  int p0 = blockIdx.x * 64, c0 = blockIdx.y * 64, t = blockIdx.z;
  int tid = threadIdx.x;
  {
    int cc = tid >> 2, pq = (tid & 3) * 16;
    const float* src = x + ((t * 256 + c0 + cc) * 65536 + p0 + pq);
    __align__(16) unsigned short tmp[16];
#pragma unroll
    for (int e = 0; e < 16; e += 4) {
      floatx4 v = *(const floatx4*)(src + e);
      tmp[e + 0] = f2bf(v[0]); tmp[e + 1] = f2bf(v[1]);
      tmp[e + 2] = f2bf(v[2]); tmp[e + 3] = f2bf(v[3]);
    }
    *(uintx4*)&tile[cc][pq] = *(const uintx4*)&tmp[0];
    *(uintx4*)&tile[cc][pq + 8] = *(const uintx4*)&tmp[8];
  }
  __syncthreads();
  {
    int pp = tid >> 2, cg = (tid & 3) * 16;
    __align__(16) unsigned short outv[16];
#pragma unroll
    for (int e = 0; e < 16; ++e) outv[e] = tile[cg + e][pp];
    unsigned short* dst = xt + ((t * 65536 + p0 + pp) * 256 + c0 + cg);
    *(uintx4*)dst = *(const uintx4*)&outv[0];
    *(uintx4*)(dst + 8) = *(const uintx4*)&outv[8];
  }
}

__global__ __launch_bounds__(256) void k_yt(const unsigned short* __restrict__ ynat,
                                            unsigned short* __restrict__ yt) {
  __shared__ __align__(16) unsigned short tile[64][72];
  int p0 = blockIdx.x * 64, c0 = blockIdx.y * 64, t = blockIdx.z;
  int tid = threadIdx.x;
  {
    int cc = tid >> 2, pq = (tid & 3) * 16;
    const unsigned short* src = ynat + ((t * 256 + c0 + cc) * 65536 + p0 + pq);
    *(uintx4*)&tile[cc][pq] = *(const uintx4*)src;
    *(uintx4*)&tile[cc][pq + 8] = *(const uintx4*)(src + 8);
  }
  __syncthreads();
  {
    int pp = tid >> 2, cg = (tid & 3) * 16;
    __align__(16) unsigned short outv[16];
#pragma unroll
    for (int e = 0; e < 16; ++e) outv[e] = tile[cg + e][pp];
    unsigned short* dst = yt + ((t * 65536 + p0 + pp) * 256 + c0 + cg);
    *(uintx4*)dst = *(const uintx4*)&outv[0];
    *(uintx4*)(dst + 8) = *(const uintx4*)&outv[8];
  }
}

// ---------------- QKV GEMM: 128x256 tile + LDS-transposed coalesced epilogue ----------------
__global__ __launch_bounds__(256, 2) void k_qkv(const unsigned short* __restrict__ xt,
                                                const unsigned short* __restrict__ wqkv,
                                                const float* __restrict__ bias,
                                                unsigned short* __restrict__ qkv) {
  extern __shared__ __align__(16) char smem[];
  auto As = (unsigned short (*)[64])(smem);            // [128][64]  16KB
  auto Bs = (unsigned short (*)[64])(smem + 16384);    // [256][64]  32KB
  auto Cs = (unsigned short (*)[280])(smem);           // [64][280]  35KB (overlay)
  int flat = blockIdx.x;
  int lg = (flat & 7) * 384 + (flat >> 3);
  int n_t = lg / 6, m_t = lg - n_t * 6;
  int n0 = n_t << 8, m0 = m_t << 7;
  int tid = threadIdx.x;
  int w = tid >> 6, l = tid & 63;
  int wr = w >> 1, wc = w & 1;
  int l15 = l & 15, lhi = l >> 4;
  int sr = tid >> 1, sbase = (tid & 1) * 4, r7 = sr & 7;
  int b7 = tid & 7;
  const unsigned short* gA = wqkv + (m0 + sr) * 256 + sbase * 8;
  const unsigned short* gB = xt + (n0 + tid) * 256;
  floatx4 zf = {0.f, 0.f, 0.f, 0.f};
  floatx4 acc[4][8];
#pragma unroll
  for (int i = 0; i < 4; ++i)
#pragma unroll
    for (int j = 0; j < 8; ++j) acc[i][j] = zf;
  uintx4 ra[4], rb[8];
#define QLOAD(K0) { const uintx4* pa = (const uintx4*)(gA + (K0)); \
                    ra[0] = pa[0]; ra[1] = pa[1]; ra[2] = pa[2]; ra[3] = pa[3]; \
                    const uintx4* pb = (const uintx4*)(gB + (K0)); \
                    rb[0] = pb[0]; rb[1] = pb[1]; rb[2] = pb[2]; rb[3] = pb[3]; \
                    rb[4] = pb[4]; rb[5] = pb[5]; rb[6] = pb[6]; rb[7] = pb[7]; }
  QLOAD(0);
#pragma unroll
  for (int ch = 0; ch < 4; ++ch) {
    __syncthreads();
#pragma unroll
    for (int j = 0; j < 4; ++j)
      *(uintx4*)&As[sr][((sbase + j) ^ r7) * 8] = ra[j];
#pragma unroll
    for (int j = 0; j < 8; ++j)
      *(uintx4*)&Bs[tid][(j ^ b7) * 8] = rb[j];
    __syncthreads();
    if (ch < 3) QLOAD((ch + 1) * 64);
#pragma unroll
    for (int kk = 0; kk < 2; ++kk) {
      short8 af[4];
#pragma unroll
      for (int f = 0; f < 4; ++f) {
        int arow = wr * 64 + f * 16 + l15;
        af[f] = *(const short8*)&As[arow][(((kk << 2) + lhi) ^ (arow & 7)) * 8];
      }
#pragma unroll
      for (int fn = 0; fn < 8; ++fn) {
        int brow = wc * 128 + fn * 16 + l15;
        short8 b = *(const short8*)&Bs[brow][(((kk << 2) + lhi) ^ (brow & 7)) * 8];
#pragma unroll
        for (int fm = 0; fm < 4; ++fm)
          acc[fm][fn] = __builtin_amdgcn_mfma_f32_16x16x32_bf16(af[fm], b, acc[fm][fn], 0, 0, 0);
      }
    }
  }
#undef QLOAD
#pragma unroll
  for (int h = 0; h < 2; ++h) {
    __syncthreads();
    if (wr == h) {
#pragma unroll
      for (int fm = 0; fm < 4; ++fm) {
#pragma unroll
        for (int rr = 0; rr < 4; ++rr) {
          int rl = fm * 16 + lhi * 4 + rr;
          float bv = bias[m0 + h * 64 + rl];
#pragma unroll
          for (int fn = 0; fn < 8; ++fn)
            Cs[rl][wc * 128 + fn * 16 + l15] = f2bf(acc[fm][fn][rr] + bv);
        }
      }
    }
    __syncthreads();
    {
      int p8 = (tid & 31) * 8;
      int pcol = n0 + p8;
      int t = pcol >> 16, p = pcol & 65535;
#pragma unroll
      for (int pass = 0; pass < 8; ++pass) {
        int rl = (tid >> 5) + pass * 8;
        uintx4 v = *(const uintx4*)&Cs[rl][p8];
        *(uintx4*)&qkv[((t * 768 + m0 + h * 64 + rl) << 16) + p] = v;
      }
    }
  }
}

// ---------------- merged mask kernel: gram (bid<328) + rowsum (bid>=328) ----------------
__global__ __launch_bounds__(256) void k_mask(const float* __restrict__ m,
                                              float* __restrict__ G,
                                              float* __restrict__ rbuf) {
  int bid = blockIdx.x;
  int tid = threadIdx.x;
  if (bid >= 328) {
    int row = (bid - 328) * 4 + (tid >> 6);
    int lane = tid & 63;
    if (row < 680) {
      int sc, n;
      if (row < 8)        { sc = 0; n = row; }
      else if (row < 40)  { sc = 1; n = row - 8; }
      else if (row < 168) { sc = 2; n = row - 40; }
      else                { sc = 3; n = row - 168; }
      int lw = 7 - sc, W = 1 << lw;
      int pt, sp0;
      patch_row(n, sc, lw, pt, sp0);
      int base = pt * 65536 + sp0;
      int S = 1 << (14 - 2 * sc);
      float acc = 0.f;
      for (int s = lane; s < S; s += 64) {
        int hh = s >> lw, ww = s & (W - 1);
        acc += m[base + (hh << 8) + ww];
      }
      for (int off = 32; off; off >>= 1) acc += __shfl_xor(acc, off);
      if (lane == 0) rbuf[row] = acc;
    }
    return;
  }
  __shared__ __align__(16) float Ns[32][68];
  __shared__ __align__(16) float Ms[32][68];
  int sc, tn, tm, z, nchunks, soff;
  if (bid < 32)      { sc = 0; tn = 0; tm = 0; z = bid;      nchunks = 8; soff = 0; }
  else if (bid < 40) { sc = 1; tn = 0; tm = 0; z = bid - 32; nchunks = 8; soff = 64; }
  else if (bid < 72) { int r = bid - 40; int tl = r >> 1; sc = 2; tn = tl >> 2; tm = tl & 3; z = r & 1; nchunks = 8; soff = 1088; }
  else               { int tl = bid - 72; sc = 3; tn = tl >> 4; tm = tl & 15; z = 0; nchunks = 4; soff = 17472; }
  int lw = 7 - sc, W = 1 << lw, N = 8 << (2 * sc);
  int kbase = z * nchunks * 64;
  int n0 = tn * 32, m0 = tm * 32;
  bool isA = tid < 128;
  int u = tid & 127;
  int srow = u >> 2, sslot0 = (u & 3) * 4;
  int grow = (isA ? n0 : m0) + srow;
  bool valid = grow < N;
  int pt = 0, sp0 = 0;
  if (valid) patch_row(grow, sc, lw, pt, sp0);
  int gbase = pt * 65536 + sp0;
  int trc = tid >> 4, tcc = tid & 15;
  float a00 = 0.f, a01 = 0.f, a10 = 0.f, a11 = 0.f;
  floatx4 zf = {0.f, 0.f, 0.f, 0.f};
  for (int c = 0; c < nchunks; ++c) {
    int k0 = kbase + c * 64;
    floatx4 v[4];
#pragma unroll
    for (int j = 0; j < 4; ++j) {
      v[j] = zf;
      if (valid) {
        int s = k0 + (sslot0 + j) * 4;
        int hh = s >> lw, ww = s & (W - 1);
        v[j] = *(const floatx4*)(m + gbase + (hh << 8) + ww);
      }
    }
    __syncthreads();
    float* dstrow = isA ? &Ns[srow][0] : &Ms[srow][0];
#pragma unroll
    for (int j = 0; j < 4; ++j) *(floatx4*)&dstrow[(sslot0 + j) * 4] = v[j];
    __syncthreads();
#pragma unroll 4
    for (int k = 0; k < 64; k += 4) {
      floatx4 na = *(const floatx4*)&Ns[2 * trc][k];
      floatx4 nb = *(const floatx4*)&Ns[2 * trc + 1][k];
      floatx4 ma = *(const floatx4*)&Ms[2 * tcc][k];
      floatx4 mb = *(const floatx4*)&Ms[2 * tcc + 1][k];
#pragma unroll
      for (int e = 0; e < 4; ++e) {
        a00 += na[e] * ma[e]; a01 += na[e] * mb[e];
        a10 += nb[e] * ma[e]; a11 += nb[e] * mb[e];
      }
    }
  }
  int rn = n0 + 2 * trc, rm = m0 + 2 * tcc;
  float res[2][2] = {{a00, a01}, {a10, a11}};
#pragma unroll
  for (int i = 0; i < 2; ++i)
#pragma unroll
    for (int j = 0; j < 2; ++j) {
      if (rn + i < N && rm + j < N) {
        float* dst = &G[soff + (rn + i) * N + rm + j];
        if (sc < 3) atomicAdd(dst, res[i][j]); else *dst = res[i][j];
      }
    }
}

// ---------------- merged scores: bid<160 big (sc2/sc3), else 32x32 (sc0/sc1) ----------------
__global__ __launch_bounds__(256) void k_scores_all(const unsigned short* __restrict__ qkv,
                                                    float* __restrict__ scores) {
  __shared__ __align__(16) char sbuf[32768];
  int bid = blockIdx.x;
  int tid = threadIdx.x;
  int w = tid >> 6, l = tid & 63;
  int wr = w >> 1, wc = w & 1, l15 = l & 15, lhi = l >> 4;
  uintx4 zu = {0u, 0u, 0u, 0u};
  floatx4 zf = {0.f, 0.f, 0.f, 0.f};
  if (bid < 160) {
    auto As = (unsigned short (*)[64])(sbuf);            // [128][64]
    auto Bs = (unsigned short (*)[64])(sbuf + 16384);    // [128][64]
    int lg = (bid & 7) * 20 + (bid >> 3);
    int sc, tn, tm, z, soff;
    if (lg < 32) { sc = 2; tn = 0; tm = 0; z = lg; soff = 1088; }
    else { int r = lg - 32; int tl = r >> 3; sc = 3; tn = tl >> 2; tm = tl & 3; z = r & 7; soff = 17472; }
    int N = 8 << (2 * sc);
    int lw = 7 - sc, W = 1 << lw, lS = 14 - 2 * sc;
    int n0 = tn * 128, m0 = tm * 128;
    int kbase = z * 2048;
    int sr = tid >> 1, sbase = (tid & 1) * 4, r7 = sr & 7;
    int ptA, spA, ptB, spB;
    patch_row(n0 + sr, sc, lw, ptA, spA);
    patch_row(m0 + sr, sc, lw, ptB, spB);
    int baseA = (ptA * 768 + sc * 64) * 65536 + spA;
    int baseB = (ptB * 768 + 256 + sc * 64) * 65536 + spB;
    floatx4 acc[4][4];
#pragma unroll
    for (int i = 0; i < 4; ++i)
#pragma unroll
      for (int j = 0; j < 4; ++j) acc[i][j] = zf;
    uintx4 ra[4], rb[4];
#define GLOAD(K0) { \
  _Pragma("unroll") for (int j = 0; j < 4; ++j) { \
    int k = kbase + (K0) + (sbase + j) * 8; \
    int cl = k >> lS; int s = k & ((1 << lS) - 1); \
    int hh = s >> lw, ww = s & (W - 1); \
    int off = cl * 65536 + (hh << 8) + ww; \
    ra[j] = *(const uintx4*)(qkv + baseA + off); \
    rb[j] = *(const uintx4*)(qkv + baseB + off); } }
    GLOAD(0);
    for (int st = 0; st < 32; ++st) {
      __syncthreads();
#pragma unroll
      for (int j = 0; j < 4; ++j) {
        *(uintx4*)&As[sr][((sbase + j) ^ r7) * 8] = ra[j];
        *(uintx4*)&Bs[sr][((sbase + j) ^ r7) * 8] = rb[j];
      }
      __syncthreads();
      if (st < 31) GLOAD((st + 1) * 64);
#pragma unroll
      for (int kk = 0; kk < 2; ++kk) {
        short8 af[4], bfr[4];
#pragma unroll
        for (int f = 0; f < 4; ++f) {
          int arow = wr * 64 + f * 16 + l15;
          af[f] = *(const short8*)&As[arow][(((kk << 2) + lhi) ^ (arow & 7)) * 8];
          int brow = wc * 64 + f * 16 + l15;
          bfr[f] = *(const short8*)&Bs[brow][(((kk << 2) + lhi) ^ (brow & 7)) * 8];
        }
#pragma unroll
        for (int fm = 0; fm < 4; ++fm)
#pragma unroll
          for (int fn = 0; fn < 4; ++fn)
            acc[fm][fn] = __builtin_amdgcn_mfma_f32_16x16x32_bf16(af[fm], bfr[fn], acc[fm][fn], 0, 0, 0);
      }
    }
#undef GLOAD
#pragma unroll
    for (int fm = 0; fm < 4; ++fm) {
      int nrow = n0 + wr * 64 + fm * 16 + lhi * 4;
#pragma unroll
      for (int rr = 0; rr < 4; ++rr) {
#pragma unroll
        for (int fn = 0; fn < 4; ++fn) {
          int mcol = m0 + wc * 64 + fn * 16 + l15;
          atomicAdd(&scores[soff + (nrow + rr) * N + mcol], acc[fm][fn][rr]);
        }
      }
    }
    return;
  }
  // ---- sc0/sc1 path ----
  {
    auto As = (unsigned short (*)[136])(sbuf);           // [32][136]
    auto Bs = (unsigned short (*)[136])(sbuf + 8704);    // [32][136]
    int b2 = bid - 160;
    int sc, z, soff;
    if (b2 < 256) { sc = 0; z = b2;       soff = 0; }
    else          { sc = 1; z = b2 - 256; soff = 64; }
    int lw = 7 - sc, W = 1 << lw, lS = 14 - 2 * sc, N = 8 << (2 * sc);
    int kbase = z * 4096;
    floatx4 acc = zf;
    bool isA = tid < 128;
    int u = tid & 127;
    int srow = u >> 2, sslot0 = (u & 3) * 4;
    int grow = srow;
    int cb = (isA ? 0 : 256) + sc * 64;
    int pt = 0, sp0 = 0;
    bool valid = grow < N;
    if (valid) patch_row(grow, sc, lw, pt, sp0);
    int rowbase = (pt * 768 + cb) * 65536 + sp0;
    uintx4 r[4];
#define SLOAD(KS) { int kb2 = kbase + (KS) * 128; \
  _Pragma("unroll") for (int j = 0; j < 4; ++j) { \
    uintx4 v = zu; \
    if (valid) { int k = kb2 + (sslot0 + j) * 8; \
      int cl = k >> lS; int s = k & ((1 << lS) - 1); \
      int hh = s >> lw, ww = s & (W - 1); \
      v = *(const uintx4*)(qkv + rowbase + cl * 65536 + (hh << 8) + ww); } \
    r[j] = v; } }
    SLOAD(0);
    for (int ks = 0; ks < 32; ++ks) {
      __syncthreads();
      {
        unsigned short* dstrow = isA ? &As[srow][0] : &Bs[srow][0];
#pragma unroll
        for (int j = 0; j < 4; ++j) *(uintx4*)&dstrow[(sslot0 + j) * 8] = r[j];
      }
      __syncthreads();
      if (ks < 31) SLOAD(ks + 1);
#pragma unroll
      for (int kk = 0; kk < 4; ++kk) {
        short8 a = *(const short8*)&As[wr * 16 + l15][(kk * 4 + lhi) * 8];
        short8 b = *(const short8*)&Bs[wc * 16 + l15][(kk * 4 + lhi) * 8];
        acc = __builtin_amdgcn_mfma_f32_16x16x32_bf16(a, b, acc, 0, 0, 0);
      }
    }
#undef SLOAD
    int rrow = wr * 16 + lhi * 4;
    int ccol = wc * 16 + l15;
    if (ccol < N) {
#pragma unroll
      for (int rr = 0; rr < 4; ++rr)
        if (rrow + rr < N) atomicAdd(&scores[soff + (rrow + rr) * N + ccol], acc[rr]);
    }
  }
}

// ---------------- logits + softmax -> P bf16 ----------------
__global__ void k_softmax(const float* __restrict__ scores, const float* __restrict__ G,
                          const float* __restrict__ rbuf, const float* __restrict__ msc,
                          unsigned short* __restrict__ pbuf) {
  int row = blockIdx.x, lane = threadIdx.x;
  int sc, n, roff, soff, poff;
  if (row < 8)        { sc = 0; n = row;       roff = 0;   soff = 0;     poff = 0; }
  else if (row < 40)  { sc = 1; n = row - 8;   roff = 8;   soff = 64;    poff = 512; }
  else if (row < 168) { sc = 2; n = row - 40;  roff = 40;  soff = 1088;  poff = 1536; }
  else                { sc = 3; n = row - 168; roff = 168; soff = 17472; poff = 17920; }
  int N = 8 << (2 * sc);
  int Kpad = (sc < 2) ? 32 : N;
  float Sf = (float)(1 << (14 - 2 * sc));
  float invD = 1.0f / (float)(1 << (20 - 2 * sc));
  float alpha = msc[sc * 4 + 0], beta = msc[sc * 4 + 1];
  float gamma = msc[sc * 4 + 2], delta = msc[sc * 4 + 3];
  float rn = rbuf[roff + n];
  float vals[8];
  float mx = -1e30f;
#pragma unroll
  for (int j = 0; j < 8; ++j) {
    float v = -1e30f;
    int mcol = lane + j * 64;
    if (j * 64 < N && mcol < N) {
      float sq = scores[soff + n * N + mcol];
      float g = G[soff + n * N + mcol];
      float rm = rbuf[roff + mcol];
      v = sq * (alpha * g + beta * rn + gamma * rm + delta * Sf) * invD;
    }
    vals[j] = v;
    mx = fmaxf(mx, v);
  }
  for (int off = 32; off; off >>= 1) mx = fmaxf(mx, __shfl_xor(mx, off));
  float sum = 0.f;
#pragma unroll
  for (int j = 0; j < 8; ++j) {
    int mcol = lane + j * 64;
    float e = 0.f;
    if (j * 64 < N && mcol < N) e = __expf(vals[j] - mx);
    vals[j] = e;
    sum += e;
  }
  for (int off = 32; off; off >>= 1) sum += __shfl_xor(sum, off);
  float inv = 1.f / sum;
#pragma unroll
  for (int j = 0; j < 8; ++j) {
    int mcol = lane + j * 64;
    if (j * 64 < N && mcol < N) pbuf[poff + n * Kpad + mcol] = f2bf(vals[j] * inv);
  }
}

// ---------------- PV GEMM: double-buffered LDS, 1 barrier/K-step (R6) ----------------
__global__ __launch_bounds__(256) void k_pv(const unsigned short* __restrict__ qkv,
                                            const unsigned short* __restrict__ pbuf,
                                            unsigned short* __restrict__ ynat) {
  int bid = blockIdx.x;
  int sc, bx, by;
  if (bid < 4096)      { sc = 0; bx = bid; by = 0; }
  else if (bid < 6144) { sc = 1; bx = bid - 4096; by = 0; }
  else if (bid < 8192) { int r = bid - 6144; sc = 2; bx = r >> 1; by = r & 1; }
  else                 { int r = bid - 8192; sc = 3; bx = r >> 3; by = r & 7; }
  int WR    = (sc == 0) ? 1 : (sc == 1) ? 2 : 4;
  int logWC = (sc == 0) ? 2 : (sc == 1) ? 1 : 0;
  int poff  = (sc == 0) ? 0 : (sc == 1) ? 512 : (sc == 2) ? 1536 : 17920;
  int lw = 7 - sc, W = 1 << lw;
  int lS = 14 - 2 * sc;
  int N = 8 << (2 * sc);
  int Kpad = (sc < 2) ? 32 : N;
  int WC = 1 << logWC;
  int d0 = bx * (WC * 64);
  int nb = by * (WR * 16);
  __shared__ __align__(16) unsigned short As[2][64][40];
  __shared__ __align__(16) unsigned short Bt[2][256][32];
  int tid = threadIdx.x;
  int w = tid >> 6, l = tid & 63;
  int wr = w >> logWC, wc = w & (WC - 1);
  int l15 = l & 15, lhi = l >> 4;
  floatx4 zf = {0.f, 0.f, 0.f, 0.f};
  floatx4 acc[4];
#pragma unroll
  for (int i = 0; i < 4; ++i) acc[i] = zf;
  int bmp = tid & 15;
  int dg = tid >> 4;
  bool act0 = (WC > 1) || (dg < 8);
  bool has1 = (WC == 4);
  bool doA = tid < WR * 64;
  int arow = tid >> 2, akg = (tid & 3) * 8;
  int ksteps = Kpad >> 5;
  uintx4 zu = {0u, 0u, 0u, 0u};
  int vcb = (512 + sc * 64) * 65536;
  uintx4 av = zu, lo0 = zu, hi0 = zu, lo1 = zu, hi1 = zu;
#define PLOADS(KS) { int k0 = (KS) * 32; \
    av = zu; lo0 = zu; hi0 = zu; lo1 = zu; hi1 = zu; \
    if (doA) av = *(const uintx4*)(pbuf + poff + (nb + arow) * Kpad + k0 + akg); \
    int gm0 = k0 + 2 * bmp, gm1 = gm0 + 1; \
    bool mv0 = gm0 < N, mv1 = gm1 < N; \
    int pt0 = 0, sp00 = 0, pt1 = 0, sp01 = 0; \
    if (mv0) patch_row(gm0, sc, lw, pt0, sp00); \
    if (mv1) patch_row(gm1, sc, lw, pt1, sp01); \
    { int d = d0 + dg * 8; int cl = d >> lS; int s = d & ((1 << lS) - 1); \
      int hh = s >> lw, ww = s & (W - 1); int sp = (hh << 8) + ww; \
      if (act0 && mv0) lo0 = *(const uintx4*)(qkv + pt0 * 768 * 65536 + vcb + cl * 65536 + sp00 + sp); \
      if (act0 && mv1) hi0 = *(const uintx4*)(qkv + pt1 * 768 * 65536 + vcb + cl * 65536 + sp01 + sp); } \
    if (has1) { int d = d0 + (dg + 16) * 8; int cl = d >> lS; int s = d & ((1 << lS) - 1); \
      int hh = s >> lw, ww = s & (W - 1); int sp = (hh << 8) + ww; \
      if (mv0) lo1 = *(const uintx4*)(qkv + pt0 * 768 * 65536 + vcb + cl * 65536 + sp00 + sp); \
      if (mv1) hi1 = *(const uintx4*)(qkv + pt1 * 768 * 65536 + vcb + cl * 65536 + sp01 + sp); } }
  PLOADS(0);
  for (int ks = 0; ks < ksteps; ++ks) {
    int b = ks & 1;
    if (doA) *(uintx4*)&As[b][arow][akg] = av;
    if (act0) {
      int du = dg * 8;
#pragma unroll
      for (int j = 0; j < 8; ++j) {
        int d = du + j;
        unsigned losh = (lo0[j >> 1] >> ((j & 1) * 16)) & 0xFFFFu;
        unsigned hish = (hi0[j >> 1] >> ((j & 1) * 16)) & 0xFFFFu;
        unsigned wv = losh | (hish << 16);
        int slot = (bmp >> 2) ^ ((d >> 1) & 3) ^ ((d >> 3) & 3);
        ((unsigned int*)&Bt[b][d][0])[slot * 4 + (bmp & 3)] = wv;
      }
    }
    if (has1) {
      int du = (dg + 16) * 8;
#pragma unroll
      for (int j = 0; j < 8; ++j) {
        int d = du + j;
        unsigned losh = (lo1[j >> 1] >> ((j & 1) * 16)) & 0xFFFFu;
        unsigned hish = (hi1[j >> 1] >> ((j & 1) * 16)) & 0xFFFFu;
        unsigned wv = losh | (hish << 16);
        int slot = (bmp >> 2) ^ ((d >> 1) & 3) ^ ((d >> 3) & 3);
        ((unsigned int*)&Bt[b][d][0])[slot * 4 + (bmp & 3)] = wv;
      }
    }
    __syncthreads();
    if (ks + 1 < ksteps) PLOADS(ks + 1);
    short8 a = *(const short8*)&As[b][wr * 16 + l15][lhi * 8];
#pragma unroll
    for (int fn = 0; fn < 4; ++fn) {
      int row = wc * 64 + fn * 16 + l15;
      int slot = lhi ^ ((row >> 1) & 3) ^ ((row >> 3) & 3);
      short8 bb = *(const short8*)&Bt[b][row][slot * 8];
      acc[fn] = __builtin_amdgcn_mfma_f32_16x16x32_bf16(a, bb, acc[fn], 0, 0, 0);
    }
  }
#undef PLOADS
  int nrow = nb + wr * 16 + lhi * 4;
#pragma unroll
  for (int rr = 0; rr < 4; ++rr) {
    int n = nrow + rr;
    if (n < N) {
      int pt, sp0;
      patch_row(n, sc, lw, pt, sp0);
#pragma unroll
      for (int fn = 0; fn < 4; ++fn) {
        int d = d0 + wc * 64 + fn * 16 + l15;
        int cl = d >> lS;
        int s = d & ((1 << lS) - 1);
        int hh = s >> lw, ww = s & (W - 1);
        int c = sc * 64 + cl;
        ynat[(pt * 256 + c) * 65536 + sp0 + (hh << 8) + ww] = f2bf(acc[fn][rr]);
      }
    }
  }
}

// ---------------- conv3x3: halo staging, 64x256 tile, acc[4][4], 3 blk/CU ----------------
__global__ __launch_bounds__(256, 3) void k_conv(const unsigned short* __restrict__ yt,
                                                 const unsigned short* __restrict__ wo,
                                                 const float* __restrict__ bo,
                                                 float* __restrict__ out) {
  __shared__ __align__(16) unsigned short As[64][128];   // o x (3dx x 4slot)x8  16KB
  __shared__ __align__(16) unsigned short Bs[130][64];   // halo row pairs       16.6KB
  int flat = blockIdx.x;                      // 2048 blocks
  int lg = ((flat & 7) << 8) + (flat >> 3);   // bijective XCD chunking (8x256)
  int n_t = lg >> 2, m_t = lg & 3;            // m-inner: B L2 reuse
  int n0 = n_t << 8, m0 = m_t << 6;           // 256 p2 (one row) x 64 o
  int tt = n0 >> 16, yy = (n0 >> 8) & 255;
  int tid = threadIdx.x;
  int w = tid >> 6, l = tid & 63;             // w = x-quarter 0..3
  int l15 = l & 15, lhi = l >> 4;
  bool doA = tid < 192;
  int a_dx = tid >> 6, a_o = tid & 63;        // threads 0..191: 3 dx x 64 o
  bool doBh = tid >= 254;                     // halo xh = 256,257
  floatx4 zf = {0.f, 0.f, 0.f, 0.f};
  floatx4 acc[4][4];
#pragma unroll
  for (int i = 0; i < 4; ++i)
#pragma unroll
    for (int j = 0; j < 4; ++j) acc[i][j] = zf;
  uintx4 zu = {0u, 0u, 0u, 0u};
  uintx4 rb[4], ra[4], rh[4];
  const unsigned short* ybase = yt + (tt << 24);
#define CLOAD(ST) { \
    int dy = (ST) >> 3, cc = ((ST) & 7) << 5; \
    int yq = yy + dy - 1; \
    bool yv = (unsigned)yq < 256u; \
    { int xq = tid - 1; \
      if (yv && (unsigned)xq < 256u) { \
        const uintx4* p = (const uintx4*)(ybase + ((yq << 8) + xq) * 256 + cc); \
        rb[0] = p[0]; rb[1] = p[1]; rb[2] = p[2]; rb[3] = p[3]; \
      } else { rb[0] = zu; rb[1] = zu; rb[2] = zu; rb[3] = zu; } } \
    if (doA) { \
      const uintx4* p = (const uintx4*)(wo + (dy * 3 + a_dx) * 65536 + (m0 + a_o) * 256 + cc); \
      ra[0] = p[0]; ra[1] = p[1]; ra[2] = p[2]; ra[3] = p[3]; \
    } else if (doBh) { \
      int xq = tid + 1;  /* 255, 256 */ \
      if (yv && xq < 256) { \
        const uintx4* p = (const uintx4*)(ybase + ((yq << 8) + xq) * 256 + cc); \
        rh[0] = p[0]; rh[1] = p[1]; rh[2] = p[2]; rh[3] = p[3]; \
      } else { rh[0] = zu; rh[1] = zu; rh[2] = zu; rh[3] = zu; } } }
  CLOAD(0);
  for (int st = 0; st < 24; ++st) {
    __syncthreads();
    {
      int brow = tid >> 1, bhf = (tid & 1) * 4, br7 = brow & 7;
#pragma unroll
      for (int j = 0; j < 4; ++j)
        *(uintx4*)&Bs[brow][((bhf + j) ^ br7) * 8] = rb[j];
      if (doA) {
        int o7 = a_o & 7;
#pragma unroll
        for (int j = 0; j < 4; ++j)
          *(uintx4*)&As[a_o][((a_dx * 4 + j) ^ o7) * 8] = ra[j];
      } else if (doBh) {
        int xh = tid + 2;  // 256, 257
        int brow2 = xh >> 1, bhf2 = (xh & 1) * 4, br72 = brow2 & 7;
#pragma unroll
        for (int j = 0; j < 4; ++j)
          *(uintx4*)&Bs[brow2][((bhf2 + j) ^ br72) * 8] = rh[j];
      }
    }
    __syncthreads();
    if (st < 23) CLOAD(st + 1);
#pragma unroll
    for (int dx = 0; dx < 3; ++dx) {
      short8 af[4];
#pragma unroll
      for (int f = 0; f < 4; ++f) {
        int ol = f * 16 + l15;
        af[f] = *(const short8*)&As[ol][((dx * 4 + lhi) ^ (ol & 7)) * 8];
      }
#pragma unroll
      for (int fn = 0; fn < 4; ++fn) {
        int xh = w * 64 + fn * 16 + l15 + dx;
        short8 b = *(const short8*)&Bs[xh >> 1][((((xh & 1) * 4 + lhi)) ^ ((xh >> 1) & 7)) * 8];
#pragma unroll
        for (int fm = 0; fm < 4; ++fm)
          acc[fm][fn] = __builtin_amdgcn_mfma_f32_16x16x32_bf16(af[fm], b, acc[fm][fn], 0, 0, 0);
      }
    }
  }
#undef CLOAD
#pragma unroll
  for (int fm = 0; fm < 4; ++fm) {
    int o = m0 + fm * 16 + lhi * 4;
#pragma unroll
    for (int rr = 0; rr < 4; ++rr) {
      float bias = bo[o + rr];
#pragma unroll
      for (int fn = 0; fn < 4; ++fn) {
        int xcol = w * 64 + fn * 16 + l15;
        float z = acc[fm][fn][rr] + bias;
        out[((tt * 256 + o + rr) << 16) + (yy << 8) + xcol] = z > 0.f ? z : 0.2f * z;
      }
    }
  }
}

// ---------------------------------------------------------------------------
extern "C" void kernel_launch(void* const* d_in, const int* in_sizes, int n_in,
                              void* d_out, int out_size, void* d_ws, size_t ws_size,
                              hipStream_t stream) {
  const float* x   = (const float*)d_in[0];
  const float* m   = (const float*)d_in[1];
  const float* Wq  = (const float*)d_in[2];
  const float* bq  = (const float*)d_in[3];
  const float* Wk  = (const float*)d_in[4];
  const float* bk  = (const float*)d_in[5];
  const float* Wv  = (const float*)d_in[6];
  const float* bv  = (const float*)d_in[7];
  const float* Wmq = (const float*)d_in[8];
  const float* bmq = (const float*)d_in[9];
  const float* Wmk = (const float*)d_in[10];
  const float* bmk = (const float*)d_in[11];
  const float* Wo  = (const float*)d_in[12];
  const float* bo  = (const float*)d_in[13];

  char* ws = (char*)d_ws;
  unsigned short* qkv   = (unsigned short*)(ws);
  unsigned short* xtb   = (unsigned short*)(ws + 201326592);  // xt, later yt
  unsigned short* wqkv  = (unsigned short*)(ws + 268435456);
  unsigned short* wobf  = (unsigned short*)(ws + 268828672);
  float* bias           = (float*)(ws + 270008320);
  float* msc            = (float*)(ws + 270011392);
  float* scores         = (float*)(ws + 270011456);
  float* G              = (float*)(ws + 271129920);
  float* rbuf           = (float*)(ws + 272248384);
  unsigned short* pbuf  = (unsigned short*)(ws + 272251104);
  float* out            = (float*)d_out;
  unsigned short* ynat  = (unsigned short*)d_out;  // low half of d_out as bf16 scratch

  k_prep<<<dim3(5258), dim3(256), 0, stream>>>(Wq, Wk, Wv, bq, bk, bv, Wmq, bmq, Wmk, bmk,
                                               Wo, bo, wqkv, bias, msc, wobf, scores,
                                               (unsigned int*)pbuf);
  k_xt<<<dim3(1024, 4, 2), dim3(256), 0, stream>>>(x, xtb);
  k_qkv<<<dim3(3072), dim3(256), 49152, stream>>>(xtb, wqkv, bias, qkv);
  k_mask<<<dim3(498), dim3(256), 0, stream>>>(m, G, rbuf);
  k_scores_all<<<dim3(480), dim3(256), 0, stream>>>(qkv, scores);
  k_softmax<<<dim3(680), dim3(64), 0, stream>>>(scores, G, rbuf, msc, pbuf);
  k_pv<<<dim3(10240), dim3(256), 0, stream>>>(qkv, pbuf, ynat);
  k_yt<<<dim3(1024, 4, 2), dim3(256), 0, stream>>>(ynat, xtb);
  k_conv<<<dim3(2048), dim3(256), 0, stream>>>(xtb, wobf, bo, out);
}

// Round 11
// 528.083 us; speedup vs baseline: 1.3379x; 1.0915x over previous
//
#include <hip/hip_runtime.h>
#include <stdint.h>

// ---------------------------------------------------------------------------
// MultiHeadedAttention (4-scale patch attention) for MI355X / gfx950
// R11: conv reverted to R9 128x256 halo kernel (R10's 64x256 regressed:
//      MFMA-per-LDS-read halved). Keep R10 launch merges. k_pv: balanced
//      per-scale XCD co-location of by-sibling groups (share V panels).
// ---------------------------------------------------------------------------

typedef __attribute__((ext_vector_type(8))) short short8;
typedef __attribute__((ext_vector_type(4))) float floatx4;
typedef __attribute__((ext_vector_type(4))) unsigned int uintx4;

#define DEV static __device__ __forceinline__

DEV unsigned short f2bf(float f) {
  unsigned u = __builtin_bit_cast(unsigned, f);
  unsigned r = u + 0x7FFFu + ((u >> 16) & 1u);
  return (unsigned short)(r >> 16);
}

DEV void patch_row(int n, int sc, int lw, int& pt, int& sp0) {
  pt = n >> (2 + 2 * sc);
  int rem = n & ((4 << (2 * sc)) - 1);
  int oh = rem >> (1 + sc), ow = rem & ((2 << sc) - 1);
  sp0 = (oh << (lw + 8)) + (ow << lw);
}

// ---------------- merged prep: weights + mask scalars + Wo repack + zeroing ----------------
__global__ void k_prep(const float* __restrict__ Wq, const float* __restrict__ Wk,
                       const float* __restrict__ Wv, const float* __restrict__ bq,
                       const float* __restrict__ bk, const float* __restrict__ bv,
                       const float* __restrict__ Wmq, const float* __restrict__ bmq,
                       const float* __restrict__ Wmk, const float* __restrict__ bmk,
                       const float* __restrict__ Wo, const float* __restrict__ bo,
                       unsigned short* __restrict__ wqkv, float* __restrict__ bias,
                       float* __restrict__ msc, unsigned short* __restrict__ wobf,
                       float* __restrict__ scoresG, unsigned int* __restrict__ pbuf) {
  int bid = blockIdx.x;
  int t = threadIdx.x;
  if (bid < 768) {
    const float* src = bid < 256 ? (Wq + bid * 256) : (bid < 512 ? (Wk + (bid - 256) * 256)
                                                                 : (Wv + (bid - 512) * 256));
    wqkv[bid * 256 + t] = f2bf(src[t]);
    if (t == 0) bias[bid] = bid < 256 ? bq[bid] : (bid < 512 ? bk[bid - 256] : bv[bid - 512]);
    return;
  }
  if (bid == 768) {
    int sc = t >> 6, lane = t & 63;
    int ch = sc * 64 + lane;
    float a0 = Wmq[ch] * Wmk[ch];
    float a1 = Wmq[ch] * bmk[ch];
    float a2 = bmq[ch] * Wmk[ch];
    float a3 = bmq[ch] * bmk[ch];
    for (int off = 32; off; off >>= 1) {
      a0 += __shfl_xor(a0, off); a1 += __shfl_xor(a1, off);
      a2 += __shfl_xor(a2, off); a3 += __shfl_xor(a3, off);
    }
    if (lane == 0) {
      msc[sc * 4 + 0] = a0; msc[sc * 4 + 1] = a1;
      msc[sc * 4 + 2] = a2; msc[sc * 4 + 3] = a3;
    }
    return;
  }
  int blk = bid - 769;
  if (blk < 2304) {
    int didx = blk >> 8, o = blk & 255, c = t;
    wobf[didx * 65536 + o * 256 + c] = f2bf(Wo[o * 2304 + c * 9 + didx]);
  } else {
    int i = (blk - 2304) * 256 + t;
    if (i < 559232) scoresG[i] = 0.f;
    if (i < 140032) pbuf[i] = 0u;
  }
}

// ---------------- transpose kernels ----------------
__global__ __launch_bounds__(256) void k_xt(const float* __restrict__ x,
                                            unsigned short* __restrict__ xt) {
  __shared__ __align__(16) unsigned short tile[64][72];
  int p0 = blockIdx.x * 64, c0 = blockIdx.y * 64, t = blockIdx.z;
  int tid = threadIdx.x;
  {
    int cc = tid >> 2, pq = (tid & 3) * 16;
    const float* src = x + ((t * 256 + c0 + cc) * 65536 + p0 + pq);
    __align__(16) unsigned short tmp[16];
#pragma unroll
    for (int e = 0; e < 16; e += 4) {
      floatx4 v = *(const floatx4*)(src + e);
      tmp[e + 0] = f2bf(v[0]); tmp[e + 1] = f2bf(v[1]);
      tmp[e + 2] = f2bf(v[2]); tmp[e + 3] = f2bf(v[3]);
    }
    *(uintx4*)&tile[cc][pq] = *(const uintx4*)&tmp[0];
    *(uintx4*)&tile[cc][pq + 8] = *(const uintx4*)&tmp[8];
  }
  __syncthreads();
  {
    int pp = tid >> 2, cg = (tid & 3) * 16;
    __align__(16) unsigned short outv[16];
#pragma unroll
    for (int e = 0; e < 16; ++e) outv[e] = tile[cg + e][pp];
    unsigned short* dst = xt + ((t * 65536 + p0 + pp) * 256 + c0 + cg);
    *(uintx4*)dst = *(const uintx4*)&outv[0];
    *(uintx4*)(dst + 8) = *(const uintx4*)&outv[8];
  }
}

__global__ __launch_bounds__(256) void k_yt(const unsigned short* __restrict__ ynat,
                                            unsigned short* __restrict__ yt) {
  __shared__ __align__(16) unsigned short tile[64][72];
  int p0 = blockIdx.x * 64, c0 = blockIdx.y * 64, t = blockIdx.z;
  int tid = threadIdx.x;
  {
    int cc = tid >> 2, pq = (tid & 3) * 16;
    const unsigned short* src = ynat + ((t * 256 + c0 + cc) * 65536 + p0 + pq);
    *(uintx4*)&tile[cc][pq] = *(const uintx4*)src;
    *(uintx4*)&tile[cc][pq + 8] = *(const uintx4*)(src + 8);
  }
  __syncthreads();
  {
    int pp = tid >> 2, cg = (tid & 3) * 16;
    __align__(16) unsigned short outv[16];
#pragma unroll
    for (int e = 0; e < 16; ++e) outv[e] = tile[cg + e][pp];
    unsigned short* dst = yt + ((t * 65536 + p0 + pp) * 256 + c0 + cg);
    *(uintx4*)dst = *(const uintx4*)&outv[0];
    *(uintx4*)(dst + 8) = *(const uintx4*)&outv[8];
  }
}

// ---------------- QKV GEMM: 128x256 tile + LDS-transposed coalesced epilogue ----------------
__global__ __launch_bounds__(256, 2) void k_qkv(const unsigned short* __restrict__ xt,
                                                const unsigned short* __restrict__ wqkv,
                                                const float* __restrict__ bias,
                                                unsigned short* __restrict__ qkv) {
  extern __shared__ __align__(16) char smem[];
  auto As = (unsigned short (*)[64])(smem);            // [128][64]  16KB
  auto Bs = (unsigned short (*)[64])(smem + 16384);    // [256][64]  32KB
  auto Cs = (unsigned short (*)[280])(smem);           // [64][280]  35KB (overlay)
  int flat = blockIdx.x;
  int lg = (flat & 7) * 384 + (flat >> 3);
  int n_t = lg / 6, m_t = lg - n_t * 6;
  int n0 = n_t << 8, m0 = m_t << 7;
  int tid = threadIdx.x;
  int w = tid >> 6, l = tid & 63;
  int wr = w >> 1, wc = w & 1;
  int l15 = l & 15, lhi = l >> 4;
  int sr = tid >> 1, sbase = (tid & 1) * 4, r7 = sr & 7;
  int b7 = tid & 7;
  const unsigned short* gA = wqkv + (m0 + sr) * 256 + sbase * 8;
  const unsigned short* gB = xt + (n0 + tid) * 256;
  floatx4 zf = {0.f, 0.f, 0.f, 0.f};
  floatx4 acc[4][8];
#pragma unroll
  for (int i = 0; i < 4; ++i)
#pragma unroll
    for (int j = 0; j < 8; ++j) acc[i][j] = zf;
  uintx4 ra[4], rb[8];
#define QLOAD(K0) { const uintx4* pa = (const uintx4*)(gA + (K0)); \
                    ra[0] = pa[0]; ra[1] = pa[1]; ra[2] = pa[2]; ra[3] = pa[3]; \
                    const uintx4* pb = (const uintx4*)(gB + (K0)); \
                    rb[0] = pb[0]; rb[1] = pb[1]; rb[2] = pb[2]; rb[3] = pb[3]; \
                    rb[4] = pb[4]; rb[5] = pb[5]; rb[6] = pb[6]; rb[7] = pb[7]; }
  QLOAD(0);
#pragma unroll
  for (int ch = 0; ch < 4; ++ch) {
    __syncthreads();
#pragma unroll
    for (int j = 0; j < 4; ++j)
      *(uintx4*)&As[sr][((sbase + j) ^ r7) * 8] = ra[j];
#pragma unroll
    for (int j = 0; j < 8; ++j)
      *(uintx4*)&Bs[tid][(j ^ b7) * 8] = rb[j];
    __syncthreads();
    if (ch < 3) QLOAD((ch + 1) * 64);
#pragma unroll
    for (int kk = 0; kk < 2; ++kk) {
      short8 af[4];
#pragma unroll
      for (int f = 0; f < 4; ++f) {
        int arow = wr * 64 + f * 16 + l15;
        af[f] = *(const short8*)&As[arow][(((kk << 2) + lhi) ^ (arow & 7)) * 8];
      }
#pragma unroll
      for (int fn = 0; fn < 8; ++fn) {
        int brow = wc * 128 + fn * 16 + l15;
        short8 b = *(const short8*)&Bs[brow][(((kk << 2) + lhi) ^ (brow & 7)) * 8];
#pragma unroll
        for (int fm = 0; fm < 4; ++fm)
          acc[fm][fn] = __builtin_amdgcn_mfma_f32_16x16x32_bf16(af[fm], b, acc[fm][fn], 0, 0, 0);
      }
    }
  }
#undef QLOAD
#pragma unroll
  for (int h = 0; h < 2; ++h) {
    __syncthreads();
    if (wr == h) {
#pragma unroll
      for (int fm = 0; fm < 4; ++fm) {
#pragma unroll
        for (int rr = 0; rr < 4; ++rr) {
          int rl = fm * 16 + lhi * 4 + rr;
          float bv = bias[m0 + h * 64 + rl];
#pragma unroll
          for (int fn = 0; fn < 8; ++fn)
            Cs[rl][wc * 128 + fn * 16 + l15] = f2bf(acc[fm][fn][rr] + bv);
        }
      }
    }
    __syncthreads();
    {
      int p8 = (tid & 31) * 8;
      int pcol = n0 + p8;
      int t = pcol >> 16, p = pcol & 65535;
#pragma unroll
      for (int pass = 0; pass < 8; ++pass) {
        int rl = (tid >> 5) + pass * 8;
        uintx4 v = *(const uintx4*)&Cs[rl][p8];
        *(uintx4*)&qkv[((t * 768 + m0 + h * 64 + rl) << 16) + p] = v;
      }
    }
  }
}

// ---------------- merged mask kernel: gram (bid<328) + rowsum (bid>=328) ----------------
__global__ __launch_bounds__(256) void k_mask(const float* __restrict__ m,
                                              float* __restrict__ G,
                                              float* __restrict__ rbuf) {
  int bid = blockIdx.x;
  int tid = threadIdx.x;
  if (bid >= 328) {
    int row = (bid - 328) * 4 + (tid >> 6);
    int lane = tid & 63;
    if (row < 680) {
      int sc, n;
      if (row < 8)        { sc = 0; n = row; }
      else if (row < 40)  { sc = 1; n = row - 8; }
      else if (row < 168) { sc = 2; n = row - 40; }
      else                { sc = 3; n = row - 168; }
      int lw = 7 - sc, W = 1 << lw;
      int pt, sp0;
      patch_row(n, sc, lw, pt, sp0);
      int base = pt * 65536 + sp0;
      int S = 1 << (14 - 2 * sc);
      float acc = 0.f;
      for (int s = lane; s < S; s += 64) {
        int hh = s >> lw, ww = s & (W - 1);
        acc += m[base + (hh << 8) + ww];
      }
      for (int off = 32; off; off >>= 1) acc += __shfl_xor(acc, off);
      if (lane == 0) rbuf[row] = acc;
    }
    return;
  }
  __shared__ __align__(16) float Ns[32][68];
  __shared__ __align__(16) float Ms[32][68];
  int sc, tn, tm, z, nchunks, soff;
  if (bid < 32)      { sc = 0; tn = 0; tm = 0; z = bid;      nchunks = 8; soff = 0; }
  else if (bid < 40) { sc = 1; tn = 0; tm = 0; z = bid - 32; nchunks = 8; soff = 64; }
  else if (bid < 72) { int r = bid - 40; int tl = r >> 1; sc = 2; tn = tl >> 2; tm = tl & 3; z = r & 1; nchunks = 8; soff = 1088; }
  else               { int tl = bid - 72; sc = 3; tn = tl >> 4; tm = tl & 15; z = 0; nchunks = 4; soff = 17472; }
  int lw = 7 - sc, W = 1 << lw, N = 8 << (2 * sc);
  int kbase = z * nchunks * 64;
  int n0 = tn * 32, m0 = tm * 32;
  bool isA = tid < 128;
  int u = tid & 127;
  int srow = u >> 2, sslot0 = (u & 3) * 4;
  int grow = (isA ? n0 : m0) + srow;
  bool valid = grow < N;
  int pt = 0, sp0 = 0;
  if (valid) patch_row(grow, sc, lw, pt, sp0);
  int gbase = pt * 65536 + sp0;
  int trc = tid >> 4, tcc = tid & 15;
  float a00 = 0.f, a01 = 0.f, a10 = 0.f, a11 = 0.f;
  floatx4 zf = {0.f, 0.f, 0.f, 0.f};
  for (int c = 0; c < nchunks; ++c) {
    int k0 = kbase + c * 64;
    floatx4 v[4];
#pragma unroll
    for (int j = 0; j < 4; ++j) {
      v[j] = zf;
      if (valid) {
        int s = k0 + (sslot0 + j) * 4;
        int hh = s >> lw, ww = s & (W - 1);
        v[j] = *(const floatx4*)(m + gbase + (hh << 8) + ww);
      }
    }
    __syncthreads();
    float* dstrow = isA ? &Ns[srow][0] : &Ms[srow][0];
#pragma unroll
    for (int j = 0; j < 4; ++j) *(floatx4*)&dstrow[(sslot0 + j) * 4] = v[j];
    __syncthreads();
#pragma unroll 4
    for (int k = 0; k < 64; k += 4) {
      floatx4 na = *(const floatx4*)&Ns[2 * trc][k];
      floatx4 nb = *(const floatx4*)&Ns[2 * trc + 1][k];
      floatx4 ma = *(const floatx4*)&Ms[2 * tcc][k];
      floatx4 mb = *(const floatx4*)&Ms[2 * tcc + 1][k];
#pragma unroll
      for (int e = 0; e < 4; ++e) {
        a00 += na[e] * ma[e]; a01 += na[e] * mb[e];
        a10 += nb[e] * ma[e]; a11 += nb[e] * mb[e];
      }
    }
  }
  int rn = n0 + 2 * trc, rm = m0 + 2 * tcc;
  float res[2][2] = {{a00, a01}, {a10, a11}};
#pragma unroll
  for (int i = 0; i < 2; ++i)
#pragma unroll
    for (int j = 0; j < 2; ++j) {
      if (rn + i < N && rm + j < N) {
        float* dst = &G[soff + (rn + i) * N + rm + j];
        if (sc < 3) atomicAdd(dst, res[i][j]); else *dst = res[i][j];
      }
    }
}

// ---------------- merged scores: bid<160 big (sc2/sc3), else 32x32 (sc0/sc1) ----------------
__global__ __launch_bounds__(256) void k_scores_all(const unsigned short* __restrict__ qkv,
                                                    float* __restrict__ scores) {
  __shared__ __align__(16) char sbuf[32768];
  int bid = blockIdx.x;
  int tid = threadIdx.x;
  int w = tid >> 6, l = tid & 63;
  int wr = w >> 1, wc = w & 1, l15 = l & 15, lhi = l >> 4;
  uintx4 zu = {0u, 0u, 0u, 0u};
  floatx4 zf = {0.f, 0.f, 0.f, 0.f};
  if (bid < 160) {
    auto As = (unsigned short (*)[64])(sbuf);
    auto Bs = (unsigned short (*)[64])(sbuf + 16384);
    int lg = (bid & 7) * 20 + (bid >> 3);
    int sc, tn, tm, z, soff;
    if (lg < 32) { sc = 2; tn = 0; tm = 0; z = lg; soff = 1088; }
    else { int r = lg - 32; int tl = r >> 3; sc = 3; tn = tl >> 2; tm = tl & 3; z = r & 7; soff = 17472; }
    int N = 8 << (2 * sc);
    int lw = 7 - sc, W = 1 << lw, lS = 14 - 2 * sc;
    int n0 = tn * 128, m0 = tm * 128;
    int kbase = z * 2048;
    int sr = tid >> 1, sbase = (tid & 1) * 4, r7 = sr & 7;
    int ptA, spA, ptB, spB;
    patch_row(n0 + sr, sc, lw, ptA, spA);
    patch_row(m0 + sr, sc, lw, ptB, spB);
    int baseA = (ptA * 768 + sc * 64) * 65536 + spA;
    int baseB = (ptB * 768 + 256 + sc * 64) * 65536 + spB;
    floatx4 acc[4][4];
#pragma unroll
    for (int i = 0; i < 4; ++i)
#pragma unroll
      for (int j = 0; j < 4; ++j) acc[i][j] = zf;
    uintx4 ra[4], rb[4];
#define GLOAD(K0) { \
  _Pragma("unroll") for (int j = 0; j < 4; ++j) { \
    int k = kbase + (K0) + (sbase + j) * 8; \
    int cl = k >> lS; int s = k & ((1 << lS) - 1); \
    int hh = s >> lw, ww = s & (W - 1); \
    int off = cl * 65536 + (hh << 8) + ww; \
    ra[j] = *(const uintx4*)(qkv + baseA + off); \
    rb[j] = *(const uintx4*)(qkv + baseB + off); } }
    GLOAD(0);
    for (int st = 0; st < 32; ++st) {
      __syncthreads();
#pragma unroll
      for (int j = 0; j < 4; ++j) {
        *(uintx4*)&As[sr][((sbase + j) ^ r7) * 8] = ra[j];
        *(uintx4*)&Bs[sr][((sbase + j) ^ r7) * 8] = rb[j];
      }
      __syncthreads();
      if (st < 31) GLOAD((st + 1) * 64);
#pragma unroll
      for (int kk = 0; kk < 2; ++kk) {
        short8 af[4], bfr[4];
#pragma unroll
        for (int f = 0; f < 4; ++f) {
          int arow = wr * 64 + f * 16 + l15;
          af[f] = *(const short8*)&As[arow][(((kk << 2) + lhi) ^ (arow & 7)) * 8];
          int brow = wc * 64 + f * 16 + l15;
          bfr[f] = *(const short8*)&Bs[brow][(((kk << 2) + lhi) ^ (brow & 7)) * 8];
        }
#pragma unroll
        for (int fm = 0; fm < 4; ++fm)
#pragma unroll
          for (int fn = 0; fn < 4; ++fn)
            acc[fm][fn] = __builtin_amdgcn_mfma_f32_16x16x32_bf16(af[fm], bfr[fn], acc[fm][fn], 0, 0, 0);
      }
    }
#undef GLOAD
#pragma unroll
    for (int fm = 0; fm < 4; ++fm) {
      int nrow = n0 + wr * 64 + fm * 16 + lhi * 4;
#pragma unroll
      for (int rr = 0; rr < 4; ++rr) {
#pragma unroll
        for (int fn = 0; fn < 4; ++fn) {
          int mcol = m0 + wc * 64 + fn * 16 + l15;
          atomicAdd(&scores[soff + (nrow + rr) * N + mcol], acc[fm][fn][rr]);
        }
      }
    }
    return;
  }
  // ---- sc0/sc1 path ----
  {
    auto As = (unsigned short (*)[136])(sbuf);
    auto Bs = (unsigned short (*)[136])(sbuf + 8704);
    int b2 = bid - 160;
    int sc, z, soff;
    if (b2 < 256) { sc = 0; z = b2;       soff = 0; }
    else          { sc = 1; z = b2 - 256; soff = 64; }
    int lw = 7 - sc, W = 1 << lw, lS = 14 - 2 * sc, N = 8 << (2 * sc);
    int kbase = z * 4096;
    floatx4 acc = zf;
    bool isA = tid < 128;
    int u = tid & 127;
    int srow = u >> 2, sslot0 = (u & 3) * 4;
    int grow = srow;
    int cb = (isA ? 0 : 256) + sc * 64;
    int pt = 0, sp0 = 0;
    bool valid = grow < N;
    if (valid) patch_row(grow, sc, lw, pt, sp0);
    int rowbase = (pt * 768 + cb) * 65536 + sp0;
    uintx4 r[4];
#define SLOAD(KS) { int kb2 = kbase + (KS) * 128; \
  _Pragma("unroll") for (int j = 0; j < 4; ++j) { \
    uintx4 v = zu; \
    if (valid) { int k = kb2 + (sslot0 + j) * 8; \
      int cl = k >> lS; int s = k & ((1 << lS) - 1); \
      int hh = s >> lw, ww = s & (W - 1); \
      v = *(const uintx4*)(qkv + rowbase + cl * 65536 + (hh << 8) + ww); } \
    r[j] = v; } }
    SLOAD(0);
    for (int ks = 0; ks < 32; ++ks) {
      __syncthreads();
      {
        unsigned short* dstrow = isA ? &As[srow][0] : &Bs[srow][0];
#pragma unroll
        for (int j = 0; j < 4; ++j) *(uintx4*)&dstrow[(sslot0 + j) * 8] = r[j];
      }
      __syncthreads();
      if (ks < 31) SLOAD(ks + 1);
#pragma unroll
      for (int kk = 0; kk < 4; ++kk) {
        short8 a = *(const short8*)&As[wr * 16 + l15][(kk * 4 + lhi) * 8];
        short8 b = *(const short8*)&Bs[wc * 16 + l15][(kk * 4 + lhi) * 8];
        acc = __builtin_amdgcn_mfma_f32_16x16x32_bf16(a, b, acc, 0, 0, 0);
      }
    }
#undef SLOAD
    int rrow = wr * 16 + lhi * 4;
    int ccol = wc * 16 + l15;
    if (ccol < N) {
#pragma unroll
      for (int rr = 0; rr < 4; ++rr)
        if (rrow + rr < N) atomicAdd(&scores[soff + (rrow + rr) * N + ccol], acc[rr]);
    }
  }
}

// ---------------- logits + softmax -> P bf16 ----------------
__global__ void k_softmax(const float* __restrict__ scores, const float* __restrict__ G,
                          const float* __restrict__ rbuf, const float* __restrict__ msc,
                          unsigned short* __restrict__ pbuf) {
  int row = blockIdx.x, lane = threadIdx.x;
  int sc, n, roff, soff, poff;
  if (row < 8)        { sc = 0; n = row;       roff = 0;   soff = 0;     poff = 0; }
  else if (row < 40)  { sc = 1; n = row - 8;   roff = 8;   soff = 64;    poff = 512; }
  else if (row < 168) { sc = 2; n = row - 40;  roff = 40;  soff = 1088;  poff = 1536; }
  else                { sc = 3; n = row - 168; roff = 168; soff = 17472; poff = 17920; }
  int N = 8 << (2 * sc);
  int Kpad = (sc < 2) ? 32 : N;
  float Sf = (float)(1 << (14 - 2 * sc));
  float invD = 1.0f / (float)(1 << (20 - 2 * sc));
  float alpha = msc[sc * 4 + 0], beta = msc[sc * 4 + 1];
  float gamma = msc[sc * 4 + 2], delta = msc[sc * 4 + 3];
  float rn = rbuf[roff + n];
  float vals[8];
  float mx = -1e30f;
#pragma unroll
  for (int j = 0; j < 8; ++j) {
    float v = -1e30f;
    int mcol = lane + j * 64;
    if (j * 64 < N && mcol < N) {
      float sq = scores[soff + n * N + mcol];
      float g = G[soff + n * N + mcol];
      float rm = rbuf[roff + mcol];
      v = sq * (alpha * g + beta * rn + gamma * rm + delta * Sf) * invD;
    }
    vals[j] = v;
    mx = fmaxf(mx, v);
  }
  for (int off = 32; off; off >>= 1) mx = fmaxf(mx, __shfl_xor(mx, off));
  float sum = 0.f;
#pragma unroll
  for (int j = 0; j < 8; ++j) {
    int mcol = lane + j * 64;
    float e = 0.f;
    if (j * 64 < N && mcol < N) e = __expf(vals[j] - mx);
    vals[j] = e;
    sum += e;
  }
  for (int off = 32; off; off >>= 1) sum += __shfl_xor(sum, off);
  float inv = 1.f / sum;
#pragma unroll
  for (int j = 0; j < 8; ++j) {
    int mcol = lane + j * 64;
    if (j * 64 < N && mcol < N) pbuf[poff + n * Kpad + mcol] = f2bf(vals[j] * inv);
  }
}

// ---------------- PV GEMM: dbuf LDS, 1 barrier/K-step, balanced XCD co-location ----------------
__global__ __launch_bounds__(256) void k_pv(const unsigned short* __restrict__ qkv,
                                            const unsigned short* __restrict__ pbuf,
                                            unsigned short* __restrict__ ynat) {
  int bid0 = blockIdx.x;
  int bid;
  if (bid0 < 6144) {
    bid = bid0;                                   // sc0/sc1: no sibling sharing
  } else if (bid0 < 8192) {                       // sc2: co-locate by-siblings per bx
    int q = bid0 - 6144; int c = q & 7, j = q >> 3;
    bid = 6144 + ((c * 128 + (j & 127)) << 1) + (j >> 7);
  } else {                                        // sc3
    int q = bid0 - 8192; int c = q & 7, j = q >> 3;
    bid = 8192 + ((c * 32 + (j & 31)) << 3) + (j >> 5);
  }
  int sc, bx, by;
  if (bid < 4096)      { sc = 0; bx = bid; by = 0; }
  else if (bid < 6144) { sc = 1; bx = bid - 4096; by = 0; }
  else if (bid < 8192) { int r = bid - 6144; sc = 2; bx = r >> 1; by = r & 1; }
  else                 { int r = bid - 8192; sc = 3; bx = r >> 3; by = r & 7; }
  int WR    = (sc == 0) ? 1 : (sc == 1) ? 2 : 4;
  int logWC = (sc == 0) ? 2 : (sc == 1) ? 1 : 0;
  int poff  = (sc == 0) ? 0 : (sc == 1) ? 512 : (sc == 2) ? 1536 : 17920;
  int lw = 7 - sc, W = 1 << lw;
  int lS = 14 - 2 * sc;
  int N = 8 << (2 * sc);
  int Kpad = (sc < 2) ? 32 : N;
  int WC = 1 << logWC;
  int d0 = bx * (WC * 64);
  int nb = by * (WR * 16);
  __shared__ __align__(16) unsigned short As[2][64][40];
  __shared__ __align__(16) unsigned short Bt[2][256][32];
  int tid = threadIdx.x;
  int w = tid >> 6, l = tid & 63;
  int wr = w >> logWC, wc = w & (WC - 1);
  int l15 = l & 15, lhi = l >> 4;
  floatx4 zf = {0.f, 0.f, 0.f, 0.f};
  floatx4 acc[4];
#pragma unroll
  for (int i = 0; i < 4; ++i) acc[i] = zf;
  int bmp = tid & 15;
  int dg = tid >> 4;
  bool act0 = (WC > 1) || (dg < 8);
  bool has1 = (WC == 4);
  bool doA = tid < WR * 64;
  int arow = tid >> 2, akg = (tid & 3) * 8;
  int ksteps = Kpad >> 5;
  uintx4 zu = {0u, 0u, 0u, 0u};
  int vcb = (512 + sc * 64) * 65536;
  uintx4 av = zu, lo0 = zu, hi0 = zu, lo1 = zu, hi1 = zu;
#define PLOADS(KS) { int k0 = (KS) * 32; \
    av = zu; lo0 = zu; hi0 = zu; lo1 = zu; hi1 = zu; \
    if (doA) av = *(const uintx4*)(pbuf + poff + (nb + arow) * Kpad + k0 + akg); \
    int gm0 = k0 + 2 * bmp, gm1 = gm0 + 1; \
    bool mv0 = gm0 < N, mv1 = gm1 < N; \
    int pt0 = 0, sp00 = 0, pt1 = 0, sp01 = 0; \
    if (mv0) patch_row(gm0, sc, lw, pt0, sp00); \
    if (mv1) patch_row(gm1, sc, lw, pt1, sp01); \
    { int d = d0 + dg * 8; int cl = d >> lS; int s = d & ((1 << lS) - 1); \
      int hh = s >> lw, ww = s & (W - 1); int sp = (hh << 8) + ww; \
      if (act0 && mv0) lo0 = *(const uintx4*)(qkv + pt0 * 768 * 65536 + vcb + cl * 65536 + sp00 + sp); \
      if (act0 && mv1) hi0 = *(const uintx4*)(qkv + pt1 * 768 * 65536 + vcb + cl * 65536 + sp01 + sp); } \
    if (has1) { int d = d0 + (dg + 16) * 8; int cl = d >> lS; int s = d & ((1 << lS) - 1); \
      int hh = s >> lw, ww = s & (W - 1); int sp = (hh << 8) + ww; \
      if (mv0) lo1 = *(const uintx4*)(qkv + pt0 * 768 * 65536 + vcb + cl * 65536 + sp00 + sp); \
      if (mv1) hi1 = *(const uintx4*)(qkv + pt1 * 768 * 65536 + vcb + cl * 65536 + sp01 + sp); } }
  PLOADS(0);
  for (int ks = 0; ks < ksteps; ++ks) {
    int b = ks & 1;
    if (doA) *(uintx4*)&As[b][arow][akg] = av;
    if (act0) {
      int du = dg * 8;
#pragma unroll
      for (int j = 0; j < 8; ++j) {
        int d = du + j;
        unsigned losh = (lo0[j >> 1] >> ((j & 1) * 16)) & 0xFFFFu;
        unsigned hish = (hi0[j >> 1] >> ((j & 1) * 16)) & 0xFFFFu;
        unsigned wv = losh | (hish << 16);
        int slot = (bmp >> 2) ^ ((d >> 1) & 3) ^ ((d >> 3) & 3);
        ((unsigned int*)&Bt[b][d][0])[slot * 4 + (bmp & 3)] = wv;
      }
    }
    if (has1) {
      int du = (dg + 16) * 8;
#pragma unroll
      for (int j = 0; j < 8; ++j) {
        int d = du + j;
        unsigned losh = (lo1[j >> 1] >> ((j & 1) * 16)) & 0xFFFFu;
        unsigned hish = (hi1[j >> 1] >> ((j & 1) * 16)) & 0xFFFFu;
        unsigned wv = losh | (hish << 16);
        int slot = (bmp >> 2) ^ ((d >> 1) & 3) ^ ((d >> 3) & 3);
        ((unsigned int*)&Bt[b][d][0])[slot * 4 + (bmp & 3)] = wv;
      }
    }
    __syncthreads();
    if (ks + 1 < ksteps) PLOADS(ks + 1);
    short8 a = *(const short8*)&As[b][wr * 16 + l15][lhi * 8];
#pragma unroll
    for (int fn = 0; fn < 4; ++fn) {
      int row = wc * 64 + fn * 16 + l15;
      int slot = lhi ^ ((row >> 1) & 3) ^ ((row >> 3) & 3);
      short8 bb = *(const short8*)&Bt[b][row][slot * 8];
      acc[fn] = __builtin_amdgcn_mfma_f32_16x16x32_bf16(a, bb, acc[fn], 0, 0, 0);
    }
  }
#undef PLOADS
  int nrow = nb + wr * 16 + lhi * 4;
#pragma unroll
  for (int rr = 0; rr < 4; ++rr) {
    int n = nrow + rr;
    if (n < N) {
      int pt, sp0;
      patch_row(n, sc, lw, pt, sp0);
#pragma unroll
      for (int fn = 0; fn < 4; ++fn) {
        int d = d0 + wc * 64 + fn * 16 + l15;
        int cl = d >> lS;
        int s = d & ((1 << lS) - 1);
        int hh = s >> lw, ww = s & (W - 1);
        int c = sc * 64 + cl;
        ynat[(pt * 256 + c) * 65536 + sp0 + (hh << 8) + ww] = f2bf(acc[fn][rr]);
      }
    }
  }
}

// ---------------- conv3x3: halo-row staging (R9, known-good 187us) ----------------
__global__ __launch_bounds__(256, 2) void k_conv(const unsigned short* __restrict__ yt,
                                                 const unsigned short* __restrict__ wo,
                                                 const float* __restrict__ bo,
                                                 float* __restrict__ out) {
  __shared__ __align__(16) unsigned short As[128][128];
  __shared__ __align__(16) unsigned short Bs[130][64];
  int flat = blockIdx.x;
  int lg = ((flat & 7) << 7) + (flat >> 3);
  int n_t = lg >> 1, m_t = lg & 1;
  int n0 = n_t << 8, m0 = m_t << 7;
  int tt = n0 >> 16, yy = (n0 >> 8) & 255;
  int tid = threadIdx.x;
  int w = tid >> 6, l = tid & 63;
  int wr = w >> 1, wc = w & 1;
  int l15 = l & 15, lhi = l >> 4;
  int a_d0 = tid >> 7, a_o0 = tid & 127;
  bool doA1 = tid < 128;
  bool doBh = tid >= 254;
  floatx4 zf = {0.f, 0.f, 0.f, 0.f};
  floatx4 acc[4][8];
#pragma unroll
  for (int i = 0; i < 4; ++i)
#pragma unroll
    for (int j = 0; j < 8; ++j) acc[i][j] = zf;
  uintx4 zu = {0u, 0u, 0u, 0u};
  uintx4 rb[4], ra0[4], ra1[4];
  const unsigned short* ybase = yt + (tt << 24);
#define CLOAD(ST) { \
    int dy = (ST) >> 3, cc = ((ST) & 7) << 5; \
    int yq = yy + dy - 1; \
    bool yv = (unsigned)yq < 256u; \
    { int xq = tid - 1; \
      if (yv && (unsigned)xq < 256u) { \
        const uintx4* p = (const uintx4*)(ybase + ((yq << 8) + xq) * 256 + cc); \
        rb[0] = p[0]; rb[1] = p[1]; rb[2] = p[2]; rb[3] = p[3]; \
      } else { rb[0] = zu; rb[1] = zu; rb[2] = zu; rb[3] = zu; } } \
    { const uintx4* p = (const uintx4*)(wo + (dy * 3 + a_d0) * 65536 + (m0 + a_o0) * 256 + cc); \
      ra0[0] = p[0]; ra0[1] = p[1]; ra0[2] = p[2]; ra0[3] = p[3]; } \
    if (doA1) { \
      const uintx4* p = (const uintx4*)(wo + (dy * 3 + 2) * 65536 + (m0 + tid) * 256 + cc); \
      ra1[0] = p[0]; ra1[1] = p[1]; ra1[2] = p[2]; ra1[3] = p[3]; \
    } else if (doBh) { \
      int xq = tid + 1; \
      if (yv && xq < 256) { \
        const uintx4* p = (const uintx4*)(ybase + ((yq << 8) + xq) * 256 + cc); \
        ra1[0] = p[0]; ra1[1] = p[1]; ra1[2] = p[2]; ra1[3] = p[3]; \
      } else { ra1[0] = zu; ra1[1] = zu; ra1[2] = zu; ra1[3] = zu; } } }
  CLOAD(0);
  for (int st = 0; st < 24; ++st) {
    __syncthreads();
    {
      int brow = tid >> 1, bhf = (tid & 1) * 4, br7 = brow & 7;
#pragma unroll
      for (int j = 0; j < 4; ++j)
        *(uintx4*)&Bs[brow][((bhf + j) ^ br7) * 8] = rb[j];
      int ao7 = a_o0 & 7;
#pragma unroll
      for (int j = 0; j < 4; ++j)
        *(uintx4*)&As[a_o0][((a_d0 * 4 + j) ^ ao7) * 8] = ra0[j];
      if (doA1) {
        int o7 = tid & 7;
#pragma unroll
        for (int j = 0; j < 4; ++j)
          *(uintx4*)&As[tid][((8 + j) ^ o7) * 8] = ra1[j];
      } else if (doBh) {
        int xh = tid + 2;
        int brow2 = xh >> 1, bhf2 = (xh & 1) * 4, br72 = brow2 & 7;
#pragma unroll
        for (int j = 0; j < 4; ++j)
          *(uintx4*)&Bs[brow2][((bhf2 + j) ^ br72) * 8] = ra1[j];
      }
    }
    __syncthreads();
    if (st < 23) CLOAD(st + 1);
#pragma unroll
    for (int dx = 0; dx < 3; ++dx) {
      short8 af[4];
#pragma unroll
      for (int f = 0; f < 4; ++f) {
        int ol = wr * 64 + f * 16 + l15;
        af[f] = *(const short8*)&As[ol][((dx * 4 + lhi) ^ (ol & 7)) * 8];
      }
#pragma unroll
      for (int fn = 0; fn < 8; ++fn) {
        int xh = wc * 128 + fn * 16 + l15 + dx;
        short8 b = *(const short8*)&Bs[xh >> 1][((((xh & 1) * 4 + lhi)) ^ ((xh >> 1) & 7)) * 8];
#pragma unroll
        for (int fm = 0; fm < 4; ++fm)
          acc[fm][fn] = __builtin_amdgcn_mfma_f32_16x16x32_bf16(af[fm], b, acc[fm][fn], 0, 0, 0);
      }
    }
  }
#undef CLOAD
#pragma unroll
  for (int fm = 0; fm < 4; ++fm) {
    int o = m0 + wr * 64 + fm * 16 + lhi * 4;
#pragma unroll
    for (int rr = 0; rr < 4; ++rr) {
      float bias = bo[o + rr];
#pragma unroll
      for (int fn = 0; fn < 8; ++fn) {
        int xcol = wc * 128 + fn * 16 + l15;
        float z = acc[fm][fn][rr] + bias;
        out[((tt * 256 + o + rr) << 16) + (yy << 8) + xcol] = z > 0.f ? z : 0.2f * z;
      }
    }
  }
}

// ---------------------------------------------------------------------------
extern "C" void kernel_launch(void* const* d_in, const int* in_sizes, int n_in,
                              void* d_out, int out_size, void* d_ws, size_t ws_size,
                              hipStream_t stream) {
  const float* x   = (const float*)d_in[0];
  const float* m   = (const float*)d_in[1];
  const float* Wq  = (const float*)d_in[2];
  const float* bq  = (const float*)d_in[3];
  const float* Wk  = (const float*)d_in[4];
  const float* bk  = (const float*)d_in[5];
  const float* Wv  = (const float*)d_in[6];
  const float* bv  = (const float*)d_in[7];
  const float* Wmq = (const float*)d_in[8];
  const float* bmq = (const float*)d_in[9];
  const float* Wmk = (const float*)d_in[10];
  const float* bmk = (const float*)d_in[11];
  const float* Wo  = (const float*)d_in[12];
  const float* bo  = (const float*)d_in[13];

  char* ws = (char*)d_ws;
  unsigned short* qkv   = (unsigned short*)(ws);
  unsigned short* xtb   = (unsigned short*)(ws + 201326592);  // xt, later yt
  unsigned short* wqkv  = (unsigned short*)(ws + 268435456);
  unsigned short* wobf  = (unsigned short*)(ws + 268828672);
  float* bias           = (float*)(ws + 270008320);
  float* msc            = (float*)(ws + 270011392);
  float* scores         = (float*)(ws + 270011456);
  float* G              = (float*)(ws + 271129920);
  float* rbuf           = (float*)(ws + 272248384);
  unsigned short* pbuf  = (unsigned short*)(ws + 272251104);
  float* out            = (float*)d_out;
  unsigned short* ynat  = (unsigned short*)d_out;  // low half of d_out as bf16 scratch

  k_prep<<<dim3(5258), dim3(256), 0, stream>>>(Wq, Wk, Wv, bq, bk, bv, Wmq, bmq, Wmk, bmk,
                                               Wo, bo, wqkv, bias, msc, wobf, scores,
                                               (unsigned int*)pbuf);
  k_xt<<<dim3(1024, 4, 2), dim3(256), 0, stream>>>(x, xtb);
  k_qkv<<<dim3(3072), dim3(256), 49152, stream>>>(xtb, wqkv, bias, qkv);
  k_mask<<<dim3(498), dim3(256), 0, stream>>>(m, G, rbuf);
  k_scores_all<<<dim3(480), dim3(256), 0, stream>>>(qkv, scores);
  k_softmax<<<dim3(680), dim3(64), 0, stream>>>(scores, G, rbuf, msc, pbuf);
  k_pv<<<dim3(10240), dim3(256), 0, stream>>>(qkv, pbuf, ynat);
  k_yt<<<dim3(1024, 4, 2), dim3(256), 0, stream>>>(ynat, xtb);
  k_conv<<<dim3(1024), dim3(256), 0, stream>>>(xtb, wobf, bo, out);
}